// Round 10
// baseline (1656.592 us; speedup 1.0000x reference)
//
#include <hip/hip_runtime.h>
#include <math.h>

typedef unsigned short u16;
typedef short v8s __attribute__((ext_vector_type(8)));
typedef u16   v4u __attribute__((ext_vector_type(4)));
typedef float v4f __attribute__((ext_vector_type(4)));

#define DEVFN static __device__ __forceinline__

constexpr int cB = 2, cS = 4096, cD = 2048, cV = 32000, cH = 16, cHD = 128;
constexpr int cBS = 16, cNA = 128, cMASK = 31999, cDFF = 8192;
constexpr int NCAND = cS - cBS + 1;   // 4081 anchor candidates
constexpr int MTOK  = cB * cNA * cBS; // 4096 query tokens
constexpr int MKV   = cB * cNA * 17;  // 4352 kv rows (ctx + 16)
constexpr int NCH   = cV / 128;       // 250 vocab chunks (128-wide, fallback)
constexpr int NCH2  = cV / 256;       // 125 vocab chunks (256-wide, fast)

constexpr int EPI_BF16 = 0, EPI_SILU = 1, EPI_OEMB = 2, EPI_DOWNACC = 3, EPI_STATS = 4;
constexpr int ASRC_BF16 = 0, ASRC_RMS = 1, ASRC_AOMAP = 2;

struct RmsSrc {
  const float* hs; const float* emb; const float* nattn; const float* nchs;
  const float* rowinv; const int* ftok; const int* cpos;
};

DEVFN u16 f2bf(float f) {               // RNE fp32 -> bf16
  union { float f; unsigned u; } a; a.f = f;
  unsigned u = a.u;
  u = u + 0x7fffu + ((u >> 16) & 1u);
  return (u16)(u >> 16);
}
DEVFN float bf2f(u16 h) {
  union { unsigned u; float f; } a; a.u = ((unsigned)h) << 16;
  return a.f;
}
DEVFN float waveSum(float v) {
  #pragma unroll
  for (int o = 32; o >= 1; o >>= 1) v += __shfl_xor(v, o);
  return v;
}
DEVFN void gload16(void* lds, const void* g) {
  __builtin_amdgcn_global_load_lds(
      (const __attribute__((address_space(1))) unsigned*)g,
      (__attribute__((address_space(3))) unsigned*)lds, 16, 0, 0);
}

// ---------------------------------------------------------------------------
__global__ void k_select(const float* __restrict__ lmask, const float* __restrict__ rv_in,
                         int* __restrict__ self) {
  int b = blockIdx.x >> 4, chunk = blockIdx.x & 15;
  __shared__ float rvs[4096];
  for (int i = threadIdx.x; i < NCAND; i += 256) {
    bool valid = lmask[(size_t)b * cS + i] > 0.5f;
    rvs[i] = valid ? rv_in[(size_t)b * NCAND + i] : 2.0f;
  }
  __syncthreads();
  int i = chunk * 256 + threadIdx.x;
  if (i < NCAND) {
    float v = rvs[i];
    int rank = 0;
    for (int j = 0; j < NCAND; ++j) {
      float u = rvs[j];
      rank += (u < v) || (u == v && j < i);
    }
    self[(size_t)b * NCAND + i] = (rank < cNA) ? 1 : 0;
  }
}

__global__ void k_anchors(const float* __restrict__ lmask, const int* __restrict__ self,
                          const int* __restrict__ ids, int* __restrict__ anchors,
                          int* __restrict__ keepA, int* __restrict__ ftok, int* __restrict__ cpos) {
  int b = blockIdx.x;
  __shared__ int flags[4096];
  __shared__ int ssum[256];
  __shared__ int soff[257];
  __shared__ int abuf[cNA];
  for (int i = threadIdx.x; i < 4096; i += 256)
    flags[i] = (i < NCAND) ? (self[(size_t)b * NCAND + i] && (lmask[(size_t)b * cS + i] > 0.5f)) : 0;
  if (threadIdx.x < cNA) abuf[threadIdx.x] = 0;
  __syncthreads();
  int s = 0;
  #pragma unroll
  for (int j = 0; j < 16; ++j) s += flags[threadIdx.x * 16 + j];
  ssum[threadIdx.x] = s;
  __syncthreads();
  if (threadIdx.x == 0) {
    int a = 0;
    for (int t = 0; t < 256; ++t) { soff[t] = a; a += ssum[t]; }
    soff[256] = a;
  }
  __syncthreads();
  int nsel = soff[256];
  int p = soff[threadIdx.x];
  for (int j = 0; j < 16; ++j) {
    int i = threadIdx.x * 16 + j;
    if (flags[i]) { if (p < cNA) abuf[p] = i; ++p; }
  }
  __syncthreads();
  if (threadIdx.x < cNA) {
    int q = threadIdx.x;
    int kp = (q < nsel) ? 1 : 0;
    int a = kp ? abuf[q] : 0;
    anchors[b * cNA + q] = a;
    keepA[b * cNA + q] = kp;
    int av = a; if (av < 0) av = 0; if (av > cS - 1) av = cS - 1;
    int tok = ids[(size_t)b * cS + av];
    ftok[b * cNA + q] = kp ? tok : cMASK;
    cpos[b * cNA + q] = (a - 1 > 0) ? (a - 1) : 0;
  }
}

// per-kv-row 1/rms (fallback tier)
__global__ void k_rowinv(const float* __restrict__ hs, const float* __restrict__ emb,
                         const int* __restrict__ ftok, const int* __restrict__ cpos,
                         float* __restrict__ rowinv) {
  int r = blockIdx.x;
  int j = r % 17, bn = r / 17, b = bn >> 7;
  const float* src = (j == 0) ? hs + ((size_t)b * cS + cpos[bn]) * cD
                              : emb + (size_t)((j == 1) ? ftok[bn] : cMASK) * cD;
  float ss = 0.f;
  for (int d = threadIdx.x; d < cD; d += 256) { float v = src[d]; ss += v * v; }
  ss = waveSum(ss);
  __shared__ float red[4];
  if ((threadIdx.x & 63) == 0) red[threadIdx.x >> 6] = ss;
  __syncthreads();
  if (threadIdx.x == 0) {
    float tot = red[0] + red[1] + red[2] + red[3];
    rowinv[r] = 1.0f / sqrtf(tot / cD + 1e-6f);
  }
}

// kv_in = rms'd rows, materialized bf16 (fast tier). grid: MKV x 256
__global__ void k_build2(const float* __restrict__ hs, const float* __restrict__ emb,
                         const float* __restrict__ nattn, const float* __restrict__ nchs,
                         const int* __restrict__ ftok, const int* __restrict__ cpos,
                         u16* __restrict__ kv) {
  int r = blockIdx.x;
  int j = r % 17, bn = r / 17, b = bn >> 7;
  const float* src; const float* w;
  if (j == 0) { src = hs + ((size_t)b * cS + cpos[bn]) * cD; w = nchs; }
  else {
    int tok = (j == 1) ? ftok[bn] : cMASK;
    src = emb + (size_t)tok * cD; w = nattn;
  }
  float ss = 0.f;
  for (int d = threadIdx.x; d < cD; d += 256) { float v = src[d]; ss += v * v; }
  ss = waveSum(ss);
  __shared__ float red[4];
  if ((threadIdx.x & 63) == 0) red[threadIdx.x >> 6] = ss;
  __syncthreads();
  float tot = red[0] + red[1] + red[2] + red[3];
  float inv = 1.0f / sqrtf(tot / cD + 1e-6f);
  for (int d = threadIdx.x; d < cD; d += 256)
    kv[(size_t)r * cD + d] = f2bf(src[d] * inv * w[d]);
}

// RMS over fp32 rows -> bf16
__global__ void k_rms(const float* __restrict__ xin, const float* __restrict__ w,
                      u16* __restrict__ outp) {
  int m = blockIdx.x;
  const float* row = xin + (size_t)m * cD;
  float ss = 0.f;
  for (int d = threadIdx.x; d < cD; d += 256) { float v = row[d]; ss += v * v; }
  ss = waveSum(ss);
  __shared__ float red[4];
  if ((threadIdx.x & 63) == 0) red[threadIdx.x >> 6] = ss;
  __syncthreads();
  float tot = red[0] + red[1] + red[2] + red[3];
  float inv = 1.0f / sqrtf(tot / cD + 1e-6f);
  for (int d = threadIdx.x; d < cD; d += 256)
    outp[(size_t)m * cD + d] = f2bf(row[d] * inv * w[d]);
}

// straight fp32 -> bf16 convert (layout preserved)
__global__ void k_conv(const float* __restrict__ in, u16* __restrict__ out, long n) {
  long i = ((long)blockIdx.x * 256 + threadIdx.x) * 8;
  long stride = (long)gridDim.x * 256 * 8;
  for (; i < n; i += stride) {
    v4f a = *(const v4f*)(in + i), b = *(const v4f*)(in + i + 4);
    v8s pk;
    #pragma unroll
    for (int e = 0; e < 4; ++e) { pk[e] = (short)f2bf(a[e]); pk[4 + e] = (short)f2bf(b[e]); }
    *(v8s*)(out + i) = pk;
  }
}

// transpose-convert: W [K][N] fp32 -> WT [N][K] bf16. 64x64 tiles, grid (N/64, K/64)
__global__ void k_tconv(const float* __restrict__ W, u16* __restrict__ WT, int K, int N) {
  __shared__ u16 t[64][72];
  int n0 = blockIdx.x * 64, k0 = blockIdx.y * 64;
  int tid = threadIdx.x;
  int c4 = (tid & 15) * 4, r0 = tid >> 4;
  #pragma unroll
  for (int rr = 0; rr < 64; rr += 16) {
    int k = r0 + rr;
    v4f v = *(const v4f*)(W + (size_t)(k0 + k) * N + n0 + c4);
    #pragma unroll
    for (int e = 0; e < 4; ++e) t[c4 + e][k] = f2bf(v[e]);
  }
  __syncthreads();
  int n = tid >> 2, kq = (tid & 3) * 16;
  v8s o0, o1;
  #pragma unroll
  for (int e = 0; e < 8; ++e) { o0[e] = (short)t[n][kq + e]; o1[e] = (short)t[n][kq + 8 + e]; }
  *(v8s*)(WT + (size_t)(n0 + n) * K + k0 + kq) = o0;
  *(v8s*)(WT + (size_t)(n0 + n) * K + k0 + kq + 8) = o1;
}

// ---------------------------------------------------------------------------
// 8-PHASE PIPELINED 256x256 GEMM (m201-style template, K-split half-tiles).
// BK=64 split into 2 K-halves (256x32 each for A and B). Per K-tile: 4 phases
// (ks x mi-half), each {8-12 ds_read | stage 1 half-tile | lgkm0 | 16 MFMA |
// [vmcnt(4) once/tile] | barrier}. Half-tile staged 5-6 phases ahead into a
// provably-dead slot. Swizzle: 16B-chunk c2 ^= (row>>1)&3 (involution, 2-way).
template <int EPI>
__launch_bounds__(512, 1)
__global__ void k_gemm6(const u16* __restrict__ Abf, const u16* __restrict__ Bbf,
                        u16* __restrict__ Cbf, const u16* __restrict__ Gaux,
                        v4f* __restrict__ partials, int K, int ldc, int nch) {
  // 128 KB: buf b at b*32768 (u16); A kh at +kh*8192; B kh at +16384+kh*8192
  __shared__ __align__(16) u16 lds[65536];
  const int tid = threadIdx.x;
  const int lane = tid & 63, wid = tid >> 6;
  const int wm = wid >> 2, wn = wid & 3;        // wave grid 2 x 4; per-wave out 128x64
  const int lc = lane & 15, lq = lane >> 4;
  const int m0 = blockIdx.x * 256, n0 = blockIdx.y * 256;

  // staging sources: chunk s = i*512+tid within a 256x32 half; row=s>>2,
  // physical c2 = s&3, logical c2 = (s&3) ^ ((row>>1)&3)
  const u16* srcA[2]; const u16* srcB[2];
  #pragma unroll
  for (int i = 0; i < 2; ++i) {
    int s = i * 512 + tid;
    int row = s >> 2;
    int c2 = (s & 3) ^ ((row >> 1) & 3);
    srcA[i] = Abf + (size_t)(m0 + row) * K + c2 * 8;
    srcB[i] = Bbf + (size_t)(n0 + row) * K + c2 * 8;
  }

  v4f acc[8][4];
  #pragma unroll
  for (int i = 0; i < 8; ++i)
    #pragma unroll
    for (int j = 0; j < 4; ++j) acc[i][j] = (v4f){0.f, 0.f, 0.f, 0.f};

  // fragment offsets (u16, within an 8192-u16 half): (row*4 + (lq^((lc>>1)&3)))*8
  const int fsw = lq ^ ((lc >> 1) & 3);
  int aoff[8], boff[4];
  #pragma unroll
  for (int mi = 0; mi < 8; ++mi) aoff[mi] = ((wm * 128 + mi * 16 + lc) * 4 + fsw) * 8;
  #pragma unroll
  for (int ni = 0; ni < 4; ++ni) boff[ni] = ((wn * 64 + ni * 16 + lc) * 4 + fsw) * 8;

  auto stageA = [&](int t, int kh) {
    int reg = (t & 1) * 32768 + kh * 8192;
    int koff = t * 64 + kh * 32;
    #pragma unroll
    for (int i = 0; i < 2; ++i)
      gload16(&lds[reg + i * 4096 + wid * 512], srcA[i] + koff);
  };
  auto stageB = [&](int t, int kh) {
    int reg = (t & 1) * 32768 + 16384 + kh * 8192;
    int koff = t * 64 + kh * 32;
    #pragma unroll
    for (int i = 0; i < 2; ++i)
      gload16(&lds[reg + i * 4096 + wid * 512], srcB[i] + koff);
  };

  // prologue: pair(0,0), pair(0,1), pair(1,0) = 12 loads; force pair(0,0)
  stageA(0, 0); stageB(0, 0);
  stageA(0, 1); stageB(0, 1);
  stageA(1, 0); stageB(1, 0);
  asm volatile("s_waitcnt vmcnt(8)" ::: "memory");
  __builtin_amdgcn_s_barrier();

  const int NT = K >> 6;
  for (int t = 0; t < NT; ++t) {
    const int bufb = (t & 1) * 32768;
    const u16* Ab0 = &lds[bufb];
    const u16* Ab1 = &lds[bufb + 8192];
    const u16* Bb0 = &lds[bufb + 16384];
    const u16* Bb1 = &lds[bufb + 24576];
    v8s a_[4], b_[4];

    // q0: ks0, mi 0-3; stage A(t+1) kh1
    #pragma unroll
    for (int ni = 0; ni < 4; ++ni) b_[ni] = *(const v8s*)(Bb0 + boff[ni]);
    #pragma unroll
    for (int mi = 0; mi < 4; ++mi) a_[mi] = *(const v8s*)(Ab0 + aoff[mi]);
    if (t + 1 < NT) stageA(t + 1, 1);
    asm volatile("s_waitcnt lgkmcnt(0)" ::: "memory");
    __builtin_amdgcn_sched_barrier(0);
    __builtin_amdgcn_s_setprio(1);
    #pragma unroll
    for (int mi = 0; mi < 4; ++mi)
      #pragma unroll
      for (int ni = 0; ni < 4; ++ni)
        acc[mi][ni] = __builtin_amdgcn_mfma_f32_16x16x32_bf16(a_[mi], b_[ni], acc[mi][ni], 0, 0, 0);
    __builtin_amdgcn_s_setprio(0);
    __builtin_amdgcn_s_barrier();

    // q1: ks0, mi 4-7 (b_ kept); stage B(t+1) kh1; vmcnt once per tile
    #pragma unroll
    for (int mi = 0; mi < 4; ++mi) a_[mi] = *(const v8s*)(Ab0 + aoff[mi + 4]);
    if (t + 1 < NT) stageB(t + 1, 1);
    asm volatile("s_waitcnt lgkmcnt(0)" ::: "memory");
    __builtin_amdgcn_sched_barrier(0);
    __builtin_amdgcn_s_setprio(1);
    #pragma unroll
    for (int mi = 0; mi < 4; ++mi)
      #pragma unroll
      for (int ni = 0; ni < 4; ++ni)
        acc[mi + 4][ni] = __builtin_amdgcn_mfma_f32_16x16x32_bf16(a_[mi], b_[ni], acc[mi + 4][ni], 0, 0, 0);
    __builtin_amdgcn_s_setprio(0);
    if (t + 1 < NT) { asm volatile("s_waitcnt vmcnt(4)" ::: "memory"); }
    else            { asm volatile("s_waitcnt vmcnt(0)" ::: "memory"); }
    __builtin_amdgcn_s_barrier();

    // q2: ks1, mi 0-3; stage A(t+2) kh0 (slot dead since end of q1)
    #pragma unroll
    for (int ni = 0; ni < 4; ++ni) b_[ni] = *(const v8s*)(Bb1 + boff[ni]);
    #pragma unroll
    for (int mi = 0; mi < 4; ++mi) a_[mi] = *(const v8s*)(Ab1 + aoff[mi]);
    if (t + 2 < NT) stageA(t + 2, 0);
    asm volatile("s_waitcnt lgkmcnt(0)" ::: "memory");
    __builtin_amdgcn_sched_barrier(0);
    __builtin_amdgcn_s_setprio(1);
    #pragma unroll
    for (int mi = 0; mi < 4; ++mi)
      #pragma unroll
      for (int ni = 0; ni < 4; ++ni)
        acc[mi][ni] = __builtin_amdgcn_mfma_f32_16x16x32_bf16(a_[mi], b_[ni], acc[mi][ni], 0, 0, 0);
    __builtin_amdgcn_s_setprio(0);
    __builtin_amdgcn_s_barrier();

    // q3: ks1, mi 4-7; stage B(t+2) kh0
    #pragma unroll
    for (int mi = 0; mi < 4; ++mi) a_[mi] = *(const v8s*)(Ab1 + aoff[mi + 4]);
    if (t + 2 < NT) stageB(t + 2, 0);
    asm volatile("s_waitcnt lgkmcnt(0)" ::: "memory");
    __builtin_amdgcn_sched_barrier(0);
    __builtin_amdgcn_s_setprio(1);
    #pragma unroll
    for (int mi = 0; mi < 4; ++mi)
      #pragma unroll
      for (int ni = 0; ni < 4; ++ni)
        acc[mi + 4][ni] = __builtin_amdgcn_mfma_f32_16x16x32_bf16(a_[mi], b_[ni], acc[mi + 4][ni], 0, 0, 0);
    __builtin_amdgcn_s_setprio(0);
    __builtin_amdgcn_s_barrier();
  }
  asm volatile("s_waitcnt vmcnt(0)" ::: "memory");

  if constexpr (EPI == EPI_STATS) {
    __shared__ float s_mx[1024], s_sm[1024];    // [256 rows][4 wn]
    __shared__ int   s_ax[1024];
    __syncthreads();
    #pragma unroll
    for (int mi = 0; mi < 8; ++mi) {
      #pragma unroll
      for (int r = 0; r < 4; ++r) {
        float v0 = acc[mi][0][r], v1 = acc[mi][1][r], v2 = acc[mi][2][r], v3 = acc[mi][3][r];
        float mx = v0; int ax = lc;
        if (v1 > mx) { mx = v1; ax = 16 + lc; }
        if (v2 > mx) { mx = v2; ax = 32 + lc; }
        if (v3 > mx) { mx = v3; ax = 48 + lc; }
        #pragma unroll
        for (int off = 1; off < 16; off <<= 1) {
          float om = __shfl_xor(mx, off); int oa = __shfl_xor(ax, off);
          if (om > mx || (om == mx && oa < ax)) { mx = om; ax = oa; }
        }
        float se = __expf(v0 - mx) + __expf(v1 - mx) + __expf(v2 - mx) + __expf(v3 - mx);
        #pragma unroll
        for (int off = 1; off < 16; off <<= 1) se += __shfl_xor(se, off);
        if (lc == 0) {
          int row = wm * 128 + mi * 16 + lq * 4 + r;
          s_mx[row * 4 + wn] = mx; s_sm[row * 4 + wn] = se; s_ax[row * 4 + wn] = wn * 64 + ax;
        }
      }
    }
    __syncthreads();
    if (tid < 256) {
      float gm = s_mx[tid * 4]; int ga = s_ax[tid * 4];
      #pragma unroll
      for (int w = 1; w < 4; ++w) {
        float m = s_mx[tid * 4 + w];
        if (m > gm) { gm = m; ga = s_ax[tid * 4 + w]; }
      }
      float gs = 0.f;
      #pragma unroll
      for (int w = 0; w < 4; ++w) gs += s_sm[tid * 4 + w] * __expf(s_mx[tid * 4 + w] - gm);
      v4f rec; rec[0] = gm; rec[1] = gs; rec[2] = __int_as_float(n0 + ga); rec[3] = 0.f;
      partials[(size_t)(m0 + tid) * nch + blockIdx.y] = rec;
    }
    return;
  } else {
    #pragma unroll
    for (int mi = 0; mi < 8; ++mi)
      #pragma unroll
      for (int ni = 0; ni < 4; ++ni)
        #pragma unroll
        for (int r = 0; r < 4; ++r) {
          int grow = m0 + wm * 128 + mi * 16 + lq * 4 + r;
          int gcol = n0 + wn * 64 + ni * 16 + lc;
          size_t idx = (size_t)grow * ldc + gcol;
          float vv = acc[mi][ni][r];
          if constexpr (EPI == EPI_BF16) {
            Cbf[idx] = f2bf(vv);
          } else {  // EPI_SILU
            float g = bf2f(Gaux[idx]);
            Cbf[idx] = f2bf(vv * g / (1.0f + __expf(-g)));
          }
        }
  }
}

// ---------------------------------------------------------------------------
// PIPELINED 128x128 GEMM bf16: BK=64, 4 waves, dbuf LDS (64 KiB -> 2 blk/CU),
// counted vmcnt, swizzled reads. A [M][K] (opt. AOMAP remap), B [N][ldb].
template <int ASRC, int EPI>
__launch_bounds__(256, 2)
__global__ void k_gemm4(const u16* __restrict__ Abf, const u16* __restrict__ Bbf,
                        u16* __restrict__ Cbf, float* __restrict__ Cf32,
                        const int* __restrict__ keepArr, RmsSrc rs, int K, int ldb, int ldc) {
  __shared__ __align__(16) u16 lds[2][16384];
  const int tid = threadIdx.x;
  const int lane = tid & 63, wid = tid >> 6;
  const int wm = wid >> 1, wn = wid & 1;
  const int lc = lane & 15, lq = lane >> 4;
  const int m0 = blockIdx.x * 128, n0 = blockIdx.y * 128;

  const u16* srcA[4]; const u16* srcB[4];
  #pragma unroll
  for (int i = 0; i < 4; ++i) {
    int s = i * 256 + tid;
    int row = s >> 3;
    int c3 = (s & 7) ^ (row & 7);
    int ar = m0 + row;
    if constexpr (ASRC == ASRC_AOMAP) ar = (ar >> 4) * 17 + 1 + (ar & 15);
    srcA[i] = Abf + (size_t)ar * K + c3 * 8;
    srcB[i] = Bbf + (size_t)(n0 + row) * ldb + c3 * 8;
  }

  v4f acc[4][4];
  #pragma unroll
  for (int i = 0; i < 4; ++i)
    #pragma unroll
    for (int j = 0; j < 4; ++j) acc[i][j] = (v4f){0.f, 0.f, 0.f, 0.f};

  const int sw = lc & 7;
  const int aoff0 = (((wm * 64 + lc) * 8 + 0 + lq) ^ sw) * 8;
  const int aoff1 = (((wm * 64 + lc) * 8 + 4 + lq) ^ sw) * 8;
  const int boff0 = (((wn * 64 + lc) * 8 + 0 + lq) ^ sw) * 8;
  const int boff1 = (((wn * 64 + lc) * 8 + 4 + lq) ^ sw) * 8;

  auto stageTo = [&](int b) {
    u16* dA = &lds[b][0] + wid * 512;
    u16* dB = &lds[b][8192] + wid * 512;
    #pragma unroll
    for (int i = 0; i < 4; ++i) { gload16(dA + i * 2048, srcA[i]); srcA[i] += 64; }
    #pragma unroll
    for (int i = 0; i < 4; ++i) { gload16(dB + i * 2048, srcB[i]); srcB[i] += 64; }
  };

  stageTo(0);
  const int NT = K >> 6;
  for (int t = 0; t < NT; ++t) {
    const int cur = t & 1;
    if (t + 1 < NT) {
      stageTo(cur ^ 1);
      asm volatile("s_waitcnt vmcnt(8)" ::: "memory");
    } else {
      asm volatile("s_waitcnt vmcnt(0)" ::: "memory");
    }
    __builtin_amdgcn_s_barrier();
    const u16* Ab = &lds[cur][0];
    const u16* Bb = &lds[cur][8192];
    v8s a0[4], a1[4], b0[4], b1[4];
    #pragma unroll
    for (int mi = 0; mi < 4; ++mi) a0[mi] = *(const v8s*)(Ab + aoff0 + mi * 1024);
    #pragma unroll
    for (int ni = 0; ni < 4; ++ni) b0[ni] = *(const v8s*)(Bb + boff0 + ni * 1024);
    #pragma unroll
    for (int mi = 0; mi < 4; ++mi) a1[mi] = *(const v8s*)(Ab + aoff1 + mi * 1024);
    #pragma unroll
    for (int ni = 0; ni < 4; ++ni) b1[ni] = *(const v8s*)(Bb + boff1 + ni * 1024);
    __builtin_amdgcn_s_setprio(1);
    #pragma unroll
    for (int mi = 0; mi < 4; ++mi)
      #pragma unroll
      for (int ni = 0; ni < 4; ++ni)
        acc[mi][ni] = __builtin_amdgcn_mfma_f32_16x16x32_bf16(a0[mi], b0[ni], acc[mi][ni], 0, 0, 0);
    __builtin_amdgcn_s_setprio(0);
    asm volatile("s_waitcnt lgkmcnt(0)" ::: "memory");
    __builtin_amdgcn_sched_barrier(0);
    __builtin_amdgcn_s_barrier();
    __builtin_amdgcn_s_setprio(1);
    #pragma unroll
    for (int mi = 0; mi < 4; ++mi)
      #pragma unroll
      for (int ni = 0; ni < 4; ++ni)
        acc[mi][ni] = __builtin_amdgcn_mfma_f32_16x16x32_bf16(a1[mi], b1[ni], acc[mi][ni], 0, 0, 0);
    __builtin_amdgcn_s_setprio(0);
  }

  #pragma unroll
  for (int mi = 0; mi < 4; ++mi)
    #pragma unroll
    for (int ni = 0; ni < 4; ++ni)
      #pragma unroll
      for (int r = 0; r < 4; ++r) {
        int grow = m0 + wm * 64 + mi * 16 + lq * 4 + r;
        int gcol = n0 + wn * 64 + ni * 16 + lc;
        size_t idx = (size_t)grow * ldc + gcol;
        float vv = acc[mi][ni][r];
        if constexpr (EPI == EPI_BF16) {
          Cbf[idx] = f2bf(vv);
        } else if constexpr (EPI == EPI_OEMB) {
          int t_ = grow & 15, bn = grow >> 4;
          int tok = (t_ == 0) ? rs.ftok[bn] : cMASK;
          float kf = (float)keepArr[bn];
          Cf32[idx] = rs.emb[(size_t)tok * cD + gcol] + vv * kf;
        } else {  // EPI_DOWNACC
          Cf32[idx] += vv;
        }
      }
}

// ---------------------------------------------------------------------------
// FALLBACK GEMM (round-3): fp32 B converted during staging.
template <int ASRC, int BLAYOUT, int EPI>
__launch_bounds__(256)
__global__ void k_gemm(const u16* __restrict__ Abf, const float* __restrict__ Bw,
                       u16* Cbf, float* Cf32, const u16* Gaux,
                       const int* __restrict__ keepArr, v4f* __restrict__ partials,
                       RmsSrc rs, int K, int ldb, int ldc) {
  __shared__ __align__(16) u16 As[128][40];
  __shared__ __align__(16) u16 Bs[128][40];
  const int tid = threadIdx.x;
  const int m0 = blockIdx.x * 128, n0 = blockIdx.y * 128;
  const int lane = tid & 63, wid = tid >> 6;
  const int wm = wid >> 1, wn = wid & 1;
  const int lc = lane & 15, lk8 = (lane >> 4) * 8;
  const int srow = tid >> 2, sk8 = (tid & 3) * 8;
  v4f acc[4][4];
  #pragma unroll
  for (int i = 0; i < 4; ++i)
    #pragma unroll
    for (int j = 0; j < 4; ++j) acc[i][j] = (v4f){0.f, 0.f, 0.f, 0.f};

  for (int kt = 0; kt < K; kt += 32) {
    __syncthreads();
    for (int mm = srow; mm < 128; mm += 64) {
      if constexpr (ASRC == ASRC_BF16) {
        *(v8s*)&As[mm][sk8] = *(const v8s*)(Abf + (size_t)(m0 + mm) * K + kt + sk8);
      } else if constexpr (ASRC == ASRC_AOMAP) {
        int m = m0 + mm, bn = m >> 4, t = m & 15;
        *(v8s*)&As[mm][sk8] = *(const v8s*)(Abf + (size_t)(bn * 17 + 1 + t) * K + kt + sk8);
      } else {
        int R = m0 + mm;
        int j = R % 17, bn = R / 17, b = bn >> 7;
        const float* src; const float* nw;
        if (j == 0) { src = rs.hs + ((size_t)b * cS + rs.cpos[bn]) * cD; nw = rs.nchs; }
        else {
          int tok = (j == 1) ? rs.ftok[bn] : cMASK;
          src = rs.emb + (size_t)tok * cD; nw = rs.nattn;
        }
        float inv = rs.rowinv[R];
        const v4f* sp = (const v4f*)(src + kt + sk8);
        const v4f* np_ = (const v4f*)(nw + kt + sk8);
        v4f s0 = sp[0], s1 = sp[1], w0 = np_[0], w1 = np_[1];
        v8s pk;
        #pragma unroll
        for (int e = 0; e < 4; ++e) pk[e] = (short)f2bf(s0[e] * inv * w0[e]);
        #pragma unroll
        for (int e = 0; e < 4; ++e) pk[4 + e] = (short)f2bf(s1[e] * inv * w1[e]);
        *(v8s*)&As[mm][sk8] = pk;
      }
    }
    if constexpr (BLAYOUT == 1) {
      for (int nn = srow; nn < 128; nn += 64) {
        const v4f* bp = (const v4f*)(Bw + (size_t)(n0 + nn) * ldb + kt + sk8);
        v4f b0 = bp[0], b1 = bp[1];
        v8s pk;
        #pragma unroll
        for (int e = 0; e < 4; ++e) { pk[e] = (short)f2bf(b0[e]); pk[4 + e] = (short)f2bf(b1[e]); }
        *(v8s*)&Bs[nn][sk8] = pk;
      }
    } else {
      const int bn_ = tid & 127, kq = tid >> 7;
      for (int kk = kq; kk < 8; kk += 2) {
        const int k4 = kk * 4;
        const float* bp = Bw + (size_t)(kt + k4) * ldb + n0 + bn_;
        v4u pk;
        #pragma unroll
        for (int e = 0; e < 4; ++e) pk[e] = f2bf(bp[(size_t)e * ldb]);
        *(v4u*)&Bs[bn_][k4] = pk;
      }
    }
    __syncthreads();
    v8s af[4], bf_[4];
    #pragma unroll
    for (int i = 0; i < 4; ++i) af[i] = *(const v8s*)&As[wm * 64 + i * 16 + lc][lk8];
    #pragma unroll
    for (int i = 0; i < 4; ++i) bf_[i] = *(const v8s*)&Bs[wn * 64 + i * 16 + lc][lk8];
    #pragma unroll
    for (int mi = 0; mi < 4; ++mi)
      #pragma unroll
      for (int ni = 0; ni < 4; ++ni)
        acc[mi][ni] = __builtin_amdgcn_mfma_f32_16x16x32_bf16(af[mi], bf_[ni], acc[mi][ni], 0, 0, 0);
  }

  if constexpr (EPI == EPI_STATS) {
    __shared__ float s_mx[128][2], s_sm[128][2];
    __shared__ int s_ax[128][2];
    #pragma unroll
    for (int mi = 0; mi < 4; ++mi) {
      #pragma unroll
      for (int r = 0; r < 4; ++r) {
        float v0 = acc[mi][0][r], v1 = acc[mi][1][r], v2 = acc[mi][2][r], v3 = acc[mi][3][r];
        float mx = v0; int ax = lc;
        if (v1 > mx) { mx = v1; ax = 16 + lc; }
        if (v2 > mx) { mx = v2; ax = 32 + lc; }
        if (v3 > mx) { mx = v3; ax = 48 + lc; }
        #pragma unroll
        for (int off = 1; off < 16; off <<= 1) {
          float om = __shfl_xor(mx, off); int oa = __shfl_xor(ax, off);
          if (om > mx || (om == mx && oa < ax)) { mx = om; ax = oa; }
        }
        float se = __expf(v0 - mx) + __expf(v1 - mx) + __expf(v2 - mx) + __expf(v3 - mx);
        #pragma unroll
        for (int off = 1; off < 16; off <<= 1) se += __shfl_xor(se, off);
        if (lc == 0) {
          int lr = wm * 64 + mi * 16 + (lane >> 4) * 4 + r;
          s_mx[lr][wn] = mx; s_sm[lr][wn] = se; s_ax[lr][wn] = wn * 64 + ax;
        }
      }
    }
    __syncthreads();
    if (tid < 128) {
      float ma = s_mx[tid][0], mb = s_mx[tid][1];
      float gm = fmaxf(ma, mb);
      float gs = s_sm[tid][0] * __expf(ma - gm) + s_sm[tid][1] * __expf(mb - gm);
      int ga = (ma >= mb) ? s_ax[tid][0] : s_ax[tid][1];
      v4f rec; rec[0] = gm; rec[1] = gs; rec[2] = __int_as_float(n0 + ga); rec[3] = 0.f;
      partials[(size_t)(m0 + tid) * NCH + blockIdx.y] = rec;
    }
    return;
  } else {
    #pragma unroll
    for (int mi = 0; mi < 4; ++mi)
      #pragma unroll
      for (int ni = 0; ni < 4; ++ni)
        #pragma unroll
        for (int r = 0; r < 4; ++r) {
          int grow = m0 + wm * 64 + mi * 16 + (lane >> 4) * 4 + r;
          int gcol = n0 + wn * 64 + ni * 16 + lc;
          size_t idx = (size_t)grow * ldc + gcol;
          float vv = acc[mi][ni][r];
          if constexpr (EPI == EPI_BF16) {
            Cbf[idx] = f2bf(vv);
          } else if constexpr (EPI == EPI_SILU) {
            float g = bf2f(Gaux[idx]);
            Cbf[idx] = f2bf(vv * g / (1.0f + __expf(-g)));
          } else if constexpr (EPI == EPI_OEMB) {
            int t = grow & 15, bn = grow >> 4;
            int tok = (t == 0) ? rs.ftok[bn] : cMASK;
            float kf = (float)keepArr[bn];
            Cf32[idx] = rs.emb[(size_t)tok * cD + gcol] + vv * kf;
          } else {
            Cf32[idx] += vv;
          }
        }
  }
}

// ---------------------------------------------------------------------------
__global__ void k_rope(u16* __restrict__ qb, u16* __restrict__ kb,
                       const int* __restrict__ anchors, const int* __restrict__ cpos) {
  int r = blockIdx.x;
  int which = (r >= MKV);
  int rr = which ? r - MKV : r;
  int j = rr % 17, bn = rr / 17;
  if (!which && j == 0) return;
  u16* buf = which ? kb : qb;
  int pos = (which && j == 0) ? cpos[bn] : (anchors[bn] + j - 1);
  float fp = (float)pos;
  for (int p = threadIdx.x; p < cH * 64; p += 256) {
    int h = p >> 6, i = p & 63;
    size_t base = (size_t)rr * cD + h * cHD;
    float x1 = bf2f(buf[base + i]);
    float x2 = bf2f(buf[base + 64 + i]);
    float freq = powf(10000.0f, -((float)(2 * i)) / 128.0f);
    float ang = fp * freq;
    float sn = sinf(ang), cn = cosf(ang);
    buf[base + i]      = f2bf(x1 * cn - x2 * sn);
    buf[base + 64 + i] = f2bf(x2 * cn + x1 * sn);
  }
}

__global__ void k_attn(u16* __restrict__ qb, const u16* __restrict__ kb,
                       const u16* __restrict__ vb) {
  int blk = blockIdx.x;
  int h = blk % cH, bn = blk / cH;
  __shared__ float qs[16][128], ks[17][128], vs[17][128], ps[16][18];
  int lane = threadIdx.x;
  for (int e = lane; e < 16 * 128; e += 64) {
    int r = e >> 7, d = e & 127;
    qs[r][d] = bf2f(qb[((size_t)(bn * 17 + 1 + r)) * cD + h * cHD + d]);
  }
  for (int e = lane; e < 17 * 128; e += 64) {
    int r = e >> 7, d = e & 127;
    ks[r][d] = bf2f(kb[((size_t)(bn * 17 + r)) * cD + h * cHD + d]);
    vs[r][d] = bf2f(vb[((size_t)(bn * 17 + r)) * cD + h * cHD + d]);
  }
  __syncthreads();
  for (int e = lane; e < 16 * 17; e += 64) {
    int qi = e / 17, ki = e % 17;
    float s = 0.f;
    for (int d = 0; d < 128; ++d) s += qs[qi][d] * ks[ki][d];
    ps[qi][ki] = s * 0.08838834764831845f;
  }
  __syncthreads();
  if (lane < 16) {
    float m = -3e38f;
    for (int kk = 0; kk < 17; ++kk) m = fmaxf(m, ps[lane][kk]);
    float s = 0.f;
    for (int kk = 0; kk < 17; ++kk) { float e_ = __expf(ps[lane][kk] - m); ps[lane][kk] = e_; s += e_; }
    float is = 1.0f / s;
    for (int kk = 0; kk < 17; ++kk) ps[lane][kk] *= is;
  }
  __syncthreads();
  for (int e = lane; e < 16 * 128; e += 64) {
    int qi = e >> 7, d = e & 127;
    float s = 0.f;
    for (int kk = 0; kk < 17; ++kk) s += ps[qi][kk] * vs[kk][d];
    qb[((size_t)(bn * 17 + 1 + qi)) * cD + h * cHD + d] = f2bf(s);
  }
}

__global__ void k_tgt(const u16* __restrict__ hout, const float* __restrict__ Wlm,
                      const int* __restrict__ ids, const int* __restrict__ anchors,
                      int* __restrict__ tgt_tok, float* __restrict__ tgt_logit) {
  int w = threadIdx.x >> 6, lane = threadIdx.x & 63;
  int m = blockIdx.x * 4 + w;
  int bn = m >> 4, t = m & 15, b = bn / cNA;
  int label = anchors[bn] + t;
  int sl = (label < cS - 1) ? label : (cS - 1);
  int tok = ids[(size_t)b * cS + sl];
  const u16* hr = hout + (size_t)m * cD;
  const float* wr = Wlm + (size_t)tok * cD;
  float s = 0.f;
  for (int d = lane; d < cD; d += 64) s += bf2f(hr[d]) * wr[d];
  s = waveSum(s);
  if (lane == 0) { tgt_tok[m] = tok; tgt_logit[m] = s; }
}

__global__ void k_combine(const v4f* __restrict__ partials, const int* __restrict__ tgt_tok,
                          const float* __restrict__ tgt_logit, const int* __restrict__ keepArr,
                          const int* __restrict__ anchors, const float* __restrict__ lmask,
                          float* __restrict__ tokOut, int nch) {
  int m = blockIdx.x;
  int tid = threadIdx.x, lane = tid & 63, w = tid >> 6;
  float cm = -3.0e38f, cs = 0.f; int ca = 0x7fffffff;
  if (tid < nch) {
    v4f rec = partials[(size_t)m * nch + tid];
    cm = rec[0]; cs = rec[1]; ca = __float_as_int(rec[2]);
  }
  float gm = cm; int ga = ca;
  #pragma unroll
  for (int off = 1; off < 64; off <<= 1) {
    float om = __shfl_xor(gm, off); int oa = __shfl_xor(ga, off);
    if (om > gm || (om == gm && oa < ga)) { gm = om; ga = oa; }
  }
  __shared__ float wmx[4]; __shared__ int wax[4]; __shared__ float wsm[4];
  if (lane == 0) { wmx[w] = gm; wax[w] = ga; }
  __syncthreads();
  if (tid == 0) {
    for (int i = 1; i < 4; ++i)
      if (wmx[i] > wmx[0] || (wmx[i] == wmx[0] && wax[i] < wax[0])) { wmx[0] = wmx[i]; wax[0] = wax[i]; }
  }
  __syncthreads();
  gm = wmx[0]; ga = wax[0];
  float s = (tid < nch) ? cs * __expf(cm - gm) : 0.f;
  s = waveSum(s);
  if (lane == 0) wsm[w] = s;
  __syncthreads();
  if (tid == 0) {
    float gs = wsm[0] + wsm[1] + wsm[2] + wsm[3];
    float logZ = gm + logf(gs);
    int bn = m >> 4, t = m & 15, b = bn / cNA;
    int label = anchors[bn] + t;
    int sl = (label < cS - 1) ? label : (cS - 1);
    float wgt = (float)keepArr[bn] * ((t > 0) ? 1.f : 0.f) * ((label < cS) ? 1.f : 0.f) *
                lmask[(size_t)b * cS + sl];
    float lp = tgt_logit[m] - logZ;
    int tg = tgt_tok[m];
    tokOut[m * 4 + 0] = lp * wgt;
    tokOut[m * 4 + 1] = wgt;
    tokOut[m * 4 + 2] = ((ga == tg) && (wgt > 0.5f)) ? 1.f : 0.f;
    tokOut[m * 4 + 3] = 0.f;
  }
}

__global__ void k_final(const float* __restrict__ tokOut, float* __restrict__ outp) {
  int tid = threadIdx.x;
  float swl = 0.f, sw = 0.f, sm = 0.f;
  for (int m = tid; m < MTOK; m += 256) {
    swl += tokOut[m * 4 + 0];
    sw  += tokOut[m * 4 + 1];
    sm  += tokOut[m * 4 + 2];
  }
  swl = waveSum(swl); sw = waveSum(sw); sm = waveSum(sm);
  __shared__ float r0[4], r1[4], r2[4];
  int lane = tid & 63, w = tid >> 6;
  if (lane == 0) { r0[w] = swl; r1[w] = sw; r2[w] = sm; }
  __syncthreads();
  if (tid == 0) {
    float a = r0[0] + r0[1] + r0[2] + r0[3];
    float b = r1[0] + r1[1] + r1[2] + r1[3];
    float c = r2[0] + r2[1] + r2[2] + r2[3];
    float denom = b + 1e-6f;
    float loss = -a / denom;
    float acc  = c / denom;
    if (b == 0.0f) loss = -300.0f;
    outp[0] = loss;
    outp[1] = acc;
  }
}

__global__ void k_heartbeat(float* outp) {
  if (threadIdx.x == 0) { outp[0] = -55.0f; outp[1] = -55.0f; }
}
__global__ void k_sentinel(float* outp) {
  if (threadIdx.x == 0) { outp[0] = -777.0f; outp[1] = -777.0f; }
}

// ---------------------------------------------------------------------------
extern "C" void kernel_launch(void* const* d_in, const int* in_sizes, int n_in,
                              void* d_out, int out_size, void* d_ws, size_t ws_size,
                              hipStream_t stream) {
  const int*   ids   = (const int*)  d_in[0];
  const float* hs    = (const float*)d_in[1];
  const float* lmask = (const float*)d_in[2];
  const float* rv    = (const float*)d_in[3];
  const float* emb   = (const float*)d_in[4];
  const float* wlm   = (const float*)d_in[5];
  const float* wq    = (const float*)d_in[6];
  const float* wk    = (const float*)d_in[7];
  const float* wv    = (const float*)d_in[8];
  const float* wo    = (const float*)d_in[9];
  const float* wg    = (const float*)d_in[10];
  const float* wu    = (const float*)d_in[11];
  const float* wd    = (const float*)d_in[12];
  const float* nattn = (const float*)d_in[13];
  const float* nmlp  = (const float*)d_in[14];
  const float* nout  = (const float*)d_in[15];
  const float* nchs  = (const float*)d_in[16];
  (void)in_sizes; (void)n_in; (void)out_size;

  float* outp = (float*)d_out;
  k_heartbeat<<<dim3(1), 64, 0, stream>>>(outp);

  char* wsb = (char*)d_ws;
  size_t off = 0;
  auto alloc = [&](size_t bytes) -> void* {
    void* p = wsb + off;
    off = (off + bytes + 255) & ~(size_t)255;
    return p;
  };
  int*   anchors = (int*)  alloc((size_t)cB * cNA * 4);
  int*   keepA   = (int*)  alloc((size_t)cB * cNA * 4);
  int*   ftok    = (int*)  alloc((size_t)cB * cNA * 4);
  int*   cpos    = (int*)  alloc((size_t)cB * cNA * 4);
  int*   self    = (int*)  alloc((size_t)cB * NCAND * 4);
  float* rowinv  = (float*)alloc((size_t)MKV * 4);
  int*   ttok    = (int*)  alloc((size_t)MTOK * 4);
  float* tlogit  = (float*)alloc((size_t)MTOK * 4);
  float* tokOut  = (float*)alloc((size_t)MTOK * 4 * 4);

  const size_t szQ  = (size_t)MKV * cD * 2;           // 17.8 MB (q/attn-out/h/h_out)
  const size_t szX  = (size_t)MTOK * cD * 4;          // 33.6 MB (fp32 residual)
  u16* qb = (u16*)alloc(szQ);
  const size_t a1off = off;

  RmsSrc rs{hs, emb, nattn, nchs, rowinv, ftok, cpos};

  // common head
  k_select <<<dim3(cB * 16), 256, 0, stream>>>(lmask, rv, self);
  k_anchors<<<dim3(cB),      256, 0, stream>>>(lmask, self, ids, anchors, keepA, ftok, cpos);

  // ---------------- fast tier
  const size_t szKV   = szQ;
  const size_t szCbuf = (size_t)MTOK * 4096 * 2;      // CW = 4096
  size_t kvb_off  = a1off;
  size_t a1f_off  = (kvb_off + szKV + 255) & ~(size_t)255;
  size_t a1f_sz   = 2 * szQ > (szX + szCbuf) ? 2 * szQ : (szX + szCbuf);  // 67 MB
  size_t wreg_off = (a1f_off + a1f_sz + 255) & ~(size_t)255;
  size_t wreg_sz  = (size_t)cV * cD * 2;              // 131 MB (largest stage)
  size_t need_fast = wreg_off + wreg_sz;

  if (need_fast <= ws_size) {
    u16*   kvb   = (u16*)(wsb + kvb_off);
    u16*   kb    = (u16*)(wsb + a1f_off);
    u16*   vb    = (u16*)(wsb + a1f_off + szQ);
    float* xb    = (float*)(wsb + a1f_off);
    u16*   cbuf  = (u16*)(wsb + a1f_off + szX);
    v4f*   parts = (v4f*)(wsb + a1f_off);
    u16*   hb    = qb;
    u16*   houtb = qb;
    u16*   wT    = (u16*)(wsb + wreg_off);
    const size_t szDD = (size_t)cD * cD;
    u16* wqT = wT;            u16* wkT = wT + szDD;
    u16* wvT = wT + 2 * szDD; u16* woT = wT + 3 * szDD;
    const size_t szDF = (size_t)cD * cDFF;
    u16* wgT = wT; u16* wuT = wT + szDF; u16* wdT = wT + 2 * szDF;
    u16* wlmT = wT;

    k_build2<<<dim3(MKV), 256, 0, stream>>>(hs, emb, nattn, nchs, ftok, cpos, kvb);

    k_tconv<<<dim3(32, 32), 256, 0, stream>>>(wq, wqT, cD, cD);
    k_tconv<<<dim3(32, 32), 256, 0, stream>>>(wk, wkT, cD, cD);
    k_tconv<<<dim3(32, 32), 256, 0, stream>>>(wv, wvT, cD, cD);
    k_tconv<<<dim3(32, 32), 256, 0, stream>>>(wo, woT, cD, cD);

    k_gemm4<ASRC_BF16, EPI_BF16><<<dim3(MKV / 128, cD / 128), 256, 0, stream>>>(
        kvb, wqT, qb, nullptr, nullptr, rs, cD, cD, cD);
    k_gemm4<ASRC_BF16, EPI_BF16><<<dim3(MKV / 128, cD / 128), 256, 0, stream>>>(
        kvb, wkT, kb, nullptr, nullptr, rs, cD, cD, cD);
    k_gemm4<ASRC_BF16, EPI_BF16><<<dim3(MKV / 128, cD / 128), 256, 0, stream>>>(
        kvb, wvT, vb, nullptr, nullptr, rs, cD, cD, cD);

    k_rope<<<dim3(2 * MKV), 256, 0, stream>>>(qb, kb, anchors, cpos);
    k_attn<<<dim3(cB * cNA * cH), 64, 0, stream>>>(qb, kb, vb);

    k_gemm4<ASRC_AOMAP, EPI_OEMB><<<dim3(MTOK / 128, cD / 128), 256, 0, stream>>>(
        qb, woT, nullptr, xb, keepA, rs, cD, cD, cD);

    k_rms<<<dim3(MTOK), 256, 0, stream>>>(xb, nmlp, hb);

    k_tconv<<<dim3(128, 32), 256, 0, stream>>>(wg, wgT, cD, cDFF);
    k_tconv<<<dim3(128, 32), 256, 0, stream>>>(wu, wuT, cD, cDFF);
    k_tconv<<<dim3(32, 128), 256, 0, stream>>>(wd, wdT, cDFF, cD);

    for (int cb = 0; cb < cDFF; cb += 4096) {
      k_gemm6<EPI_BF16><<<dim3(MTOK / 256, 16), 512, 0, stream>>>(
          hb, wgT + (size_t)cb * cD, cbuf, nullptr, nullptr, cD, 4096, 0);
      k_gemm6<EPI_SILU><<<dim3(MTOK / 256, 16), 512, 0, stream>>>(
          hb, wuT + (size_t)cb * cD, cbuf, cbuf, nullptr, cD, 4096, 0);
      k_gemm4<ASRC_BF16, EPI_DOWNACC><<<dim3(MTOK / 128, cD / 128), 256, 0, stream>>>(
          cbuf, wdT + cb, nullptr, xb, nullptr, rs, 4096, cDFF, cD);
    }

    k_rms<<<dim3(MTOK), 256, 0, stream>>>(xb, nout, houtb);

    k_tgt<<<dim3(MTOK / 4), 256, 0, stream>>>(houtb, wlm, ids, anchors, ttok, tlogit);

    k_conv<<<dim3(2048), 256, 0, stream>>>(wlm, wlmT, (long)cV * cD);
    k_gemm6<EPI_STATS><<<dim3(MTOK / 256, NCH2), 512, 0, stream>>>(
        houtb, wlmT, nullptr, nullptr, parts, cD, 0, NCH2);

    k_combine<<<dim3(MTOK), 256, 0, stream>>>(parts, ttok, tlogit, keepA, anchors, lmask, tokOut, NCH2);
    k_final  <<<dim3(1), 256, 0, stream>>>(tokOut, outp);
    return;
  }

  // ---------------- fallback tier (round-3 path, fp32 weights in GEMM)
  const int cwopts[4] = {4096, 2048, 1024, 512};
  int CW = 0;
  for (int ci = 0; ci < 4; ++ci) {
    int cw = cwopts[ci];
    size_t cbufsz = (size_t)MTOK * cw * 2;
    size_t s1 = 2 * szQ;
    size_t s2 = szX + cbufsz;
    size_t sz = s1 > s2 ? s1 : s2;
    size_t pmin = (size_t)MTOK * NCH * 16;
    if (pmin > sz) sz = pmin;
    if (a1off + sz <= ws_size) { CW = cw; break; }
  }
  if (CW == 0) { k_sentinel<<<dim3(1), 64, 0, stream>>>(outp); return; }

  u16*   kb    = (u16*)(wsb + a1off);
  u16*   vb    = (u16*)(wsb + a1off + szQ);
  float* xb    = (float*)(wsb + a1off);
  u16*   cbuf  = (u16*)(wsb + a1off + szX);
  v4f*   parts = (v4f*)(wsb + a1off);
  u16*   hb    = qb;
  u16*   houtb = qb;

  k_rowinv<<<dim3(MKV), 256, 0, stream>>>(hs, emb, ftok, cpos, rowinv);

  k_gemm<ASRC_RMS, 0, EPI_BF16><<<dim3(MKV / 128, cD / 128), 256, 0, stream>>>(
      nullptr, wq, qb, nullptr, nullptr, nullptr, nullptr, rs, cD, cD, cD);
  k_gemm<ASRC_RMS, 0, EPI_BF16><<<dim3(MKV / 128, cD / 128), 256, 0, stream>>>(
      nullptr, wk, kb, nullptr, nullptr, nullptr, nullptr, rs, cD, cD, cD);
  k_gemm<ASRC_RMS, 0, EPI_BF16><<<dim3(MKV / 128, cD / 128), 256, 0, stream>>>(
      nullptr, wv, vb, nullptr, nullptr, nullptr, nullptr, rs, cD, cD, cD);

  k_rope<<<dim3(2 * MKV), 256, 0, stream>>>(qb, kb, anchors, cpos);
  k_attn<<<dim3(cB * cNA * cH), 64, 0, stream>>>(qb, kb, vb);

  k_gemm<ASRC_AOMAP, 0, EPI_OEMB><<<dim3(MTOK / 128, cD / 128), 256, 0, stream>>>(
      qb, wo, nullptr, xb, nullptr, keepA, nullptr, rs, cD, cD, cD);

  k_rms<<<dim3(MTOK), 256, 0, stream>>>(xb, nmlp, hb);

  for (int cb = 0; cb < cDFF; cb += CW) {
    k_gemm<ASRC_BF16, 0, EPI_BF16><<<dim3(MTOK / 128, CW / 128), 256, 0, stream>>>(
        hb, wg + cb, cbuf, nullptr, nullptr, nullptr, nullptr, rs, cD, cDFF, CW);
    k_gemm<ASRC_BF16, 0, EPI_SILU><<<dim3(MTOK / 128, CW / 128), 256, 0, stream>>>(
        hb, wu + cb, cbuf, nullptr, cbuf, nullptr, nullptr, rs, cD, cDFF, CW);
    k_gemm<ASRC_BF16, 0, EPI_DOWNACC><<<dim3(MTOK / 128, cD / 128), 256, 0, stream>>>(
        cbuf, wd + (size_t)cb * cD, nullptr, xb, nullptr, nullptr, nullptr, rs, CW, cD, cD);
  }

  k_rms<<<dim3(MTOK), 256, 0, stream>>>(xb, nout, houtb);

  k_tgt<<<dim3(MTOK / 4), 256, 0, stream>>>(houtb, wlm, ids, anchors, ttok, tlogit);
  k_gemm<ASRC_BF16, 1, EPI_STATS><<<dim3(MTOK / 128, cV / 128), 256, 0, stream>>>(
      houtb, wlm, nullptr, nullptr, nullptr, nullptr, parts, rs, cD, cD, 0);

  k_combine<<<dim3(MTOK), 256, 0, stream>>>(parts, ttok, tlogit, keepA, anchors, lmask, tokOut, NCH);
  k_final  <<<dim3(1), 256, 0, stream>>>(tokOut, outp);
}

// Round 11
// 1614.411 us; speedup vs baseline: 1.0261x; 1.0261x over previous
//
#include <hip/hip_runtime.h>
#include <math.h>

typedef unsigned short u16;
typedef unsigned char u8;
typedef short v8s __attribute__((ext_vector_type(8)));
typedef u16   v4u __attribute__((ext_vector_type(4)));
typedef float v4f __attribute__((ext_vector_type(4)));
typedef int   v2i __attribute__((ext_vector_type(2)));

#define DEVFN static __device__ __forceinline__

constexpr int cB = 2, cS = 4096, cD = 2048, cV = 32000, cH = 16, cHD = 128;
constexpr int cBS = 16, cNA = 128, cMASK = 31999, cDFF = 8192;
constexpr int NCAND = cS - cBS + 1;   // 4081 anchor candidates
constexpr int MTOK  = cB * cNA * cBS; // 4096 query tokens
constexpr int MKV   = cB * cNA * 17;  // 4352 kv rows (ctx + 16)
constexpr int NCH   = cV / 128;       // 250 vocab chunks (128-wide, fallback)
constexpr int NCH2  = cV / 256;       // 125 vocab chunks (256-wide, fast)

constexpr int EPI_BF16 = 0, EPI_SILU = 1, EPI_OEMB = 2, EPI_DOWNACC = 3, EPI_STATS = 4;
constexpr int ASRC_BF16 = 0, ASRC_RMS = 1, ASRC_AOMAP = 2;

struct RmsSrc {
  const float* hs; const float* emb; const float* nattn; const float* nchs;
  const float* rowinv; const int* ftok; const int* cpos;
};

DEVFN u16 f2bf(float f) {               // RNE fp32 -> bf16
  union { float f; unsigned u; } a; a.f = f;
  unsigned u = a.u;
  u = u + 0x7fffu + ((u >> 16) & 1u);
  return (u16)(u >> 16);
}
DEVFN float bf2f(u16 h) {
  union { unsigned u; float f; } a; a.u = ((unsigned)h) << 16;
  return a.f;
}
DEVFN float waveSum(float v) {
  #pragma unroll
  for (int o = 32; o >= 1; o >>= 1) v += __shfl_xor(v, o);
  return v;
}
DEVFN void gload16(void* lds, const void* g) {
  __builtin_amdgcn_global_load_lds(
      (const __attribute__((address_space(1))) unsigned*)g,
      (__attribute__((address_space(3))) unsigned*)lds, 16, 0, 0);
}
DEVFN int pack4fp8(float a, float b, float c, float d) {
  int p = __builtin_amdgcn_cvt_pk_fp8_f32(a, b, 0, 0);
  p = __builtin_amdgcn_cvt_pk_fp8_f32(c, d, p, 1);
  return p;
}

// ---------------------------------------------------------------------------
__global__ void k_select(const float* __restrict__ lmask, const float* __restrict__ rv_in,
                         int* __restrict__ self) {
  int b = blockIdx.x >> 4, chunk = blockIdx.x & 15;
  __shared__ float rvs[4096];
  for (int i = threadIdx.x; i < NCAND; i += 256) {
    bool valid = lmask[(size_t)b * cS + i] > 0.5f;
    rvs[i] = valid ? rv_in[(size_t)b * NCAND + i] : 2.0f;
  }
  __syncthreads();
  int i = chunk * 256 + threadIdx.x;
  if (i < NCAND) {
    float v = rvs[i];
    int rank = 0;
    for (int j = 0; j < NCAND; ++j) {
      float u = rvs[j];
      rank += (u < v) || (u == v && j < i);
    }
    self[(size_t)b * NCAND + i] = (rank < cNA) ? 1 : 0;
  }
}

__global__ void k_anchors(const float* __restrict__ lmask, const int* __restrict__ self,
                          const int* __restrict__ ids, int* __restrict__ anchors,
                          int* __restrict__ keepA, int* __restrict__ ftok, int* __restrict__ cpos) {
  int b = blockIdx.x;
  __shared__ int flags[4096];
  __shared__ int ssum[256];
  __shared__ int soff[257];
  __shared__ int abuf[cNA];
  for (int i = threadIdx.x; i < 4096; i += 256)
    flags[i] = (i < NCAND) ? (self[(size_t)b * NCAND + i] && (lmask[(size_t)b * cS + i] > 0.5f)) : 0;
  if (threadIdx.x < cNA) abuf[threadIdx.x] = 0;
  __syncthreads();
  int s = 0;
  #pragma unroll
  for (int j = 0; j < 16; ++j) s += flags[threadIdx.x * 16 + j];
  ssum[threadIdx.x] = s;
  __syncthreads();
  if (threadIdx.x == 0) {
    int a = 0;
    for (int t = 0; t < 256; ++t) { soff[t] = a; a += ssum[t]; }
    soff[256] = a;
  }
  __syncthreads();
  int nsel = soff[256];
  int p = soff[threadIdx.x];
  for (int j = 0; j < 16; ++j) {
    int i = threadIdx.x * 16 + j;
    if (flags[i]) { if (p < cNA) abuf[p] = i; ++p; }
  }
  __syncthreads();
  if (threadIdx.x < cNA) {
    int q = threadIdx.x;
    int kp = (q < nsel) ? 1 : 0;
    int a = kp ? abuf[q] : 0;
    anchors[b * cNA + q] = a;
    keepA[b * cNA + q] = kp;
    int av = a; if (av < 0) av = 0; if (av > cS - 1) av = cS - 1;
    int tok = ids[(size_t)b * cS + av];
    ftok[b * cNA + q] = kp ? tok : cMASK;
    cpos[b * cNA + q] = (a - 1 > 0) ? (a - 1) : 0;
  }
}

// per-kv-row 1/rms (fallback tier)
__global__ void k_rowinv(const float* __restrict__ hs, const float* __restrict__ emb,
                         const int* __restrict__ ftok, const int* __restrict__ cpos,
                         float* __restrict__ rowinv) {
  int r = blockIdx.x;
  int j = r % 17, bn = r / 17, b = bn >> 7;
  const float* src = (j == 0) ? hs + ((size_t)b * cS + cpos[bn]) * cD
                              : emb + (size_t)((j == 1) ? ftok[bn] : cMASK) * cD;
  float ss = 0.f;
  for (int d = threadIdx.x; d < cD; d += 256) { float v = src[d]; ss += v * v; }
  ss = waveSum(ss);
  __shared__ float red[4];
  if ((threadIdx.x & 63) == 0) red[threadIdx.x >> 6] = ss;
  __syncthreads();
  if (threadIdx.x == 0) {
    float tot = red[0] + red[1] + red[2] + red[3];
    rowinv[r] = 1.0f / sqrtf(tot / cD + 1e-6f);
  }
}

// kv_in = rms'd rows, materialized bf16 (fast tier). grid: MKV x 256
__global__ void k_build2(const float* __restrict__ hs, const float* __restrict__ emb,
                         const float* __restrict__ nattn, const float* __restrict__ nchs,
                         const int* __restrict__ ftok, const int* __restrict__ cpos,
                         u16* __restrict__ kv) {
  int r = blockIdx.x;
  int j = r % 17, bn = r / 17, b = bn >> 7;
  const float* src; const float* w;
  if (j == 0) { src = hs + ((size_t)b * cS + cpos[bn]) * cD; w = nchs; }
  else {
    int tok = (j == 1) ? ftok[bn] : cMASK;
    src = emb + (size_t)tok * cD; w = nattn;
  }
  float ss = 0.f;
  for (int d = threadIdx.x; d < cD; d += 256) { float v = src[d]; ss += v * v; }
  ss = waveSum(ss);
  __shared__ float red[4];
  if ((threadIdx.x & 63) == 0) red[threadIdx.x >> 6] = ss;
  __syncthreads();
  float tot = red[0] + red[1] + red[2] + red[3];
  float inv = 1.0f / sqrtf(tot / cD + 1e-6f);
  for (int d = threadIdx.x; d < cD; d += 256)
    kv[(size_t)r * cD + d] = f2bf(src[d] * inv * w[d]);
}

// RMS over fp32 rows -> bf16
__global__ void k_rms(const float* __restrict__ xin, const float* __restrict__ w,
                      u16* __restrict__ outp) {
  int m = blockIdx.x;
  const float* row = xin + (size_t)m * cD;
  float ss = 0.f;
  for (int d = threadIdx.x; d < cD; d += 256) { float v = row[d]; ss += v * v; }
  ss = waveSum(ss);
  __shared__ float red[4];
  if ((threadIdx.x & 63) == 0) red[threadIdx.x >> 6] = ss;
  __syncthreads();
  float tot = red[0] + red[1] + red[2] + red[3];
  float inv = 1.0f / sqrtf(tot / cD + 1e-6f);
  for (int d = threadIdx.x; d < cD; d += 256)
    outp[(size_t)m * cD + d] = f2bf(row[d] * inv * w[d]);
}

// fp32 -> fp8 e4m3 with scale (layout preserved). 8 elems/thread
__global__ void k_conv8(const float* __restrict__ in, u8* __restrict__ out, long n, float scale) {
  long i = ((long)blockIdx.x * 256 + threadIdx.x) * 8;
  long stride = (long)gridDim.x * 256 * 8;
  for (; i < n; i += stride) {
    v4f a = *(const v4f*)(in + i), b = *(const v4f*)(in + i + 4);
    v2i pk;
    pk[0] = pack4fp8(a[0] * scale, a[1] * scale, a[2] * scale, a[3] * scale);
    pk[1] = pack4fp8(b[0] * scale, b[1] * scale, b[2] * scale, b[3] * scale);
    *(v2i*)(out + i) = pk;
  }
}

// bf16 -> fp8 e4m3 (layout preserved). 8 elems/thread
__global__ void k_cvt8(const u16* __restrict__ in, u8* __restrict__ out, long n) {
  long i = ((long)blockIdx.x * 256 + threadIdx.x) * 8;
  long stride = (long)gridDim.x * 256 * 8;
  for (; i < n; i += stride) {
    v8s a = *(const v8s*)(in + i);
    v2i pk;
    pk[0] = pack4fp8(bf2f((u16)a[0]), bf2f((u16)a[1]), bf2f((u16)a[2]), bf2f((u16)a[3]));
    pk[1] = pack4fp8(bf2f((u16)a[4]), bf2f((u16)a[5]), bf2f((u16)a[6]), bf2f((u16)a[7]));
    *(v2i*)(out + i) = pk;
  }
}

// transpose-convert: W [K][N] fp32 -> WT [N][K] bf16. 64x64 tiles, grid (N/64, K/64)
__global__ void k_tconv(const float* __restrict__ W, u16* __restrict__ WT, int K, int N) {
  __shared__ u16 t[64][72];
  int n0 = blockIdx.x * 64, k0 = blockIdx.y * 64;
  int tid = threadIdx.x;
  int c4 = (tid & 15) * 4, r0 = tid >> 4;
  #pragma unroll
  for (int rr = 0; rr < 64; rr += 16) {
    int k = r0 + rr;
    v4f v = *(const v4f*)(W + (size_t)(k0 + k) * N + n0 + c4);
    #pragma unroll
    for (int e = 0; e < 4; ++e) t[c4 + e][k] = f2bf(v[e]);
  }
  __syncthreads();
  int n = tid >> 2, kq = (tid & 3) * 16;
  v8s o0, o1;
  #pragma unroll
  for (int e = 0; e < 8; ++e) { o0[e] = (short)t[n][kq + e]; o1[e] = (short)t[n][kq + 8 + e]; }
  *(v8s*)(WT + (size_t)(n0 + n) * K + k0 + kq) = o0;
  *(v8s*)(WT + (size_t)(n0 + n) * K + k0 + kq + 8) = o1;
}

// ---------------------------------------------------------------------------
// 8-PHASE PIPELINED 256x256 GEMM bf16 (round-10 verified). K-split half-tiles.
template <int EPI>
__launch_bounds__(512, 1)
__global__ void k_gemm6(const u16* __restrict__ Abf, const u16* __restrict__ Bbf,
                        u16* __restrict__ Cbf, const u16* __restrict__ Gaux,
                        v4f* __restrict__ partials, int K, int ldc, int nch) {
  __shared__ __align__(16) u16 lds[65536];
  const int tid = threadIdx.x;
  const int lane = tid & 63, wid = tid >> 6;
  const int wm = wid >> 2, wn = wid & 3;
  const int lc = lane & 15, lq = lane >> 4;
  const int m0 = blockIdx.x * 256, n0 = blockIdx.y * 256;

  const u16* srcA[2]; const u16* srcB[2];
  #pragma unroll
  for (int i = 0; i < 2; ++i) {
    int s = i * 512 + tid;
    int row = s >> 2;
    int c2 = (s & 3) ^ ((row >> 1) & 3);
    srcA[i] = Abf + (size_t)(m0 + row) * K + c2 * 8;
    srcB[i] = Bbf + (size_t)(n0 + row) * K + c2 * 8;
  }

  v4f acc[8][4];
  #pragma unroll
  for (int i = 0; i < 8; ++i)
    #pragma unroll
    for (int j = 0; j < 4; ++j) acc[i][j] = (v4f){0.f, 0.f, 0.f, 0.f};

  const int fsw = lq ^ ((lc >> 1) & 3);
  int aoff[8], boff[4];
  #pragma unroll
  for (int mi = 0; mi < 8; ++mi) aoff[mi] = ((wm * 128 + mi * 16 + lc) * 4 + fsw) * 8;
  #pragma unroll
  for (int ni = 0; ni < 4; ++ni) boff[ni] = ((wn * 64 + ni * 16 + lc) * 4 + fsw) * 8;

  auto stageA = [&](int t, int kh) {
    int reg = (t & 1) * 32768 + kh * 8192;
    int koff = t * 64 + kh * 32;
    #pragma unroll
    for (int i = 0; i < 2; ++i)
      gload16(&lds[reg + i * 4096 + wid * 512], srcA[i] + koff);
  };
  auto stageB = [&](int t, int kh) {
    int reg = (t & 1) * 32768 + 16384 + kh * 8192;
    int koff = t * 64 + kh * 32;
    #pragma unroll
    for (int i = 0; i < 2; ++i)
      gload16(&lds[reg + i * 4096 + wid * 512], srcB[i] + koff);
  };

  stageA(0, 0); stageB(0, 0);
  stageA(0, 1); stageB(0, 1);
  stageA(1, 0); stageB(1, 0);
  asm volatile("s_waitcnt vmcnt(8)" ::: "memory");
  __builtin_amdgcn_s_barrier();

  const int NT = K >> 6;
  for (int t = 0; t < NT; ++t) {
    const int bufb = (t & 1) * 32768;
    const u16* Ab0 = &lds[bufb];
    const u16* Ab1 = &lds[bufb + 8192];
    const u16* Bb0 = &lds[bufb + 16384];
    const u16* Bb1 = &lds[bufb + 24576];
    v8s a_[4], b_[4];

    #pragma unroll
    for (int ni = 0; ni < 4; ++ni) b_[ni] = *(const v8s*)(Bb0 + boff[ni]);
    #pragma unroll
    for (int mi = 0; mi < 4; ++mi) a_[mi] = *(const v8s*)(Ab0 + aoff[mi]);
    if (t + 1 < NT) stageA(t + 1, 1);
    asm volatile("s_waitcnt lgkmcnt(0)" ::: "memory");
    __builtin_amdgcn_sched_barrier(0);
    __builtin_amdgcn_s_setprio(1);
    #pragma unroll
    for (int mi = 0; mi < 4; ++mi)
      #pragma unroll
      for (int ni = 0; ni < 4; ++ni)
        acc[mi][ni] = __builtin_amdgcn_mfma_f32_16x16x32_bf16(a_[mi], b_[ni], acc[mi][ni], 0, 0, 0);
    __builtin_amdgcn_s_setprio(0);
    __builtin_amdgcn_s_barrier();

    #pragma unroll
    for (int mi = 0; mi < 4; ++mi) a_[mi] = *(const v8s*)(Ab0 + aoff[mi + 4]);
    if (t + 1 < NT) stageB(t + 1, 1);
    asm volatile("s_waitcnt lgkmcnt(0)" ::: "memory");
    __builtin_amdgcn_sched_barrier(0);
    __builtin_amdgcn_s_setprio(1);
    #pragma unroll
    for (int mi = 0; mi < 4; ++mi)
      #pragma unroll
      for (int ni = 0; ni < 4; ++ni)
        acc[mi + 4][ni] = __builtin_amdgcn_mfma_f32_16x16x32_bf16(a_[mi], b_[ni], acc[mi + 4][ni], 0, 0, 0);
    __builtin_amdgcn_s_setprio(0);
    if (t + 1 < NT) { asm volatile("s_waitcnt vmcnt(4)" ::: "memory"); }
    else            { asm volatile("s_waitcnt vmcnt(0)" ::: "memory"); }
    __builtin_amdgcn_s_barrier();

    #pragma unroll
    for (int ni = 0; ni < 4; ++ni) b_[ni] = *(const v8s*)(Bb1 + boff[ni]);
    #pragma unroll
    for (int mi = 0; mi < 4; ++mi) a_[mi] = *(const v8s*)(Ab1 + aoff[mi]);
    if (t + 2 < NT) stageA(t + 2, 0);
    asm volatile("s_waitcnt lgkmcnt(0)" ::: "memory");
    __builtin_amdgcn_sched_barrier(0);
    __builtin_amdgcn_s_setprio(1);
    #pragma unroll
    for (int mi = 0; mi < 4; ++mi)
      #pragma unroll
      for (int ni = 0; ni < 4; ++ni)
        acc[mi][ni] = __builtin_amdgcn_mfma_f32_16x16x32_bf16(a_[mi], b_[ni], acc[mi][ni], 0, 0, 0);
    __builtin_amdgcn_s_setprio(0);
    __builtin_amdgcn_s_barrier();

    #pragma unroll
    for (int mi = 0; mi < 4; ++mi) a_[mi] = *(const v8s*)(Ab1 + aoff[mi + 4]);
    if (t + 2 < NT) stageB(t + 2, 0);
    asm volatile("s_waitcnt lgkmcnt(0)" ::: "memory");
    __builtin_amdgcn_sched_barrier(0);
    __builtin_amdgcn_s_setprio(1);
    #pragma unroll
    for (int mi = 0; mi < 4; ++mi)
      #pragma unroll
      for (int ni = 0; ni < 4; ++ni)
        acc[mi + 4][ni] = __builtin_amdgcn_mfma_f32_16x16x32_bf16(a_[mi], b_[ni], acc[mi + 4][ni], 0, 0, 0);
    __builtin_amdgcn_s_setprio(0);
    __builtin_amdgcn_s_barrier();
  }
  asm volatile("s_waitcnt vmcnt(0)" ::: "memory");

  #pragma unroll
  for (int mi = 0; mi < 8; ++mi)
    #pragma unroll
    for (int ni = 0; ni < 4; ++ni)
      #pragma unroll
      for (int r = 0; r < 4; ++r) {
        int grow = m0 + wm * 128 + mi * 16 + lq * 4 + r;
        int gcol = n0 + wn * 64 + ni * 16 + lc;
        size_t idx = (size_t)grow * ldc + gcol;
        float vv = acc[mi][ni][r];
        if constexpr (EPI == EPI_BF16) {
          Cbf[idx] = f2bf(vv);
        } else {  // EPI_SILU
          float g = bf2f(Gaux[idx]);
          Cbf[idx] = f2bf(vv * g / (1.0f + __expf(-g)));
        }
      }
  (void)partials; (void)nch;
}

// ---------------------------------------------------------------------------
// 8-PHASE PIPELINED 256x256 GEMM fp8 e4m3 with STATS epilogue.
// K-split half-tiles of 256x32B; swizzle: 16B-chunk ^= (row>>2)&1 (involution,
// 2-way bank = free). Per-tile single vmcnt(4). logits = acc/64 (B pre-x64).
__launch_bounds__(512, 2)
__global__ void k_gemm7(const u8* __restrict__ A8, const u8* __restrict__ B8,
                        v4f* __restrict__ partials, int K, int nch) {
  // 64 KB: buf b at b*32768 B; A kh at +kh*8192; B kh at +16384+kh*8192
  __shared__ __align__(16) u8 lds8[65536];
  const int tid = threadIdx.x;
  const int lane = tid & 63, wid = tid >> 6;
  const int wm = wid >> 2, wn = wid & 3;        // per-wave out 128x64
  const int lc = lane & 15, lq = lane >> 4;
  const int m0 = blockIdx.x * 256, n0 = blockIdx.y * 256;

  // staging: thread covers (row = tid>>1, chunk_phys = tid&1) of a 256x32B half
  // logical chunk = (tid&1) ^ ((row>>2)&1)
  const u8* srcA; const u8* srcB;
  {
    int row = tid >> 1;
    int cl = (tid & 1) ^ ((row >> 2) & 1);
    srcA = A8 + (size_t)(m0 + row) * K + cl * 16;
    srcB = B8 + (size_t)(n0 + row) * K + cl * 16;
  }

  v4f acc[8][4];
  #pragma unroll
  for (int i = 0; i < 8; ++i)
    #pragma unroll
    for (int j = 0; j < 4; ++j) acc[i][j] = (v4f){0.f, 0.f, 0.f, 0.f};

  // fragment byte offsets within an 8192B half: row*32 + (lq ^ (((row>>2)&1)<<1))*8
  int aoff[8], boff[4];
  #pragma unroll
  for (int mi = 0; mi < 8; ++mi) {
    int row = wm * 128 + mi * 16 + lc;
    aoff[mi] = row * 32 + (lq ^ (((row >> 2) & 1) << 1)) * 8;
  }
  #pragma unroll
  for (int ni = 0; ni < 4; ++ni) {
    int row = wn * 64 + ni * 16 + lc;
    boff[ni] = row * 32 + (lq ^ (((row >> 2) & 1) << 1)) * 8;
  }

  auto stageA = [&](int t, int kh) {
    int reg = (t & 1) * 32768 + kh * 8192;
    gload16(&lds8[reg + wid * 1024], srcA + t * 64 + kh * 32);
  };
  auto stageB = [&](int t, int kh) {
    int reg = (t & 1) * 32768 + 16384 + kh * 8192;
    gload16(&lds8[reg + wid * 1024], srcB + t * 64 + kh * 32);
  };

  // prologue: 6 loads; wait first pair -> vmcnt(4)
  stageA(0, 0); stageB(0, 0);
  stageA(0, 1); stageB(0, 1);
  stageA(1, 0); stageB(1, 0);
  asm volatile("s_waitcnt vmcnt(4)" ::: "memory");
  __builtin_amdgcn_s_barrier();

  const int NT = K >> 6;
  for (int t = 0; t < NT; ++t) {
    const int bufb = (t & 1) * 32768;
    const u8* Ab0 = &lds8[bufb];
    const u8* Ab1 = &lds8[bufb + 8192];
    const u8* Bb0 = &lds8[bufb + 16384];
    const u8* Bb1 = &lds8[bufb + 24576];
    long long a_[4], b_[4];

    // q0: kh0, mi 0-3; stage A(t+1) kh1
    #pragma unroll
    for (int ni = 0; ni < 4; ++ni) b_[ni] = *(const long long*)(Bb0 + boff[ni]);
    #pragma unroll
    for (int mi = 0; mi < 4; ++mi) a_[mi] = *(const long long*)(Ab0 + aoff[mi]);
    if (t + 1 < NT) stageA(t + 1, 1);
    asm volatile("s_waitcnt lgkmcnt(0)" ::: "memory");
    __builtin_amdgcn_sched_barrier(0);
    __builtin_amdgcn_s_setprio(1);
    #pragma unroll
    for (int mi = 0; mi < 4; ++mi)
      #pragma unroll
      for (int ni = 0; ni < 4; ++ni)
        acc[mi][ni] = __builtin_amdgcn_mfma_f32_16x16x32_fp8_fp8(a_[mi], b_[ni], acc[mi][ni], 0, 0, 0);
    __builtin_amdgcn_s_setprio(0);
    __builtin_amdgcn_s_barrier();

    // q1: kh0, mi 4-7; stage B(t+1) kh1; single per-tile vmcnt
    #pragma unroll
    for (int mi = 0; mi < 4; ++mi) a_[mi] = *(const long long*)(Ab0 + aoff[mi + 4]);
    if (t + 1 < NT) stageB(t + 1, 1);
    asm volatile("s_waitcnt lgkmcnt(0)" ::: "memory");
    __builtin_amdgcn_sched_barrier(0);
    __builtin_amdgcn_s_setprio(1);
    #pragma unroll
    for (int mi = 0; mi < 4; ++mi)
      #pragma unroll
      for (int ni = 0; ni < 4; ++ni)
        acc[mi + 4][ni] = __builtin_amdgcn_mfma_f32_16x16x32_fp8_fp8(a_[mi], b_[ni], acc[mi + 4][ni], 0, 0, 0);
    __builtin_amdgcn_s_setprio(0);
    if (t + 1 < NT) { asm volatile("s_waitcnt vmcnt(4)" ::: "memory"); }
    else            { asm volatile("s_waitcnt vmcnt(0)" ::: "memory"); }
    __builtin_amdgcn_s_barrier();

    // q2: kh1, mi 0-3; stage A(t+2) kh0
    #pragma unroll
    for (int ni = 0; ni < 4; ++ni) b_[ni] = *(const long long*)(Bb1 + boff[ni]);
    #pragma unroll
    for (int mi = 0; mi < 4; ++mi) a_[mi] = *(const long long*)(Ab1 + aoff[mi]);
    if (t + 2 < NT) stageA(t + 2, 0);
    asm volatile("s_waitcnt lgkmcnt(0)" ::: "memory");
    __builtin_amdgcn_sched_barrier(0);
    __builtin_amdgcn_s_setprio(1);
    #pragma unroll
    for (int mi = 0; mi < 4; ++mi)
      #pragma unroll
      for (int ni = 0; ni < 4; ++ni)
        acc[mi][ni] = __builtin_amdgcn_mfma_f32_16x16x32_fp8_fp8(a_[mi], b_[ni], acc[mi][ni], 0, 0, 0);
    __builtin_amdgcn_s_setprio(0);
    __builtin_amdgcn_s_barrier();

    // q3: kh1, mi 4-7; stage B(t+2) kh0
    #pragma unroll
    for (int mi = 0; mi < 4; ++mi) a_[mi] = *(const long long*)(Ab1 + aoff[mi + 4]);
    if (t + 2 < NT) stageB(t + 2, 0);
    asm volatile("s_waitcnt lgkmcnt(0)" ::: "memory");
    __builtin_amdgcn_sched_barrier(0);
    __builtin_amdgcn_s_setprio(1);
    #pragma unroll
    for (int mi = 0; mi < 4; ++mi)
      #pragma unroll
      for (int ni = 0; ni < 4; ++ni)
        acc[mi + 4][ni] = __builtin_amdgcn_mfma_f32_16x16x32_fp8_fp8(a_[mi], b_[ni], acc[mi + 4][ni], 0, 0, 0);
    __builtin_amdgcn_s_setprio(0);
    __builtin_amdgcn_s_barrier();
  }
  asm volatile("s_waitcnt vmcnt(0)" ::: "memory");

  // undo the x64 weight scale
  #pragma unroll
  for (int mi = 0; mi < 8; ++mi)
    #pragma unroll
    for (int ni = 0; ni < 4; ++ni)
      acc[mi][ni] *= 0.015625f;

  __shared__ float s_mx[1024], s_sm[1024];
  __shared__ int   s_ax[1024];
  __syncthreads();
  #pragma unroll
  for (int mi = 0; mi < 8; ++mi) {
    #pragma unroll
    for (int r = 0; r < 4; ++r) {
      float v0 = acc[mi][0][r], v1 = acc[mi][1][r], v2 = acc[mi][2][r], v3 = acc[mi][3][r];
      float mx = v0; int ax = lc;
      if (v1 > mx) { mx = v1; ax = 16 + lc; }
      if (v2 > mx) { mx = v2; ax = 32 + lc; }
      if (v3 > mx) { mx = v3; ax = 48 + lc; }
      #pragma unroll
      for (int off = 1; off < 16; off <<= 1) {
        float om = __shfl_xor(mx, off); int oa = __shfl_xor(ax, off);
        if (om > mx || (om == mx && oa < ax)) { mx = om; ax = oa; }
      }
      float se = __expf(v0 - mx) + __expf(v1 - mx) + __expf(v2 - mx) + __expf(v3 - mx);
      #pragma unroll
      for (int off = 1; off < 16; off <<= 1) se += __shfl_xor(se, off);
      if (lc == 0) {
        int row = wm * 128 + mi * 16 + lq * 4 + r;
        s_mx[row * 4 + wn] = mx; s_sm[row * 4 + wn] = se; s_ax[row * 4 + wn] = wn * 64 + ax;
      }
    }
  }
  __syncthreads();
  if (tid < 256) {
    float gm = s_mx[tid * 4]; int ga = s_ax[tid * 4];
    #pragma unroll
    for (int w = 1; w < 4; ++w) {
      float m = s_mx[tid * 4 + w];
      if (m > gm) { gm = m; ga = s_ax[tid * 4 + w]; }
    }
    float gs = 0.f;
    #pragma unroll
    for (int w = 0; w < 4; ++w) gs += s_sm[tid * 4 + w] * __expf(s_mx[tid * 4 + w] - gm);
    v4f rec; rec[0] = gm; rec[1] = gs; rec[2] = __int_as_float(n0 + ga); rec[3] = 0.f;
    partials[(size_t)(m0 + tid) * nch + blockIdx.y] = rec;
  }
}

// ---------------------------------------------------------------------------
// PIPELINED 128x128 GEMM bf16: BK=64, 4 waves, dbuf LDS (2 blk/CU).
template <int ASRC, int EPI>
__launch_bounds__(256, 2)
__global__ void k_gemm4(const u16* __restrict__ Abf, const u16* __restrict__ Bbf,
                        u16* __restrict__ Cbf, float* __restrict__ Cf32,
                        const int* __restrict__ keepArr, RmsSrc rs, int K, int ldb, int ldc) {
  __shared__ __align__(16) u16 lds[2][16384];
  const int tid = threadIdx.x;
  const int lane = tid & 63, wid = tid >> 6;
  const int wm = wid >> 1, wn = wid & 1;
  const int lc = lane & 15, lq = lane >> 4;
  const int m0 = blockIdx.x * 128, n0 = blockIdx.y * 128;

  const u16* srcA[4]; const u16* srcB[4];
  #pragma unroll
  for (int i = 0; i < 4; ++i) {
    int s = i * 256 + tid;
    int row = s >> 3;
    int c3 = (s & 7) ^ (row & 7);
    int ar = m0 + row;
    if constexpr (ASRC == ASRC_AOMAP) ar = (ar >> 4) * 17 + 1 + (ar & 15);
    srcA[i] = Abf + (size_t)ar * K + c3 * 8;
    srcB[i] = Bbf + (size_t)(n0 + row) * ldb + c3 * 8;
  }

  v4f acc[4][4];
  #pragma unroll
  for (int i = 0; i < 4; ++i)
    #pragma unroll
    for (int j = 0; j < 4; ++j) acc[i][j] = (v4f){0.f, 0.f, 0.f, 0.f};

  const int sw = lc & 7;
  const int aoff0 = (((wm * 64 + lc) * 8 + 0 + lq) ^ sw) * 8;
  const int aoff1 = (((wm * 64 + lc) * 8 + 4 + lq) ^ sw) * 8;
  const int boff0 = (((wn * 64 + lc) * 8 + 0 + lq) ^ sw) * 8;
  const int boff1 = (((wn * 64 + lc) * 8 + 4 + lq) ^ sw) * 8;

  auto stageTo = [&](int b) {
    u16* dA = &lds[b][0] + wid * 512;
    u16* dB = &lds[b][8192] + wid * 512;
    #pragma unroll
    for (int i = 0; i < 4; ++i) { gload16(dA + i * 2048, srcA[i]); srcA[i] += 64; }
    #pragma unroll
    for (int i = 0; i < 4; ++i) { gload16(dB + i * 2048, srcB[i]); srcB[i] += 64; }
  };

  stageTo(0);
  const int NT = K >> 6;
  for (int t = 0; t < NT; ++t) {
    const int cur = t & 1;
    if (t + 1 < NT) {
      stageTo(cur ^ 1);
      asm volatile("s_waitcnt vmcnt(8)" ::: "memory");
    } else {
      asm volatile("s_waitcnt vmcnt(0)" ::: "memory");
    }
    __builtin_amdgcn_s_barrier();
    const u16* Ab = &lds[cur][0];
    const u16* Bb = &lds[cur][8192];
    v8s a0[4], a1[4], b0[4], b1[4];
    #pragma unroll
    for (int mi = 0; mi < 4; ++mi) a0[mi] = *(const v8s*)(Ab + aoff0 + mi * 1024);
    #pragma unroll
    for (int ni = 0; ni < 4; ++ni) b0[ni] = *(const v8s*)(Bb + boff0 + ni * 1024);
    #pragma unroll
    for (int mi = 0; mi < 4; ++mi) a1[mi] = *(const v8s*)(Ab + aoff1 + mi * 1024);
    #pragma unroll
    for (int ni = 0; ni < 4; ++ni) b1[ni] = *(const v8s*)(Bb + boff1 + ni * 1024);
    __builtin_amdgcn_s_setprio(1);
    #pragma unroll
    for (int mi = 0; mi < 4; ++mi)
      #pragma unroll
      for (int ni = 0; ni < 4; ++ni)
        acc[mi][ni] = __builtin_amdgcn_mfma_f32_16x16x32_bf16(a0[mi], b0[ni], acc[mi][ni], 0, 0, 0);
    __builtin_amdgcn_s_setprio(0);
    asm volatile("s_waitcnt lgkmcnt(0)" ::: "memory");
    __builtin_amdgcn_sched_barrier(0);
    __builtin_amdgcn_s_barrier();
    __builtin_amdgcn_s_setprio(1);
    #pragma unroll
    for (int mi = 0; mi < 4; ++mi)
      #pragma unroll
      for (int ni = 0; ni < 4; ++ni)
        acc[mi][ni] = __builtin_amdgcn_mfma_f32_16x16x32_bf16(a1[mi], b1[ni], acc[mi][ni], 0, 0, 0);
    __builtin_amdgcn_s_setprio(0);
  }

  #pragma unroll
  for (int mi = 0; mi < 4; ++mi)
    #pragma unroll
    for (int ni = 0; ni < 4; ++ni)
      #pragma unroll
      for (int r = 0; r < 4; ++r) {
        int grow = m0 + wm * 64 + mi * 16 + lq * 4 + r;
        int gcol = n0 + wn * 64 + ni * 16 + lc;
        size_t idx = (size_t)grow * ldc + gcol;
        float vv = acc[mi][ni][r];
        if constexpr (EPI == EPI_BF16) {
          Cbf[idx] = f2bf(vv);
        } else if constexpr (EPI == EPI_OEMB) {
          int t_ = grow & 15, bn = grow >> 4;
          int tok = (t_ == 0) ? rs.ftok[bn] : cMASK;
          float kf = (float)keepArr[bn];
          Cf32[idx] = rs.emb[(size_t)tok * cD + gcol] + vv * kf;
        } else {  // EPI_DOWNACC
          Cf32[idx] += vv;
        }
      }
}

// ---------------------------------------------------------------------------
// FALLBACK GEMM (round-3): fp32 B converted during staging.
template <int ASRC, int BLAYOUT, int EPI>
__launch_bounds__(256)
__global__ void k_gemm(const u16* __restrict__ Abf, const float* __restrict__ Bw,
                       u16* Cbf, float* Cf32, const u16* Gaux,
                       const int* __restrict__ keepArr, v4f* __restrict__ partials,
                       RmsSrc rs, int K, int ldb, int ldc) {
  __shared__ __align__(16) u16 As[128][40];
  __shared__ __align__(16) u16 Bs[128][40];
  const int tid = threadIdx.x;
  const int m0 = blockIdx.x * 128, n0 = blockIdx.y * 128;
  const int lane = tid & 63, wid = tid >> 6;
  const int wm = wid >> 1, wn = wid & 1;
  const int lc = lane & 15, lk8 = (lane >> 4) * 8;
  const int srow = tid >> 2, sk8 = (tid & 3) * 8;
  v4f acc[4][4];
  #pragma unroll
  for (int i = 0; i < 4; ++i)
    #pragma unroll
    for (int j = 0; j < 4; ++j) acc[i][j] = (v4f){0.f, 0.f, 0.f, 0.f};

  for (int kt = 0; kt < K; kt += 32) {
    __syncthreads();
    for (int mm = srow; mm < 128; mm += 64) {
      if constexpr (ASRC == ASRC_BF16) {
        *(v8s*)&As[mm][sk8] = *(const v8s*)(Abf + (size_t)(m0 + mm) * K + kt + sk8);
      } else if constexpr (ASRC == ASRC_AOMAP) {
        int m = m0 + mm, bn = m >> 4, t = m & 15;
        *(v8s*)&As[mm][sk8] = *(const v8s*)(Abf + (size_t)(bn * 17 + 1 + t) * K + kt + sk8);
      } else {
        int R = m0 + mm;
        int j = R % 17, bn = R / 17, b = bn >> 7;
        const float* src; const float* nw;
        if (j == 0) { src = rs.hs + ((size_t)b * cS + rs.cpos[bn]) * cD; nw = rs.nchs; }
        else {
          int tok = (j == 1) ? rs.ftok[bn] : cMASK;
          src = rs.emb + (size_t)tok * cD; nw = rs.nattn;
        }
        float inv = rs.rowinv[R];
        const v4f* sp = (const v4f*)(src + kt + sk8);
        const v4f* np_ = (const v4f*)(nw + kt + sk8);
        v4f s0 = sp[0], s1 = sp[1], w0 = np_[0], w1 = np_[1];
        v8s pk;
        #pragma unroll
        for (int e = 0; e < 4; ++e) pk[e] = (short)f2bf(s0[e] * inv * w0[e]);
        #pragma unroll
        for (int e = 0; e < 4; ++e) pk[4 + e] = (short)f2bf(s1[e] * inv * w1[e]);
        *(v8s*)&As[mm][sk8] = pk;
      }
    }
    if constexpr (BLAYOUT == 1) {
      for (int nn = srow; nn < 128; nn += 64) {
        const v4f* bp = (const v4f*)(Bw + (size_t)(n0 + nn) * ldb + kt + sk8);
        v4f b0 = bp[0], b1 = bp[1];
        v8s pk;
        #pragma unroll
        for (int e = 0; e < 4; ++e) { pk[e] = (short)f2bf(b0[e]); pk[4 + e] = (short)f2bf(b1[e]); }
        *(v8s*)&Bs[nn][sk8] = pk;
      }
    } else {
      const int bn_ = tid & 127, kq = tid >> 7;
      for (int kk = kq; kk < 8; kk += 2) {
        const int k4 = kk * 4;
        const float* bp = Bw + (size_t)(kt + k4) * ldb + n0 + bn_;
        v4u pk;
        #pragma unroll
        for (int e = 0; e < 4; ++e) pk[e] = f2bf(bp[(size_t)e * ldb]);
        *(v4u*)&Bs[bn_][k4] = pk;
      }
    }
    __syncthreads();
    v8s af[4], bf_[4];
    #pragma unroll
    for (int i = 0; i < 4; ++i) af[i] = *(const v8s*)&As[wm * 64 + i * 16 + lc][lk8];
    #pragma unroll
    for (int i = 0; i < 4; ++i) bf_[i] = *(const v8s*)&Bs[wn * 64 + i * 16 + lc][lk8];
    #pragma unroll
    for (int mi = 0; mi < 4; ++mi)
      #pragma unroll
      for (int ni = 0; ni < 4; ++ni)
        acc[mi][ni] = __builtin_amdgcn_mfma_f32_16x16x32_bf16(af[mi], bf_[ni], acc[mi][ni], 0, 0, 0);
  }

  if constexpr (EPI == EPI_STATS) {
    __shared__ float s_mx[128][2], s_sm[128][2];
    __shared__ int s_ax[128][2];
    #pragma unroll
    for (int mi = 0; mi < 4; ++mi) {
      #pragma unroll
      for (int r = 0; r < 4; ++r) {
        float v0 = acc[mi][0][r], v1 = acc[mi][1][r], v2 = acc[mi][2][r], v3 = acc[mi][3][r];
        float mx = v0; int ax = lc;
        if (v1 > mx) { mx = v1; ax = 16 + lc; }
        if (v2 > mx) { mx = v2; ax = 32 + lc; }
        if (v3 > mx) { mx = v3; ax = 48 + lc; }
        #pragma unroll
        for (int off = 1; off < 16; off <<= 1) {
          float om = __shfl_xor(mx, off); int oa = __shfl_xor(ax, off);
          if (om > mx || (om == mx && oa < ax)) { mx = om; ax = oa; }
        }
        float se = __expf(v0 - mx) + __expf(v1 - mx) + __expf(v2 - mx) + __expf(v3 - mx);
        #pragma unroll
        for (int off = 1; off < 16; off <<= 1) se += __shfl_xor(se, off);
        if (lc == 0) {
          int lr = wm * 64 + mi * 16 + (lane >> 4) * 4 + r;
          s_mx[lr][wn] = mx; s_sm[lr][wn] = se; s_ax[lr][wn] = wn * 64 + ax;
        }
      }
    }
    __syncthreads();
    if (tid < 128) {
      float ma = s_mx[tid][0], mb = s_mx[tid][1];
      float gm = fmaxf(ma, mb);
      float gs = s_sm[tid][0] * __expf(ma - gm) + s_sm[tid][1] * __expf(mb - gm);
      int ga = (ma >= mb) ? s_ax[tid][0] : s_ax[tid][1];
      v4f rec; rec[0] = gm; rec[1] = gs; rec[2] = __int_as_float(n0 + ga); rec[3] = 0.f;
      partials[(size_t)(m0 + tid) * NCH + blockIdx.y] = rec;
    }
    return;
  } else {
    #pragma unroll
    for (int mi = 0; mi < 4; ++mi)
      #pragma unroll
      for (int ni = 0; ni < 4; ++ni)
        #pragma unroll
        for (int r = 0; r < 4; ++r) {
          int grow = m0 + wm * 64 + mi * 16 + (lane >> 4) * 4 + r;
          int gcol = n0 + wn * 64 + ni * 16 + lc;
          size_t idx = (size_t)grow * ldc + gcol;
          float vv = acc[mi][ni][r];
          if constexpr (EPI == EPI_BF16) {
            Cbf[idx] = f2bf(vv);
          } else if constexpr (EPI == EPI_SILU) {
            float g = bf2f(Gaux[idx]);
            Cbf[idx] = f2bf(vv * g / (1.0f + __expf(-g)));
          } else if constexpr (EPI == EPI_OEMB) {
            int t = grow & 15, bn = grow >> 4;
            int tok = (t == 0) ? rs.ftok[bn] : cMASK;
            float kf = (float)keepArr[bn];
            Cf32[idx] = rs.emb[(size_t)tok * cD + gcol] + vv * kf;
          } else {
            Cf32[idx] += vv;
          }
        }
  }
}

// ---------------------------------------------------------------------------
__global__ void k_rope(u16* __restrict__ qb, u16* __restrict__ kb,
                       const int* __restrict__ anchors, const int* __restrict__ cpos) {
  int r = blockIdx.x;
  int which = (r >= MKV);
  int rr = which ? r - MKV : r;
  int j = rr % 17, bn = rr / 17;
  if (!which && j == 0) return;
  u16* buf = which ? kb : qb;
  int pos = (which && j == 0) ? cpos[bn] : (anchors[bn] + j - 1);
  float fp = (float)pos;
  for (int p = threadIdx.x; p < cH * 64; p += 256) {
    int h = p >> 6, i = p & 63;
    size_t base = (size_t)rr * cD + h * cHD;
    float x1 = bf2f(buf[base + i]);
    float x2 = bf2f(buf[base + 64 + i]);
    float freq = powf(10000.0f, -((float)(2 * i)) / 128.0f);
    float ang = fp * freq;
    float sn = sinf(ang), cn = cosf(ang);
    buf[base + i]      = f2bf(x1 * cn - x2 * sn);
    buf[base + 64 + i] = f2bf(x2 * cn + x1 * sn);
  }
}

__global__ void k_attn(u16* __restrict__ qb, const u16* __restrict__ kb,
                       const u16* __restrict__ vb) {
  int blk = blockIdx.x;
  int h = blk % cH, bn = blk / cH;
  __shared__ float qs[16][128], ks[17][128], vs[17][128], ps[16][18];
  int lane = threadIdx.x;
  for (int e = lane; e < 16 * 128; e += 64) {
    int r = e >> 7, d = e & 127;
    qs[r][d] = bf2f(qb[((size_t)(bn * 17 + 1 + r)) * cD + h * cHD + d]);
  }
  for (int e = lane; e < 17 * 128; e += 64) {
    int r = e >> 7, d = e & 127;
    ks[r][d] = bf2f(kb[((size_t)(bn * 17 + r)) * cD + h * cHD + d]);
    vs[r][d] = bf2f(vb[((size_t)(bn * 17 + r)) * cD + h * cHD + d]);
  }
  __syncthreads();
  for (int e = lane; e < 16 * 17; e += 64) {
    int qi = e / 17, ki = e % 17;
    float s = 0.f;
    for (int d = 0; d < 128; ++d) s += qs[qi][d] * ks[ki][d];
    ps[qi][ki] = s * 0.08838834764831845f;
  }
  __syncthreads();
  if (lane < 16) {
    float m = -3e38f;
    for (int kk = 0; kk < 17; ++kk) m = fmaxf(m, ps[lane][kk]);
    float s = 0.f;
    for (int kk = 0; kk < 17; ++kk) { float e_ = __expf(ps[lane][kk] - m); ps[lane][kk] = e_; s += e_; }
    float is = 1.0f / s;
    for (int kk = 0; kk < 17; ++kk) ps[lane][kk] *= is;
  }
  __syncthreads();
  for (int e = lane; e < 16 * 128; e += 64) {
    int qi = e >> 7, d = e & 127;
    float s = 0.f;
    for (int kk = 0; kk < 17; ++kk) s += ps[qi][kk] * vs[kk][d];
    qb[((size_t)(bn * 17 + 1 + qi)) * cD + h * cHD + d] = f2bf(s);
  }
}

__global__ void k_tgt(const u16* __restrict__ hout, const float* __restrict__ Wlm,
                      const int* __restrict__ ids, const int* __restrict__ anchors,
                      int* __restrict__ tgt_tok, float* __restrict__ tgt_logit) {
  int w = threadIdx.x >> 6, lane = threadIdx.x & 63;
  int m = blockIdx.x * 4 + w;
  int bn = m >> 4, t = m & 15, b = bn / cNA;
  int label = anchors[bn] + t;
  int sl = (label < cS - 1) ? label : (cS - 1);
  int tok = ids[(size_t)b * cS + sl];
  const u16* hr = hout + (size_t)m * cD;
  const float* wr = Wlm + (size_t)tok * cD;
  float s = 0.f;
  for (int d = lane; d < cD; d += 64) s += bf2f(hr[d]) * wr[d];
  s = waveSum(s);
  if (lane == 0) { tgt_tok[m] = tok; tgt_logit[m] = s; }
}

__global__ void k_combine(const v4f* __restrict__ partials, const int* __restrict__ tgt_tok,
                          const float* __restrict__ tgt_logit, const int* __restrict__ keepArr,
                          const int* __restrict__ anchors, const float* __restrict__ lmask,
                          float* __restrict__ tokOut, int nch) {
  int m = blockIdx.x;
  int tid = threadIdx.x, lane = tid & 63, w = tid >> 6;
  float cm = -3.0e38f, cs = 0.f; int ca = 0x7fffffff;
  if (tid < nch) {
    v4f rec = partials[(size_t)m * nch + tid];
    cm = rec[0]; cs = rec[1]; ca = __float_as_int(rec[2]);
  }
  float gm = cm; int ga = ca;
  #pragma unroll
  for (int off = 1; off < 64; off <<= 1) {
    float om = __shfl_xor(gm, off); int oa = __shfl_xor(ga, off);
    if (om > gm || (om == gm && oa < ga)) { gm = om; ga = oa; }
  }
  __shared__ float wmx[4]; __shared__ int wax[4]; __shared__ float wsm[4];
  if (lane == 0) { wmx[w] = gm; wax[w] = ga; }
  __syncthreads();
  if (tid == 0) {
    for (int i = 1; i < 4; ++i)
      if (wmx[i] > wmx[0] || (wmx[i] == wmx[0] && wax[i] < wax[0])) { wmx[0] = wmx[i]; wax[0] = wax[i]; }
  }
  __syncthreads();
  gm = wmx[0]; ga = wax[0];
  float s = (tid < nch) ? cs * __expf(cm - gm) : 0.f;
  s = waveSum(s);
  if (lane == 0) wsm[w] = s;
  __syncthreads();
  if (tid == 0) {
    float gs = wsm[0] + wsm[1] + wsm[2] + wsm[3];
    float logZ = gm + logf(gs);
    int bn = m >> 4, t = m & 15, b = bn / cNA;
    int label = anchors[bn] + t;
    int sl = (label < cS - 1) ? label : (cS - 1);
    float wgt = (float)keepArr[bn] * ((t > 0) ? 1.f : 0.f) * ((label < cS) ? 1.f : 0.f) *
                lmask[(size_t)b * cS + sl];
    float lp = tgt_logit[m] - logZ;
    int tg = tgt_tok[m];
    tokOut[m * 4 + 0] = lp * wgt;
    tokOut[m * 4 + 1] = wgt;
    tokOut[m * 4 + 2] = ((ga == tg) && (wgt > 0.5f)) ? 1.f : 0.f;
    tokOut[m * 4 + 3] = 0.f;
  }
}

__global__ void k_final(const float* __restrict__ tokOut, float* __restrict__ outp) {
  int tid = threadIdx.x;
  float swl = 0.f, sw = 0.f, sm = 0.f;
  for (int m = tid; m < MTOK; m += 256) {
    swl += tokOut[m * 4 + 0];
    sw  += tokOut[m * 4 + 1];
    sm  += tokOut[m * 4 + 2];
  }
  swl = waveSum(swl); sw = waveSum(sw); sm = waveSum(sm);
  __shared__ float r0[4], r1[4], r2[4];
  int lane = tid & 63, w = tid >> 6;
  if (lane == 0) { r0[w] = swl; r1[w] = sw; r2[w] = sm; }
  __syncthreads();
  if (tid == 0) {
    float a = r0[0] + r0[1] + r0[2] + r0[3];
    float b = r1[0] + r1[1] + r1[2] + r1[3];
    float c = r2[0] + r2[1] + r2[2] + r2[3];
    float denom = b + 1e-6f;
    float loss = -a / denom;
    float acc  = c / denom;
    if (b == 0.0f) loss = -300.0f;
    outp[0] = loss;
    outp[1] = acc;
  }
}

__global__ void k_heartbeat(float* outp) {
  if (threadIdx.x == 0) { outp[0] = -55.0f; outp[1] = -55.0f; }
}
__global__ void k_sentinel(float* outp) {
  if (threadIdx.x == 0) { outp[0] = -777.0f; outp[1] = -777.0f; }
}

// ---------------------------------------------------------------------------
extern "C" void kernel_launch(void* const* d_in, const int* in_sizes, int n_in,
                              void* d_out, int out_size, void* d_ws, size_t ws_size,
                              hipStream_t stream) {
  const int*   ids   = (const int*)  d_in[0];
  const float* hs    = (const float*)d_in[1];
  const float* lmask = (const float*)d_in[2];
  const float* rv    = (const float*)d_in[3];
  const float* emb   = (const float*)d_in[4];
  const float* wlm   = (const float*)d_in[5];
  const float* wq    = (const float*)d_in[6];
  const float* wk    = (const float*)d_in[7];
  const float* wv    = (const float*)d_in[8];
  const float* wo    = (const float*)d_in[9];
  const float* wg    = (const float*)d_in[10];
  const float* wu    = (const float*)d_in[11];
  const float* wd    = (const float*)d_in[12];
  const float* nattn = (const float*)d_in[13];
  const float* nmlp  = (const float*)d_in[14];
  const float* nout  = (const float*)d_in[15];
  const float* nchs  = (const float*)d_in[16];
  (void)in_sizes; (void)n_in; (void)out_size;

  float* outp = (float*)d_out;
  k_heartbeat<<<dim3(1), 64, 0, stream>>>(outp);

  char* wsb = (char*)d_ws;
  size_t off = 0;
  auto alloc = [&](size_t bytes) -> void* {
    void* p = wsb + off;
    off = (off + bytes + 255) & ~(size_t)255;
    return p;
  };
  int*   anchors = (int*)  alloc((size_t)cB * cNA * 4);
  int*   keepA   = (int*)  alloc((size_t)cB * cNA * 4);
  int*   ftok    = (int*)  alloc((size_t)cB * cNA * 4);
  int*   cpos    = (int*)  alloc((size_t)cB * cNA * 4);
  int*   self    = (int*)  alloc((size_t)cB * NCAND * 4);
  float* rowinv  = (float*)alloc((size_t)MKV * 4);
  int*   ttok    = (int*)  alloc((size_t)MTOK * 4);
  float* tlogit  = (float*)alloc((size_t)MTOK * 4);
  float* tokOut  = (float*)alloc((size_t)MTOK * 4 * 4);

  const size_t szQ  = (size_t)MKV * cD * 2;           // 17.8 MB (q/attn-out/h/h_out)
  const size_t szX  = (size_t)MTOK * cD * 4;          // 33.6 MB (fp32 residual)
  u16* qb = (u16*)alloc(szQ);
  const size_t a1off = off;

  RmsSrc rs{hs, emb, nattn, nchs, rowinv, ftok, cpos};

  // common head
  k_select <<<dim3(cB * 16), 256, 0, stream>>>(lmask, rv, self);
  k_anchors<<<dim3(cB),      256, 0, stream>>>(lmask, self, ids, anchors, keepA, ftok, cpos);

  // ---------------- fast tier
  const size_t szKV   = szQ;
  const size_t szCbuf = (size_t)MTOK * 4096 * 2;      // CW = 4096
  size_t kvb_off  = a1off;
  size_t a1f_off  = (kvb_off + szKV + 255) & ~(size_t)255;
  size_t a1f_sz   = 2 * szQ > (szX + szCbuf) ? 2 * szQ : (szX + szCbuf);  // 67 MB
  size_t wreg_off = (a1f_off + a1f_sz + 255) & ~(size_t)255;
  size_t wreg_sz  = (size_t)cV * cD * 2;              // 131 MB (largest stage)
  size_t need_fast = wreg_off + wreg_sz;

  if (need_fast <= ws_size) {
    u16*   kvb   = (u16*)(wsb + kvb_off);
    u16*   kb    = (u16*)(wsb + a1f_off);
    u16*   vb    = (u16*)(wsb + a1f_off + szQ);
    float* xb    = (float*)(wsb + a1f_off);
    u16*   cbuf  = (u16*)(wsb + a1f_off + szX);
    v4f*   parts = (v4f*)(wsb + a1f_off);             // 8.2 MB (lm-head stage)
    u8*    h8    = (u8*)(wsb + a1f_off + (size_t)16 * 1024 * 1024);  // 8.4 MB
    u16*   hb    = qb;
    u16*   houtb = qb;
    u16*   wT    = (u16*)(wsb + wreg_off);
    const size_t szDD = (size_t)cD * cD;
    u16* wqT = wT;            u16* wkT = wT + szDD;
    u16* wvT = wT + 2 * szDD; u16* woT = wT + 3 * szDD;
    const size_t szDF = (size_t)cD * cDFF;
    u16* wgT = wT; u16* wuT = wT + szDF; u16* wdT = wT + 2 * szDF;
    u8*  wlm8 = (u8*)wT;                              // 65.5 MB (lm-head stage)

    k_build2<<<dim3(MKV), 256, 0, stream>>>(hs, emb, nattn, nchs, ftok, cpos, kvb);

    k_tconv<<<dim3(32, 32), 256, 0, stream>>>(wq, wqT, cD, cD);
    k_tconv<<<dim3(32, 32), 256, 0, stream>>>(wk, wkT, cD, cD);
    k_tconv<<<dim3(32, 32), 256, 0, stream>>>(wv, wvT, cD, cD);
    k_tconv<<<dim3(32, 32), 256, 0, stream>>>(wo, woT, cD, cD);

    k_gemm4<ASRC_BF16, EPI_BF16><<<dim3(MKV / 128, cD / 128), 256, 0, stream>>>(
        kvb, wqT, qb, nullptr, nullptr, rs, cD, cD, cD);
    k_gemm4<ASRC_BF16, EPI_BF16><<<dim3(MKV / 128, cD / 128), 256, 0, stream>>>(
        kvb, wkT, kb, nullptr, nullptr, rs, cD, cD, cD);
    k_gemm4<ASRC_BF16, EPI_BF16><<<dim3(MKV / 128, cD / 128), 256, 0, stream>>>(
        kvb, wvT, vb, nullptr, nullptr, rs, cD, cD, cD);

    k_rope<<<dim3(2 * MKV), 256, 0, stream>>>(qb, kb, anchors, cpos);
    k_attn<<<dim3(cB * cNA * cH), 64, 0, stream>>>(qb, kb, vb);

    k_gemm4<ASRC_AOMAP, EPI_OEMB><<<dim3(MTOK / 128, cD / 128), 256, 0, stream>>>(
        qb, woT, nullptr, xb, keepA, rs, cD, cD, cD);

    k_rms<<<dim3(MTOK), 256, 0, stream>>>(xb, nmlp, hb);

    k_tconv<<<dim3(128, 32), 256, 0, stream>>>(wg, wgT, cD, cDFF);
    k_tconv<<<dim3(128, 32), 256, 0, stream>>>(wu, wuT, cD, cDFF);
    k_tconv<<<dim3(32, 128), 256, 0, stream>>>(wd, wdT, cDFF, cD);

    for (int cb = 0; cb < cDFF; cb += 4096) {
      k_gemm6<EPI_BF16><<<dim3(MTOK / 256, 16), 512, 0, stream>>>(
          hb, wgT + (size_t)cb * cD, cbuf, nullptr, nullptr, cD, 4096, 0);
      k_gemm6<EPI_SILU><<<dim3(MTOK / 256, 16), 512, 0, stream>>>(
          hb, wuT + (size_t)cb * cD, cbuf, cbuf, nullptr, cD, 4096, 0);
      k_gemm4<ASRC_BF16, EPI_DOWNACC><<<dim3(MTOK / 128, cD / 128), 256, 0, stream>>>(
          cbuf, wdT + cb, nullptr, xb, nullptr, rs, 4096, cDFF, cD);
    }

    k_rms<<<dim3(MTOK), 256, 0, stream>>>(xb, nout, houtb);

    k_tgt<<<dim3(MTOK / 4), 256, 0, stream>>>(houtb, wlm, ids, anchors, ttok, tlogit);

    // fp8 lm-head: h_out -> fp8 (scale 1), wlm -> fp8 (scale 64); logits = acc/64
    k_cvt8 <<<dim3(1024), 256, 0, stream>>>(houtb, h8, (long)MTOK * cD);
    k_conv8<<<dim3(2048), 256, 0, stream>>>(wlm, wlm8, (long)cV * cD, 64.0f);
    k_gemm7<<<dim3(MTOK / 256, NCH2), 512, 0, stream>>>(h8, wlm8, parts, cD, NCH2);

    k_combine<<<dim3(MTOK), 256, 0, stream>>>(parts, ttok, tlogit, keepA, anchors, lmask, tokOut, NCH2);
    k_final  <<<dim3(1), 256, 0, stream>>>(tokOut, outp);
    return;
  }

  // ---------------- fallback tier (round-3 path, fp32 weights in GEMM)
  const int cwopts[4] = {4096, 2048, 1024, 512};
  int CW = 0;
  for (int ci = 0; ci < 4; ++ci) {
    int cw = cwopts[ci];
    size_t cbufsz = (size_t)MTOK * cw * 2;
    size_t s1 = 2 * szQ;
    size_t s2 = szX + cbufsz;
    size_t sz = s1 > s2 ? s1 : s2;
    size_t pmin = (size_t)MTOK * NCH * 16;
    if (pmin > sz) sz = pmin;
    if (a1off + sz <= ws_size) { CW = cw; break; }
  }
  if (CW == 0) { k_sentinel<<<dim3(1), 64, 0, stream>>>(outp); return; }

  u16*   kb    = (u16*)(wsb + a1off);
  u16*   vb    = (u16*)(wsb + a1off + szQ);
  float* xb    = (float*)(wsb + a1off);
  u16*   cbuf  = (u16*)(wsb + a1off + szX);
  v4f*   parts = (v4f*)(wsb + a1off);
  u16*   hb    = qb;
  u16*   houtb = qb;

  k_rowinv<<<dim3(MKV), 256, 0, stream>>>(hs, emb, ftok, cpos, rowinv);

  k_gemm<ASRC_RMS, 0, EPI_BF16><<<dim3(MKV / 128, cD / 128), 256, 0, stream>>>(
      nullptr, wq, qb, nullptr, nullptr, nullptr, nullptr, rs, cD, cD, cD);
  k_gemm<ASRC_RMS, 0, EPI_BF16><<<dim3(MKV / 128, cD / 128), 256, 0, stream>>>(
      nullptr, wk, kb, nullptr, nullptr, nullptr, nullptr, rs, cD, cD, cD);
  k_gemm<ASRC_RMS, 0, EPI_BF16><<<dim3(MKV / 128, cD / 128), 256, 0, stream>>>(
      nullptr, wv, vb, nullptr, nullptr, nullptr, nullptr, rs, cD, cD, cD);

  k_rope<<<dim3(2 * MKV), 256, 0, stream>>>(qb, kb, anchors, cpos);
  k_attn<<<dim3(cB * cNA * cH), 64, 0, stream>>>(qb, kb, vb);

  k_gemm<ASRC_AOMAP, 0, EPI_OEMB><<<dim3(MTOK / 128, cD / 128), 256, 0, stream>>>(
      qb, wo, nullptr, xb, nullptr, keepA, nullptr, rs, cD, cD, cD);

  k_rms<<<dim3(MTOK), 256, 0, stream>>>(xb, nmlp, hb);

  for (int cb = 0; cb < cDFF; cb += CW) {
    k_gemm<ASRC_BF16, 0, EPI_BF16><<<dim3(MTOK / 128, CW / 128), 256, 0, stream>>>(
        hb, wg + cb, cbuf, nullptr, nullptr, nullptr, nullptr, rs, cD, cDFF, CW);
    k_gemm<ASRC_BF16, 0, EPI_SILU><<<dim3(MTOK / 128, CW / 128), 256, 0, stream>>>(
        hb, wu + cb, cbuf, nullptr, cbuf, nullptr, nullptr, rs, cD, cDFF, CW);
    k_gemm<ASRC_BF16, 0, EPI_DOWNACC><<<dim3(MTOK / 128, cD / 128), 256, 0, stream>>>(
        cbuf, wd + (size_t)cb * cD, nullptr, xb, nullptr, nullptr, nullptr, rs, CW, cD, cD);
  }

  k_rms<<<dim3(MTOK), 256, 0, stream>>>(xb, nout, houtb);

  k_tgt<<<dim3(MTOK / 4), 256, 0, stream>>>(houtb, wlm, ids, anchors, ttok, tlogit);
  k_gemm<ASRC_BF16, 1, EPI_STATS><<<dim3(MTOK / 128, cV / 128), 256, 0, stream>>>(
      houtb, wlm, nullptr, nullptr, nullptr, nullptr, parts, rs, cD, cD, 0);

  k_combine<<<dim3(MTOK), 256, 0, stream>>>(parts, ttok, tlogit, keepA, anchors, lmask, tokOut, NCH);
  k_final  <<<dim3(1), 256, 0, stream>>>(tokOut, outp);
}

// Round 12
// 1556.531 us; speedup vs baseline: 1.0643x; 1.0372x over previous
//
#include <hip/hip_runtime.h>
#include <math.h>

typedef unsigned short u16;
typedef unsigned char u8;
typedef short v8s __attribute__((ext_vector_type(8)));
typedef u16   v4u __attribute__((ext_vector_type(4)));
typedef float v4f __attribute__((ext_vector_type(4)));
typedef int   v2i __attribute__((ext_vector_type(2)));
typedef int   v4i __attribute__((ext_vector_type(4)));

#define DEVFN static __device__ __forceinline__

constexpr int cB = 2, cS = 4096, cD = 2048, cV = 32000, cH = 16, cHD = 128;
constexpr int cBS = 16, cNA = 128, cMASK = 31999, cDFF = 8192;
constexpr int NCAND = cS - cBS + 1;   // 4081 anchor candidates
constexpr int MTOK  = cB * cNA * cBS; // 4096 query tokens
constexpr int MKV   = cB * cNA * 17;  // 4352 kv rows (ctx + 16)
constexpr int NCH   = cV / 128;       // 250 vocab chunks (128-wide, fallback)
constexpr int NCH2  = cV / 256;       // 125 vocab chunks (256-wide, fast)

constexpr int EPI_BF16 = 0, EPI_SILU = 1, EPI_OEMB = 2, EPI_DOWNACC = 3, EPI_STATS = 4;
constexpr int ASRC_BF16 = 0, ASRC_RMS = 1, ASRC_AOMAP = 2;

struct RmsSrc {
  const float* hs; const float* emb; const float* nattn; const float* nchs;
  const float* rowinv; const int* ftok; const int* cpos;
};

DEVFN u16 f2bf(float f) {               // RNE fp32 -> bf16
  union { float f; unsigned u; } a; a.f = f;
  unsigned u = a.u;
  u = u + 0x7fffu + ((u >> 16) & 1u);
  return (u16)(u >> 16);
}
DEVFN float bf2f(u16 h) {
  union { unsigned u; float f; } a; a.u = ((unsigned)h) << 16;
  return a.f;
}
DEVFN float waveSum(float v) {
  #pragma unroll
  for (int o = 32; o >= 1; o >>= 1) v += __shfl_xor(v, o);
  return v;
}
DEVFN void gload16(void* lds, const void* g) {
  __builtin_amdgcn_global_load_lds(
      (const __attribute__((address_space(1))) unsigned*)g,
      (__attribute__((address_space(3))) unsigned*)lds, 16, 0, 0);
}
DEVFN int pack4fp8(float a, float b, float c, float d) {
  int p = __builtin_amdgcn_cvt_pk_fp8_f32(a, b, 0, 0);
  p = __builtin_amdgcn_cvt_pk_fp8_f32(c, d, p, 1);
  return p;
}
// permuted output offset for fp8 buffers: within each 64B K-group,
// newpos = lq*16 + kh*8 + j  for k = kh*32 + lq*8 + j  (i multiple of 8)
DEVFN long perm8(long i) {
  return (i & ~63L) | (((i >> 3) & 3) << 4) | (((i >> 5) & 1) << 3);
}

// ---------------------------------------------------------------------------
__global__ void k_select(const float* __restrict__ lmask, const float* __restrict__ rv_in,
                         int* __restrict__ self) {
  int b = blockIdx.x >> 4, chunk = blockIdx.x & 15;
  __shared__ float rvs[4096];
  for (int i = threadIdx.x; i < NCAND; i += 256) {
    bool valid = lmask[(size_t)b * cS + i] > 0.5f;
    rvs[i] = valid ? rv_in[(size_t)b * NCAND + i] : 2.0f;
  }
  __syncthreads();
  int i = chunk * 256 + threadIdx.x;
  if (i < NCAND) {
    float v = rvs[i];
    int rank = 0;
    for (int j = 0; j < NCAND; ++j) {
      float u = rvs[j];
      rank += (u < v) || (u == v && j < i);
    }
    self[(size_t)b * NCAND + i] = (rank < cNA) ? 1 : 0;
  }
}

__global__ void k_anchors(const float* __restrict__ lmask, const int* __restrict__ self,
                          const int* __restrict__ ids, int* __restrict__ anchors,
                          int* __restrict__ keepA, int* __restrict__ ftok, int* __restrict__ cpos) {
  int b = blockIdx.x;
  __shared__ int flags[4096];
  __shared__ int ssum[256];
  __shared__ int soff[257];
  __shared__ int abuf[cNA];
  for (int i = threadIdx.x; i < 4096; i += 256)
    flags[i] = (i < NCAND) ? (self[(size_t)b * NCAND + i] && (lmask[(size_t)b * cS + i] > 0.5f)) : 0;
  if (threadIdx.x < cNA) abuf[threadIdx.x] = 0;
  __syncthreads();
  int s = 0;
  #pragma unroll
  for (int j = 0; j < 16; ++j) s += flags[threadIdx.x * 16 + j];
  ssum[threadIdx.x] = s;
  __syncthreads();
  if (threadIdx.x == 0) {
    int a = 0;
    for (int t = 0; t < 256; ++t) { soff[t] = a; a += ssum[t]; }
    soff[256] = a;
  }
  __syncthreads();
  int nsel = soff[256];
  int p = soff[threadIdx.x];
  for (int j = 0; j < 16; ++j) {
    int i = threadIdx.x * 16 + j;
    if (flags[i]) { if (p < cNA) abuf[p] = i; ++p; }
  }
  __syncthreads();
  if (threadIdx.x < cNA) {
    int q = threadIdx.x;
    int kp = (q < nsel) ? 1 : 0;
    int a = kp ? abuf[q] : 0;
    anchors[b * cNA + q] = a;
    keepA[b * cNA + q] = kp;
    int av = a; if (av < 0) av = 0; if (av > cS - 1) av = cS - 1;
    int tok = ids[(size_t)b * cS + av];
    ftok[b * cNA + q] = kp ? tok : cMASK;
    cpos[b * cNA + q] = (a - 1 > 0) ? (a - 1) : 0;
  }
}

// per-kv-row 1/rms (fallback tier)
__global__ void k_rowinv(const float* __restrict__ hs, const float* __restrict__ emb,
                         const int* __restrict__ ftok, const int* __restrict__ cpos,
                         float* __restrict__ rowinv) {
  int r = blockIdx.x;
  int j = r % 17, bn = r / 17, b = bn >> 7;
  const float* src = (j == 0) ? hs + ((size_t)b * cS + cpos[bn]) * cD
                              : emb + (size_t)((j == 1) ? ftok[bn] : cMASK) * cD;
  float ss = 0.f;
  for (int d = threadIdx.x; d < cD; d += 256) { float v = src[d]; ss += v * v; }
  ss = waveSum(ss);
  __shared__ float red[4];
  if ((threadIdx.x & 63) == 0) red[threadIdx.x >> 6] = ss;
  __syncthreads();
  if (threadIdx.x == 0) {
    float tot = red[0] + red[1] + red[2] + red[3];
    rowinv[r] = 1.0f / sqrtf(tot / cD + 1e-6f);
  }
}

// kv_in = rms'd rows, materialized bf16 (fast tier). grid: MKV x 256
__global__ void k_build2(const float* __restrict__ hs, const float* __restrict__ emb,
                         const float* __restrict__ nattn, const float* __restrict__ nchs,
                         const int* __restrict__ ftok, const int* __restrict__ cpos,
                         u16* __restrict__ kv) {
  int r = blockIdx.x;
  int j = r % 17, bn = r / 17, b = bn >> 7;
  const float* src; const float* w;
  if (j == 0) { src = hs + ((size_t)b * cS + cpos[bn]) * cD; w = nchs; }
  else {
    int tok = (j == 1) ? ftok[bn] : cMASK;
    src = emb + (size_t)tok * cD; w = nattn;
  }
  float ss = 0.f;
  for (int d = threadIdx.x; d < cD; d += 256) { float v = src[d]; ss += v * v; }
  ss = waveSum(ss);
  __shared__ float red[4];
  if ((threadIdx.x & 63) == 0) red[threadIdx.x >> 6] = ss;
  __syncthreads();
  float tot = red[0] + red[1] + red[2] + red[3];
  float inv = 1.0f / sqrtf(tot / cD + 1e-6f);
  for (int d = threadIdx.x; d < cD; d += 256)
    kv[(size_t)r * cD + d] = f2bf(src[d] * inv * w[d]);
}

// RMS over fp32 rows -> bf16
__global__ void k_rms(const float* __restrict__ xin, const float* __restrict__ w,
                      u16* __restrict__ outp) {
  int m = blockIdx.x;
  const float* row = xin + (size_t)m * cD;
  float ss = 0.f;
  for (int d = threadIdx.x; d < cD; d += 256) { float v = row[d]; ss += v * v; }
  ss = waveSum(ss);
  __shared__ float red[4];
  if ((threadIdx.x & 63) == 0) red[threadIdx.x >> 6] = ss;
  __syncthreads();
  float tot = red[0] + red[1] + red[2] + red[3];
  float inv = 1.0f / sqrtf(tot / cD + 1e-6f);
  for (int d = threadIdx.x; d < cD; d += 256)
    outp[(size_t)m * cD + d] = f2bf(row[d] * inv * w[d]);
}

// fp32 -> fp8 e4m3 with scale, PERMUTED 64B-group layout. 8 elems/thread
__global__ void k_conv8(const float* __restrict__ in, u8* __restrict__ out, long n, float scale) {
  long i = ((long)blockIdx.x * 256 + threadIdx.x) * 8;
  long stride = (long)gridDim.x * 256 * 8;
  for (; i < n; i += stride) {
    v4f a = *(const v4f*)(in + i), b = *(const v4f*)(in + i + 4);
    v2i pk;
    pk[0] = pack4fp8(a[0] * scale, a[1] * scale, a[2] * scale, a[3] * scale);
    pk[1] = pack4fp8(b[0] * scale, b[1] * scale, b[2] * scale, b[3] * scale);
    *(v2i*)(out + perm8(i)) = pk;
  }
}

// bf16 -> fp8 e4m3, PERMUTED 64B-group layout. 8 elems/thread
__global__ void k_cvt8(const u16* __restrict__ in, u8* __restrict__ out, long n) {
  long i = ((long)blockIdx.x * 256 + threadIdx.x) * 8;
  long stride = (long)gridDim.x * 256 * 8;
  for (; i < n; i += stride) {
    v8s a = *(const v8s*)(in + i);
    v2i pk;
    pk[0] = pack4fp8(bf2f((u16)a[0]), bf2f((u16)a[1]), bf2f((u16)a[2]), bf2f((u16)a[3]));
    pk[1] = pack4fp8(bf2f((u16)a[4]), bf2f((u16)a[5]), bf2f((u16)a[6]), bf2f((u16)a[7]));
    *(v2i*)(out + perm8(i)) = pk;
  }
}

// transpose-convert: W [K][N] fp32 -> WT [N][K] bf16. 64x64 tiles, grid (N/64, K/64)
__global__ void k_tconv(const float* __restrict__ W, u16* __restrict__ WT, int K, int N) {
  __shared__ u16 t[64][72];
  int n0 = blockIdx.x * 64, k0 = blockIdx.y * 64;
  int tid = threadIdx.x;
  int c4 = (tid & 15) * 4, r0 = tid >> 4;
  #pragma unroll
  for (int rr = 0; rr < 64; rr += 16) {
    int k = r0 + rr;
    v4f v = *(const v4f*)(W + (size_t)(k0 + k) * N + n0 + c4);
    #pragma unroll
    for (int e = 0; e < 4; ++e) t[c4 + e][k] = f2bf(v[e]);
  }
  __syncthreads();
  int n = tid >> 2, kq = (tid & 3) * 16;
  v8s o0, o1;
  #pragma unroll
  for (int e = 0; e < 8; ++e) { o0[e] = (short)t[n][kq + e]; o1[e] = (short)t[n][kq + 8 + e]; }
  *(v8s*)(WT + (size_t)(n0 + n) * K + k0 + kq) = o0;
  *(v8s*)(WT + (size_t)(n0 + n) * K + k0 + kq + 8) = o1;
}

// ---------------------------------------------------------------------------
// 8-PHASE PIPELINED 256x256 GEMM bf16 (round-10 verified). K-split half-tiles.
template <int EPI>
__launch_bounds__(512, 1)
__global__ void k_gemm6(const u16* __restrict__ Abf, const u16* __restrict__ Bbf,
                        u16* __restrict__ Cbf, const u16* __restrict__ Gaux,
                        v4f* __restrict__ partials, int K, int ldc, int nch) {
  __shared__ __align__(16) u16 lds[65536];
  const int tid = threadIdx.x;
  const int lane = tid & 63, wid = tid >> 6;
  const int wm = wid >> 2, wn = wid & 3;
  const int lc = lane & 15, lq = lane >> 4;
  const int m0 = blockIdx.x * 256, n0 = blockIdx.y * 256;

  const u16* srcA[2]; const u16* srcB[2];
  #pragma unroll
  for (int i = 0; i < 2; ++i) {
    int s = i * 512 + tid;
    int row = s >> 2;
    int c2 = (s & 3) ^ ((row >> 1) & 3);
    srcA[i] = Abf + (size_t)(m0 + row) * K + c2 * 8;
    srcB[i] = Bbf + (size_t)(n0 + row) * K + c2 * 8;
  }

  v4f acc[8][4];
  #pragma unroll
  for (int i = 0; i < 8; ++i)
    #pragma unroll
    for (int j = 0; j < 4; ++j) acc[i][j] = (v4f){0.f, 0.f, 0.f, 0.f};

  const int fsw = lq ^ ((lc >> 1) & 3);
  int aoff[8], boff[4];
  #pragma unroll
  for (int mi = 0; mi < 8; ++mi) aoff[mi] = ((wm * 128 + mi * 16 + lc) * 4 + fsw) * 8;
  #pragma unroll
  for (int ni = 0; ni < 4; ++ni) boff[ni] = ((wn * 64 + ni * 16 + lc) * 4 + fsw) * 8;

  auto stageA = [&](int t, int kh) {
    int reg = (t & 1) * 32768 + kh * 8192;
    int koff = t * 64 + kh * 32;
    #pragma unroll
    for (int i = 0; i < 2; ++i)
      gload16(&lds[reg + i * 4096 + wid * 512], srcA[i] + koff);
  };
  auto stageB = [&](int t, int kh) {
    int reg = (t & 1) * 32768 + 16384 + kh * 8192;
    int koff = t * 64 + kh * 32;
    #pragma unroll
    for (int i = 0; i < 2; ++i)
      gload16(&lds[reg + i * 4096 + wid * 512], srcB[i] + koff);
  };

  stageA(0, 0); stageB(0, 0);
  stageA(0, 1); stageB(0, 1);
  stageA(1, 0); stageB(1, 0);
  asm volatile("s_waitcnt vmcnt(8)" ::: "memory");
  __builtin_amdgcn_s_barrier();

  const int NT = K >> 6;
  for (int t = 0; t < NT; ++t) {
    const int bufb = (t & 1) * 32768;
    const u16* Ab0 = &lds[bufb];
    const u16* Ab1 = &lds[bufb + 8192];
    const u16* Bb0 = &lds[bufb + 16384];
    const u16* Bb1 = &lds[bufb + 24576];
    v8s a_[4], b_[4];

    #pragma unroll
    for (int ni = 0; ni < 4; ++ni) b_[ni] = *(const v8s*)(Bb0 + boff[ni]);
    #pragma unroll
    for (int mi = 0; mi < 4; ++mi) a_[mi] = *(const v8s*)(Ab0 + aoff[mi]);
    if (t + 1 < NT) stageA(t + 1, 1);
    asm volatile("s_waitcnt lgkmcnt(0)" ::: "memory");
    __builtin_amdgcn_sched_barrier(0);
    __builtin_amdgcn_s_setprio(1);
    #pragma unroll
    for (int mi = 0; mi < 4; ++mi)
      #pragma unroll
      for (int ni = 0; ni < 4; ++ni)
        acc[mi][ni] = __builtin_amdgcn_mfma_f32_16x16x32_bf16(a_[mi], b_[ni], acc[mi][ni], 0, 0, 0);
    __builtin_amdgcn_s_setprio(0);
    __builtin_amdgcn_s_barrier();

    #pragma unroll
    for (int mi = 0; mi < 4; ++mi) a_[mi] = *(const v8s*)(Ab0 + aoff[mi + 4]);
    if (t + 1 < NT) stageB(t + 1, 1);
    asm volatile("s_waitcnt lgkmcnt(0)" ::: "memory");
    __builtin_amdgcn_sched_barrier(0);
    __builtin_amdgcn_s_setprio(1);
    #pragma unroll
    for (int mi = 0; mi < 4; ++mi)
      #pragma unroll
      for (int ni = 0; ni < 4; ++ni)
        acc[mi + 4][ni] = __builtin_amdgcn_mfma_f32_16x16x32_bf16(a_[mi], b_[ni], acc[mi + 4][ni], 0, 0, 0);
    __builtin_amdgcn_s_setprio(0);
    if (t + 1 < NT) { asm volatile("s_waitcnt vmcnt(4)" ::: "memory"); }
    else            { asm volatile("s_waitcnt vmcnt(0)" ::: "memory"); }
    __builtin_amdgcn_s_barrier();

    #pragma unroll
    for (int ni = 0; ni < 4; ++ni) b_[ni] = *(const v8s*)(Bb1 + boff[ni]);
    #pragma unroll
    for (int mi = 0; mi < 4; ++mi) a_[mi] = *(const v8s*)(Ab1 + aoff[mi]);
    if (t + 2 < NT) stageA(t + 2, 0);
    asm volatile("s_waitcnt lgkmcnt(0)" ::: "memory");
    __builtin_amdgcn_sched_barrier(0);
    __builtin_amdgcn_s_setprio(1);
    #pragma unroll
    for (int mi = 0; mi < 4; ++mi)
      #pragma unroll
      for (int ni = 0; ni < 4; ++ni)
        acc[mi][ni] = __builtin_amdgcn_mfma_f32_16x16x32_bf16(a_[mi], b_[ni], acc[mi][ni], 0, 0, 0);
    __builtin_amdgcn_s_setprio(0);
    __builtin_amdgcn_s_barrier();

    #pragma unroll
    for (int mi = 0; mi < 4; ++mi) a_[mi] = *(const v8s*)(Ab1 + aoff[mi + 4]);
    if (t + 2 < NT) stageB(t + 2, 0);
    asm volatile("s_waitcnt lgkmcnt(0)" ::: "memory");
    __builtin_amdgcn_sched_barrier(0);
    __builtin_amdgcn_s_setprio(1);
    #pragma unroll
    for (int mi = 0; mi < 4; ++mi)
      #pragma unroll
      for (int ni = 0; ni < 4; ++ni)
        acc[mi + 4][ni] = __builtin_amdgcn_mfma_f32_16x16x32_bf16(a_[mi], b_[ni], acc[mi + 4][ni], 0, 0, 0);
    __builtin_amdgcn_s_setprio(0);
    __builtin_amdgcn_s_barrier();
  }
  asm volatile("s_waitcnt vmcnt(0)" ::: "memory");

  #pragma unroll
  for (int mi = 0; mi < 8; ++mi)
    #pragma unroll
    for (int ni = 0; ni < 4; ++ni)
      #pragma unroll
      for (int r = 0; r < 4; ++r) {
        int grow = m0 + wm * 128 + mi * 16 + lq * 4 + r;
        int gcol = n0 + wn * 64 + ni * 16 + lc;
        size_t idx = (size_t)grow * ldc + gcol;
        float vv = acc[mi][ni][r];
        if constexpr (EPI == EPI_BF16) {
          Cbf[idx] = f2bf(vv);
        } else {  // EPI_SILU
          float g = bf2f(Gaux[idx]);
          Cbf[idx] = f2bf(vv * g / (1.0f + __expf(-g)));
        }
      }
  (void)partials; (void)nch;
}

// ---------------------------------------------------------------------------
// 8-PHASE PIPELINED 256x256 GEMM fp8 e4m3, b128 fragment reads (gemm6-geometry
// LDS: 256 rows x 64B per region, chunk swizzle ^=(lc>>1)&3; one b128 read per
// fragment-row delivers BOTH K-halves). STATS epilogue. logits = acc/64.
__launch_bounds__(512, 2)
__global__ void k_gemm8(const u8* __restrict__ A8, const u8* __restrict__ B8,
                        v4f* __restrict__ partials, int K, int nch) {
  // 64 KB: buf b at b*32768; A region 16KB at +0, B at +16384
  __shared__ __align__(16) u8 lds8[65536];
  const int tid = threadIdx.x;
  const int lane = tid & 63, wid = tid >> 6;
  const int wm = wid >> 2, wn = wid & 3;        // per-wave out 128x64
  const int lc = lane & 15, lq = lane >> 4;
  const int m0 = blockIdx.x * 256, n0 = blockIdx.y * 256;

  // staging: issue i covers 16B-chunk ci = i*512+tid of a 16KB region;
  // r = ci>>2, phys chunk = ci&3, logical = phys ^ ((r>>1)&3)
  const u8* srcA[2]; const u8* srcB[2];
  #pragma unroll
  for (int i = 0; i < 2; ++i) {
    int ci = i * 512 + tid;
    int r = ci >> 2;
    int logc = (ci & 3) ^ ((r >> 1) & 3);
    srcA[i] = A8 + (size_t)(m0 + r) * K + logc * 16;
    srcB[i] = B8 + (size_t)(n0 + r) * K + logc * 16;
  }

  v4f acc[8][4];
  #pragma unroll
  for (int i = 0; i < 8; ++i)
    #pragma unroll
    for (int j = 0; j < 4; ++j) acc[i][j] = (v4f){0.f, 0.f, 0.f, 0.f};

  // fragment byte offsets within a region: row*64 + ((lq ^ ((lc>>1)&3)) << 4)
  const int csw = (lc >> 1) & 3;
  int aoff[8], boff[4];
  #pragma unroll
  for (int mi = 0; mi < 8; ++mi) aoff[mi] = (wm * 128 + mi * 16 + lc) * 64 + ((lq ^ csw) << 4);
  #pragma unroll
  for (int ni = 0; ni < 4; ++ni) boff[ni] = (wn * 64 + ni * 16 + lc) * 64 + ((lq ^ csw) << 4);

  auto stageA = [&](int t, int i) {
    gload16(&lds8[(t & 1) * 32768 + i * 8192 + wid * 1024], srcA[i] + t * 64);
  };
  auto stageB = [&](int t, int i) {
    gload16(&lds8[(t & 1) * 32768 + 16384 + i * 8192 + wid * 1024], srcB[i] + t * 64);
  };

  // prologue: tiles 0 and 1 (8 issues); wait tile0's 4 -> vmcnt(4)
  stageA(0, 0); stageA(0, 1); stageB(0, 0); stageB(0, 1);
  stageA(1, 0); stageA(1, 1); stageB(1, 0); stageB(1, 1);
  asm volatile("s_waitcnt vmcnt(4)" ::: "memory");
  __builtin_amdgcn_s_barrier();

  union Frag { v4i v; long long ll[2]; };
  const int NT = K >> 6;
  for (int t = 0; t < NT; ++t) {
    const u8* Ab = &lds8[(t & 1) * 32768];
    const u8* Bb = Ab + 16384;
    Frag fa[8], fb[4];

    // q0: read all B + A0-3 (b128 each, both K-halves); MFMA kh0 mi0-3
    #pragma unroll
    for (int ni = 0; ni < 4; ++ni) fb[ni].v = *(const v4i*)(Bb + boff[ni]);
    #pragma unroll
    for (int mi = 0; mi < 4; ++mi) fa[mi].v = *(const v4i*)(Ab + aoff[mi]);
    asm volatile("s_waitcnt lgkmcnt(0)" ::: "memory");
    __builtin_amdgcn_sched_barrier(0);
    __builtin_amdgcn_s_setprio(1);
    #pragma unroll
    for (int mi = 0; mi < 4; ++mi)
      #pragma unroll
      for (int ni = 0; ni < 4; ++ni)
        acc[mi][ni] = __builtin_amdgcn_mfma_f32_16x16x32_fp8_fp8(fa[mi].ll[0], fb[ni].ll[0], acc[mi][ni], 0, 0, 0);
    __builtin_amdgcn_s_setprio(0);
    __builtin_amdgcn_s_barrier();

    // q1: read A4-7; stage B(t+2).0 into cur B-region (dead after q0 barrier)
    #pragma unroll
    for (int mi = 0; mi < 4; ++mi) fa[mi + 4].v = *(const v4i*)(Ab + aoff[mi + 4]);
    if (t + 2 < NT) stageB(t + 2, 0);
    asm volatile("s_waitcnt lgkmcnt(0)" ::: "memory");
    __builtin_amdgcn_sched_barrier(0);
    __builtin_amdgcn_s_setprio(1);
    #pragma unroll
    for (int mi = 0; mi < 4; ++mi)
      #pragma unroll
      for (int ni = 0; ni < 4; ++ni)
        acc[mi + 4][ni] = __builtin_amdgcn_mfma_f32_16x16x32_fp8_fp8(fa[mi + 4].ll[0], fb[ni].ll[0], acc[mi + 4][ni], 0, 0, 0);
    __builtin_amdgcn_s_setprio(0);
    __builtin_amdgcn_s_barrier();

    // q2: no reads (kh1 from regs); stage B(t+2).1, A(t+2).0 (A dead after q1 barrier)
    if (t + 2 < NT) { stageB(t + 2, 1); stageA(t + 2, 0); }
    __builtin_amdgcn_s_setprio(1);
    #pragma unroll
    for (int mi = 0; mi < 4; ++mi)
      #pragma unroll
      for (int ni = 0; ni < 4; ++ni)
        acc[mi][ni] = __builtin_amdgcn_mfma_f32_16x16x32_fp8_fp8(fa[mi].ll[1], fb[ni].ll[1], acc[mi][ni], 0, 0, 0);
    __builtin_amdgcn_s_setprio(0);
    __builtin_amdgcn_s_barrier();

    // q3: stage A(t+2).1; MFMA kh1 mi4-7; per-tile counted vmcnt
    if (t + 2 < NT) stageA(t + 2, 1);
    __builtin_amdgcn_s_setprio(1);
    #pragma unroll
    for (int mi = 0; mi < 4; ++mi)
      #pragma unroll
      for (int ni = 0; ni < 4; ++ni)
        acc[mi + 4][ni] = __builtin_amdgcn_mfma_f32_16x16x32_fp8_fp8(fa[mi + 4].ll[1], fb[ni].ll[1], acc[mi + 4][ni], 0, 0, 0);
    __builtin_amdgcn_s_setprio(0);
    if (t + 2 < NT) { asm volatile("s_waitcnt vmcnt(4)" ::: "memory"); }
    else            { asm volatile("s_waitcnt vmcnt(0)" ::: "memory"); }
    __builtin_amdgcn_s_barrier();
  }
  asm volatile("s_waitcnt vmcnt(0)" ::: "memory");

  // undo the x64 weight scale
  #pragma unroll
  for (int mi = 0; mi < 8; ++mi)
    #pragma unroll
    for (int ni = 0; ni < 4; ++ni)
      acc[mi][ni] *= 0.015625f;

  // epilogue scratch aliased onto (dead) staging LDS
  float* s_mx = (float*)lds8;
  float* s_sm = (float*)(lds8 + 4096);
  int*   s_ax = (int*)(lds8 + 8192);
  __syncthreads();
  #pragma unroll
  for (int mi = 0; mi < 8; ++mi) {
    #pragma unroll
    for (int r = 0; r < 4; ++r) {
      float v0 = acc[mi][0][r], v1 = acc[mi][1][r], v2 = acc[mi][2][r], v3 = acc[mi][3][r];
      float mx = v0; int ax = lc;
      if (v1 > mx) { mx = v1; ax = 16 + lc; }
      if (v2 > mx) { mx = v2; ax = 32 + lc; }
      if (v3 > mx) { mx = v3; ax = 48 + lc; }
      #pragma unroll
      for (int off = 1; off < 16; off <<= 1) {
        float om = __shfl_xor(mx, off); int oa = __shfl_xor(ax, off);
        if (om > mx || (om == mx && oa < ax)) { mx = om; ax = oa; }
      }
      float se = __expf(v0 - mx) + __expf(v1 - mx) + __expf(v2 - mx) + __expf(v3 - mx);
      #pragma unroll
      for (int off = 1; off < 16; off <<= 1) se += __shfl_xor(se, off);
      if (lc == 0) {
        int row = wm * 128 + mi * 16 + lq * 4 + r;
        s_mx[row * 4 + wn] = mx; s_sm[row * 4 + wn] = se; s_ax[row * 4 + wn] = wn * 64 + ax;
      }
    }
  }
  __syncthreads();
  if (tid < 256) {
    float gm = s_mx[tid * 4]; int ga = s_ax[tid * 4];
    #pragma unroll
    for (int w = 1; w < 4; ++w) {
      float m = s_mx[tid * 4 + w];
      if (m > gm) { gm = m; ga = s_ax[tid * 4 + w]; }
    }
    float gs = 0.f;
    #pragma unroll
    for (int w = 0; w < 4; ++w) gs += s_sm[tid * 4 + w] * __expf(s_mx[tid * 4 + w] - gm);
    v4f rec; rec[0] = gm; rec[1] = gs; rec[2] = __int_as_float(n0 + ga); rec[3] = 0.f;
    partials[(size_t)(m0 + tid) * nch + blockIdx.y] = rec;
  }
}

// ---------------------------------------------------------------------------
// PIPELINED 128x128 GEMM bf16: BK=64, 4 waves, dbuf LDS (2 blk/CU).
template <int ASRC, int EPI>
__launch_bounds__(256, 2)
__global__ void k_gemm4(const u16* __restrict__ Abf, const u16* __restrict__ Bbf,
                        u16* __restrict__ Cbf, float* __restrict__ Cf32,
                        const int* __restrict__ keepArr, RmsSrc rs, int K, int ldb, int ldc) {
  __shared__ __align__(16) u16 lds[2][16384];
  const int tid = threadIdx.x;
  const int lane = tid & 63, wid = tid >> 6;
  const int wm = wid >> 1, wn = wid & 1;
  const int lc = lane & 15, lq = lane >> 4;
  const int m0 = blockIdx.x * 128, n0 = blockIdx.y * 128;

  const u16* srcA[4]; const u16* srcB[4];
  #pragma unroll
  for (int i = 0; i < 4; ++i) {
    int s = i * 256 + tid;
    int row = s >> 3;
    int c3 = (s & 7) ^ (row & 7);
    int ar = m0 + row;
    if constexpr (ASRC == ASRC_AOMAP) ar = (ar >> 4) * 17 + 1 + (ar & 15);
    srcA[i] = Abf + (size_t)ar * K + c3 * 8;
    srcB[i] = Bbf + (size_t)(n0 + row) * ldb + c3 * 8;
  }

  v4f acc[4][4];
  #pragma unroll
  for (int i = 0; i < 4; ++i)
    #pragma unroll
    for (int j = 0; j < 4; ++j) acc[i][j] = (v4f){0.f, 0.f, 0.f, 0.f};

  const int sw = lc & 7;
  const int aoff0 = (((wm * 64 + lc) * 8 + 0 + lq) ^ sw) * 8;
  const int aoff1 = (((wm * 64 + lc) * 8 + 4 + lq) ^ sw) * 8;
  const int boff0 = (((wn * 64 + lc) * 8 + 0 + lq) ^ sw) * 8;
  const int boff1 = (((wn * 64 + lc) * 8 + 4 + lq) ^ sw) * 8;

  auto stageTo = [&](int b) {
    u16* dA = &lds[b][0] + wid * 512;
    u16* dB = &lds[b][8192] + wid * 512;
    #pragma unroll
    for (int i = 0; i < 4; ++i) { gload16(dA + i * 2048, srcA[i]); srcA[i] += 64; }
    #pragma unroll
    for (int i = 0; i < 4; ++i) { gload16(dB + i * 2048, srcB[i]); srcB[i] += 64; }
  };

  stageTo(0);
  const int NT = K >> 6;
  for (int t = 0; t < NT; ++t) {
    const int cur = t & 1;
    if (t + 1 < NT) {
      stageTo(cur ^ 1);
      asm volatile("s_waitcnt vmcnt(8)" ::: "memory");
    } else {
      asm volatile("s_waitcnt vmcnt(0)" ::: "memory");
    }
    __builtin_amdgcn_s_barrier();
    const u16* Ab = &lds[cur][0];
    const u16* Bb = &lds[cur][8192];
    v8s a0[4], a1[4], b0[4], b1[4];
    #pragma unroll
    for (int mi = 0; mi < 4; ++mi) a0[mi] = *(const v8s*)(Ab + aoff0 + mi * 1024);
    #pragma unroll
    for (int ni = 0; ni < 4; ++ni) b0[ni] = *(const v8s*)(Bb + boff0 + ni * 1024);
    #pragma unroll
    for (int mi = 0; mi < 4; ++mi) a1[mi] = *(const v8s*)(Ab + aoff1 + mi * 1024);
    #pragma unroll
    for (int ni = 0; ni < 4; ++ni) b1[ni] = *(const v8s*)(Bb + boff1 + ni * 1024);
    __builtin_amdgcn_s_setprio(1);
    #pragma unroll
    for (int mi = 0; mi < 4; ++mi)
      #pragma unroll
      for (int ni = 0; ni < 4; ++ni)
        acc[mi][ni] = __builtin_amdgcn_mfma_f32_16x16x32_bf16(a0[mi], b0[ni], acc[mi][ni], 0, 0, 0);
    __builtin_amdgcn_s_setprio(0);
    asm volatile("s_waitcnt lgkmcnt(0)" ::: "memory");
    __builtin_amdgcn_sched_barrier(0);
    __builtin_amdgcn_s_barrier();
    __builtin_amdgcn_s_setprio(1);
    #pragma unroll
    for (int mi = 0; mi < 4; ++mi)
      #pragma unroll
      for (int ni = 0; ni < 4; ++ni)
        acc[mi][ni] = __builtin_amdgcn_mfma_f32_16x16x32_bf16(a1[mi], b1[ni], acc[mi][ni], 0, 0, 0);
    __builtin_amdgcn_s_setprio(0);
  }

  #pragma unroll
  for (int mi = 0; mi < 4; ++mi)
    #pragma unroll
    for (int ni = 0; ni < 4; ++ni)
      #pragma unroll
      for (int r = 0; r < 4; ++r) {
        int grow = m0 + wm * 64 + mi * 16 + lq * 4 + r;
        int gcol = n0 + wn * 64 + ni * 16 + lc;
        size_t idx = (size_t)grow * ldc + gcol;
        float vv = acc[mi][ni][r];
        if constexpr (EPI == EPI_BF16) {
          Cbf[idx] = f2bf(vv);
        } else if constexpr (EPI == EPI_OEMB) {
          int t_ = grow & 15, bn = grow >> 4;
          int tok = (t_ == 0) ? rs.ftok[bn] : cMASK;
          float kf = (float)keepArr[bn];
          Cf32[idx] = rs.emb[(size_t)tok * cD + gcol] + vv * kf;
        } else {  // EPI_DOWNACC
          Cf32[idx] += vv;
        }
      }
}

// ---------------------------------------------------------------------------
// FALLBACK GEMM (round-3): fp32 B converted during staging.
template <int ASRC, int BLAYOUT, int EPI>
__launch_bounds__(256)
__global__ void k_gemm(const u16* __restrict__ Abf, const float* __restrict__ Bw,
                       u16* Cbf, float* Cf32, const u16* Gaux,
                       const int* __restrict__ keepArr, v4f* __restrict__ partials,
                       RmsSrc rs, int K, int ldb, int ldc) {
  __shared__ __align__(16) u16 As[128][40];
  __shared__ __align__(16) u16 Bs[128][40];
  const int tid = threadIdx.x;
  const int m0 = blockIdx.x * 128, n0 = blockIdx.y * 128;
  const int lane = tid & 63, wid = tid >> 6;
  const int wm = wid >> 1, wn = wid & 1;
  const int lc = lane & 15, lk8 = (lane >> 4) * 8;
  const int srow = tid >> 2, sk8 = (tid & 3) * 8;
  v4f acc[4][4];
  #pragma unroll
  for (int i = 0; i < 4; ++i)
    #pragma unroll
    for (int j = 0; j < 4; ++j) acc[i][j] = (v4f){0.f, 0.f, 0.f, 0.f};

  for (int kt = 0; kt < K; kt += 32) {
    __syncthreads();
    for (int mm = srow; mm < 128; mm += 64) {
      if constexpr (ASRC == ASRC_BF16) {
        *(v8s*)&As[mm][sk8] = *(const v8s*)(Abf + (size_t)(m0 + mm) * K + kt + sk8);
      } else if constexpr (ASRC == ASRC_AOMAP) {
        int m = m0 + mm, bn = m >> 4, t = m & 15;
        *(v8s*)&As[mm][sk8] = *(const v8s*)(Abf + (size_t)(bn * 17 + 1 + t) * K + kt + sk8);
      } else {
        int R = m0 + mm;
        int j = R % 17, bn = R / 17, b = bn >> 7;
        const float* src; const float* nw;
        if (j == 0) { src = rs.hs + ((size_t)b * cS + rs.cpos[bn]) * cD; nw = rs.nchs; }
        else {
          int tok = (j == 1) ? rs.ftok[bn] : cMASK;
          src = rs.emb + (size_t)tok * cD; nw = rs.nattn;
        }
        float inv = rs.rowinv[R];
        const v4f* sp = (const v4f*)(src + kt + sk8);
        const v4f* np_ = (const v4f*)(nw + kt + sk8);
        v4f s0 = sp[0], s1 = sp[1], w0 = np_[0], w1 = np_[1];
        v8s pk;
        #pragma unroll
        for (int e = 0; e < 4; ++e) pk[e] = (short)f2bf(s0[e] * inv * w0[e]);
        #pragma unroll
        for (int e = 0; e < 4; ++e) pk[4 + e] = (short)f2bf(s1[e] * inv * w1[e]);
        *(v8s*)&As[mm][sk8] = pk;
      }
    }
    if constexpr (BLAYOUT == 1) {
      for (int nn = srow; nn < 128; nn += 64) {
        const v4f* bp = (const v4f*)(Bw + (size_t)(n0 + nn) * ldb + kt + sk8);
        v4f b0 = bp[0], b1 = bp[1];
        v8s pk;
        #pragma unroll
        for (int e = 0; e < 4; ++e) { pk[e] = (short)f2bf(b0[e]); pk[4 + e] = (short)f2bf(b1[e]); }
        *(v8s*)&Bs[nn][sk8] = pk;
      }
    } else {
      const int bn_ = tid & 127, kq = tid >> 7;
      for (int kk = kq; kk < 8; kk += 2) {
        const int k4 = kk * 4;
        const float* bp = Bw + (size_t)(kt + k4) * ldb + n0 + bn_;
        v4u pk;
        #pragma unroll
        for (int e = 0; e < 4; ++e) pk[e] = f2bf(bp[(size_t)e * ldb]);
        *(v4u*)&Bs[bn_][k4] = pk;
      }
    }
    __syncthreads();
    v8s af[4], bf_[4];
    #pragma unroll
    for (int i = 0; i < 4; ++i) af[i] = *(const v8s*)&As[wm * 64 + i * 16 + lc][lk8];
    #pragma unroll
    for (int i = 0; i < 4; ++i) bf_[i] = *(const v8s*)&Bs[wn * 64 + i * 16 + lc][lk8];
    #pragma unroll
    for (int mi = 0; mi < 4; ++mi)
      #pragma unroll
      for (int ni = 0; ni < 4; ++ni)
        acc[mi][ni] = __builtin_amdgcn_mfma_f32_16x16x32_bf16(af[mi], bf_[ni], acc[mi][ni], 0, 0, 0);
  }

  if constexpr (EPI == EPI_STATS) {
    __shared__ float s_mx[128][2], s_sm[128][2];
    __shared__ int s_ax[128][2];
    #pragma unroll
    for (int mi = 0; mi < 4; ++mi) {
      #pragma unroll
      for (int r = 0; r < 4; ++r) {
        float v0 = acc[mi][0][r], v1 = acc[mi][1][r], v2 = acc[mi][2][r], v3 = acc[mi][3][r];
        float mx = v0; int ax = lc;
        if (v1 > mx) { mx = v1; ax = 16 + lc; }
        if (v2 > mx) { mx = v2; ax = 32 + lc; }
        if (v3 > mx) { mx = v3; ax = 48 + lc; }
        #pragma unroll
        for (int off = 1; off < 16; off <<= 1) {
          float om = __shfl_xor(mx, off); int oa = __shfl_xor(ax, off);
          if (om > mx || (om == mx && oa < ax)) { mx = om; ax = oa; }
        }
        float se = __expf(v0 - mx) + __expf(v1 - mx) + __expf(v2 - mx) + __expf(v3 - mx);
        #pragma unroll
        for (int off = 1; off < 16; off <<= 1) se += __shfl_xor(se, off);
        if (lc == 0) {
          int lr = wm * 64 + mi * 16 + (lane >> 4) * 4 + r;
          s_mx[lr][wn] = mx; s_sm[lr][wn] = se; s_ax[lr][wn] = wn * 64 + ax;
        }
      }
    }
    __syncthreads();
    if (tid < 128) {
      float ma = s_mx[tid][0], mb = s_mx[tid][1];
      float gm = fmaxf(ma, mb);
      float gs = s_sm[tid][0] * __expf(ma - gm) + s_sm[tid][1] * __expf(mb - gm);
      int ga = (ma >= mb) ? s_ax[tid][0] : s_ax[tid][1];
      v4f rec; rec[0] = gm; rec[1] = gs; rec[2] = __int_as_float(n0 + ga); rec[3] = 0.f;
      partials[(size_t)(m0 + tid) * NCH + blockIdx.y] = rec;
    }
    return;
  } else {
    #pragma unroll
    for (int mi = 0; mi < 4; ++mi)
      #pragma unroll
      for (int ni = 0; ni < 4; ++ni)
        #pragma unroll
        for (int r = 0; r < 4; ++r) {
          int grow = m0 + wm * 64 + mi * 16 + (lane >> 4) * 4 + r;
          int gcol = n0 + wn * 64 + ni * 16 + lc;
          size_t idx = (size_t)grow * ldc + gcol;
          float vv = acc[mi][ni][r];
          if constexpr (EPI == EPI_BF16) {
            Cbf[idx] = f2bf(vv);
          } else if constexpr (EPI == EPI_SILU) {
            float g = bf2f(Gaux[idx]);
            Cbf[idx] = f2bf(vv * g / (1.0f + __expf(-g)));
          } else if constexpr (EPI == EPI_OEMB) {
            int t = grow & 15, bn = grow >> 4;
            int tok = (t == 0) ? rs.ftok[bn] : cMASK;
            float kf = (float)keepArr[bn];
            Cf32[idx] = rs.emb[(size_t)tok * cD + gcol] + vv * kf;
          } else {
            Cf32[idx] += vv;
          }
        }
  }
}

// ---------------------------------------------------------------------------
__global__ void k_rope(u16* __restrict__ qb, u16* __restrict__ kb,
                       const int* __restrict__ anchors, const int* __restrict__ cpos) {
  int r = blockIdx.x;
  int which = (r >= MKV);
  int rr = which ? r - MKV : r;
  int j = rr % 17, bn = rr / 17;
  if (!which && j == 0) return;
  u16* buf = which ? kb : qb;
  int pos = (which && j == 0) ? cpos[bn] : (anchors[bn] + j - 1);
  float fp = (float)pos;
  for (int p = threadIdx.x; p < cH * 64; p += 256) {
    int h = p >> 6, i = p & 63;
    size_t base = (size_t)rr * cD + h * cHD;
    float x1 = bf2f(buf[base + i]);
    float x2 = bf2f(buf[base + 64 + i]);
    float freq = powf(10000.0f, -((float)(2 * i)) / 128.0f);
    float ang = fp * freq;
    float sn = sinf(ang), cn = cosf(ang);
    buf[base + i]      = f2bf(x1 * cn - x2 * sn);
    buf[base + 64 + i] = f2bf(x2 * cn + x1 * sn);
  }
}

__global__ void k_attn(u16* __restrict__ qb, const u16* __restrict__ kb,
                       const u16* __restrict__ vb) {
  int blk = blockIdx.x;
  int h = blk % cH, bn = blk / cH;
  __shared__ float qs[16][128], ks[17][128], vs[17][128], ps[16][18];
  int lane = threadIdx.x;
  for (int e = lane; e < 16 * 128; e += 64) {
    int r = e >> 7, d = e & 127;
    qs[r][d] = bf2f(qb[((size_t)(bn * 17 + 1 + r)) * cD + h * cHD + d]);
  }
  for (int e = lane; e < 17 * 128; e += 64) {
    int r = e >> 7, d = e & 127;
    ks[r][d] = bf2f(kb[((size_t)(bn * 17 + r)) * cD + h * cHD + d]);
    vs[r][d] = bf2f(vb[((size_t)(bn * 17 + r)) * cD + h * cHD + d]);
  }
  __syncthreads();
  for (int e = lane; e < 16 * 17; e += 64) {
    int qi = e / 17, ki = e % 17;
    float s = 0.f;
    for (int d = 0; d < 128; ++d) s += qs[qi][d] * ks[ki][d];
    ps[qi][ki] = s * 0.08838834764831845f;
  }
  __syncthreads();
  if (lane < 16) {
    float m = -3e38f;
    for (int kk = 0; kk < 17; ++kk) m = fmaxf(m, ps[lane][kk]);
    float s = 0.f;
    for (int kk = 0; kk < 17; ++kk) { float e_ = __expf(ps[lane][kk] - m); ps[lane][kk] = e_; s += e_; }
    float is = 1.0f / s;
    for (int kk = 0; kk < 17; ++kk) ps[lane][kk] *= is;
  }
  __syncthreads();
  for (int e = lane; e < 16 * 128; e += 64) {
    int qi = e >> 7, d = e & 127;
    float s = 0.f;
    for (int kk = 0; kk < 17; ++kk) s += ps[qi][kk] * vs[kk][d];
    qb[((size_t)(bn * 17 + 1 + qi)) * cD + h * cHD + d] = f2bf(s);
  }
}

__global__ void k_tgt(const u16* __restrict__ hout, const float* __restrict__ Wlm,
                      const int* __restrict__ ids, const int* __restrict__ anchors,
                      int* __restrict__ tgt_tok, float* __restrict__ tgt_logit) {
  int w = threadIdx.x >> 6, lane = threadIdx.x & 63;
  int m = blockIdx.x * 4 + w;
  int bn = m >> 4, t = m & 15, b = bn / cNA;
  int label = anchors[bn] + t;
  int sl = (label < cS - 1) ? label : (cS - 1);
  int tok = ids[(size_t)b * cS + sl];
  const u16* hr = hout + (size_t)m * cD;
  const float* wr = Wlm + (size_t)tok * cD;
  float s = 0.f;
  for (int d = lane; d < cD; d += 64) s += bf2f(hr[d]) * wr[d];
  s = waveSum(s);
  if (lane == 0) { tgt_tok[m] = tok; tgt_logit[m] = s; }
}

__global__ void k_combine(const v4f* __restrict__ partials, const int* __restrict__ tgt_tok,
                          const float* __restrict__ tgt_logit, const int* __restrict__ keepArr,
                          const int* __restrict__ anchors, const float* __restrict__ lmask,
                          float* __restrict__ tokOut, int nch) {
  int m = blockIdx.x;
  int tid = threadIdx.x, lane = tid & 63, w = tid >> 6;
  float cm = -3.0e38f, cs = 0.f; int ca = 0x7fffffff;
  if (tid < nch) {
    v4f rec = partials[(size_t)m * nch + tid];
    cm = rec[0]; cs = rec[1]; ca = __float_as_int(rec[2]);
  }
  float gm = cm; int ga = ca;
  #pragma unroll
  for (int off = 1; off < 64; off <<= 1) {
    float om = __shfl_xor(gm, off); int oa = __shfl_xor(ga, off);
    if (om > gm || (om == gm && oa < ga)) { gm = om; ga = oa; }
  }
  __shared__ float wmx[4]; __shared__ int wax[4]; __shared__ float wsm[4];
  if (lane == 0) { wmx[w] = gm; wax[w] = ga; }
  __syncthreads();
  if (tid == 0) {
    for (int i = 1; i < 4; ++i)
      if (wmx[i] > wmx[0] || (wmx[i] == wmx[0] && wax[i] < wax[0])) { wmx[0] = wmx[i]; wax[0] = wax[i]; }
  }
  __syncthreads();
  gm = wmx[0]; ga = wax[0];
  float s = (tid < nch) ? cs * __expf(cm - gm) : 0.f;
  s = waveSum(s);
  if (lane == 0) wsm[w] = s;
  __syncthreads();
  if (tid == 0) {
    float gs = wsm[0] + wsm[1] + wsm[2] + wsm[3];
    float logZ = gm + logf(gs);
    int bn = m >> 4, t = m & 15, b = bn / cNA;
    int label = anchors[bn] + t;
    int sl = (label < cS - 1) ? label : (cS - 1);
    float wgt = (float)keepArr[bn] * ((t > 0) ? 1.f : 0.f) * ((label < cS) ? 1.f : 0.f) *
                lmask[(size_t)b * cS + sl];
    float lp = tgt_logit[m] - logZ;
    int tg = tgt_tok[m];
    tokOut[m * 4 + 0] = lp * wgt;
    tokOut[m * 4 + 1] = wgt;
    tokOut[m * 4 + 2] = ((ga == tg) && (wgt > 0.5f)) ? 1.f : 0.f;
    tokOut[m * 4 + 3] = 0.f;
  }
}

__global__ void k_final(const float* __restrict__ tokOut, float* __restrict__ outp) {
  int tid = threadIdx.x;
  float swl = 0.f, sw = 0.f, sm = 0.f;
  for (int m = tid; m < MTOK; m += 256) {
    swl += tokOut[m * 4 + 0];
    sw  += tokOut[m * 4 + 1];
    sm  += tokOut[m * 4 + 2];
  }
  swl = waveSum(swl); sw = waveSum(sw); sm = waveSum(sm);
  __shared__ float r0[4], r1[4], r2[4];
  int lane = tid & 63, w = tid >> 6;
  if (lane == 0) { r0[w] = swl; r1[w] = sw; r2[w] = sm; }
  __syncthreads();
  if (tid == 0) {
    float a = r0[0] + r0[1] + r0[2] + r0[3];
    float b = r1[0] + r1[1] + r1[2] + r1[3];
    float c = r2[0] + r2[1] + r2[2] + r2[3];
    float denom = b + 1e-6f;
    float loss = -a / denom;
    float acc  = c / denom;
    if (b == 0.0f) loss = -300.0f;
    outp[0] = loss;
    outp[1] = acc;
  }
}

__global__ void k_heartbeat(float* outp) {
  if (threadIdx.x == 0) { outp[0] = -55.0f; outp[1] = -55.0f; }
}
__global__ void k_sentinel(float* outp) {
  if (threadIdx.x == 0) { outp[0] = -777.0f; outp[1] = -777.0f; }
}

// ---------------------------------------------------------------------------
extern "C" void kernel_launch(void* const* d_in, const int* in_sizes, int n_in,
                              void* d_out, int out_size, void* d_ws, size_t ws_size,
                              hipStream_t stream) {
  const int*   ids   = (const int*)  d_in[0];
  const float* hs    = (const float*)d_in[1];
  const float* lmask = (const float*)d_in[2];
  const float* rv    = (const float*)d_in[3];
  const float* emb   = (const float*)d_in[4];
  const float* wlm   = (const float*)d_in[5];
  const float* wq    = (const float*)d_in[6];
  const float* wk    = (const float*)d_in[7];
  const float* wv    = (const float*)d_in[8];
  const float* wo    = (const float*)d_in[9];
  const float* wg    = (const float*)d_in[10];
  const float* wu    = (const float*)d_in[11];
  const float* wd    = (const float*)d_in[12];
  const float* nattn = (const float*)d_in[13];
  const float* nmlp  = (const float*)d_in[14];
  const float* nout  = (const float*)d_in[15];
  const float* nchs  = (const float*)d_in[16];
  (void)in_sizes; (void)n_in; (void)out_size;

  float* outp = (float*)d_out;
  k_heartbeat<<<dim3(1), 64, 0, stream>>>(outp);

  char* wsb = (char*)d_ws;
  size_t off = 0;
  auto alloc = [&](size_t bytes) -> void* {
    void* p = wsb + off;
    off = (off + bytes + 255) & ~(size_t)255;
    return p;
  };
  int*   anchors = (int*)  alloc((size_t)cB * cNA * 4);
  int*   keepA   = (int*)  alloc((size_t)cB * cNA * 4);
  int*   ftok    = (int*)  alloc((size_t)cB * cNA * 4);
  int*   cpos    = (int*)  alloc((size_t)cB * cNA * 4);
  int*   self    = (int*)  alloc((size_t)cB * NCAND * 4);
  float* rowinv  = (float*)alloc((size_t)MKV * 4);
  int*   ttok    = (int*)  alloc((size_t)MTOK * 4);
  float* tlogit  = (float*)alloc((size_t)MTOK * 4);
  float* tokOut  = (float*)alloc((size_t)MTOK * 4 * 4);

  const size_t szQ  = (size_t)MKV * cD * 2;           // 17.8 MB (q/attn-out/h/h_out)
  const size_t szX  = (size_t)MTOK * cD * 4;          // 33.6 MB (fp32 residual)
  u16* qb = (u16*)alloc(szQ);
  const size_t a1off = off;

  RmsSrc rs{hs, emb, nattn, nchs, rowinv, ftok, cpos};

  // common head
  k_select <<<dim3(cB * 16), 256, 0, stream>>>(lmask, rv, self);
  k_anchors<<<dim3(cB),      256, 0, stream>>>(lmask, self, ids, anchors, keepA, ftok, cpos);

  // ---------------- fast tier
  const size_t szKV   = szQ;
  const size_t szCbuf = (size_t)MTOK * 4096 * 2;      // CW = 4096
  size_t kvb_off  = a1off;
  size_t a1f_off  = (kvb_off + szKV + 255) & ~(size_t)255;
  size_t a1f_sz   = 2 * szQ > (szX + szCbuf) ? 2 * szQ : (szX + szCbuf);  // 67 MB
  size_t wreg_off = (a1f_off + a1f_sz + 255) & ~(size_t)255;
  size_t wreg_sz  = (size_t)cV * cD * 2;              // 131 MB (largest stage)
  size_t need_fast = wreg_off + wreg_sz;

  if (need_fast <= ws_size) {
    u16*   kvb   = (u16*)(wsb + kvb_off);
    u16*   kb    = (u16*)(wsb + a1f_off);
    u16*   vb    = (u16*)(wsb + a1f_off + szQ);
    float* xb    = (float*)(wsb + a1f_off);
    u16*   cbuf  = (u16*)(wsb + a1f_off + szX);
    v4f*   parts = (v4f*)(wsb + a1f_off);             // 8.2 MB (lm-head stage)
    u8*    h8    = (u8*)(wsb + a1f_off + (size_t)16 * 1024 * 1024);  // 8.4 MB
    u16*   hb    = qb;
    u16*   houtb = qb;
    u16*   wT    = (u16*)(wsb + wreg_off);
    const size_t szDD = (size_t)cD * cD;
    u16* wqT = wT;            u16* wkT = wT + szDD;
    u16* wvT = wT + 2 * szDD; u16* woT = wT + 3 * szDD;
    const size_t szDF = (size_t)cD * cDFF;
    u16* wgT = wT; u16* wuT = wT + szDF; u16* wdT = wT + 2 * szDF;
    u8*  wlm8 = (u8*)wT;                              // 65.5 MB (lm-head stage)

    k_build2<<<dim3(MKV), 256, 0, stream>>>(hs, emb, nattn, nchs, ftok, cpos, kvb);

    k_tconv<<<dim3(32, 32), 256, 0, stream>>>(wq, wqT, cD, cD);
    k_tconv<<<dim3(32, 32), 256, 0, stream>>>(wk, wkT, cD, cD);
    k_tconv<<<dim3(32, 32), 256, 0, stream>>>(wv, wvT, cD, cD);
    k_tconv<<<dim3(32, 32), 256, 0, stream>>>(wo, woT, cD, cD);

    k_gemm4<ASRC_BF16, EPI_BF16><<<dim3(MKV / 128, cD / 128), 256, 0, stream>>>(
        kvb, wqT, qb, nullptr, nullptr, rs, cD, cD, cD);
    k_gemm4<ASRC_BF16, EPI_BF16><<<dim3(MKV / 128, cD / 128), 256, 0, stream>>>(
        kvb, wkT, kb, nullptr, nullptr, rs, cD, cD, cD);
    k_gemm4<ASRC_BF16, EPI_BF16><<<dim3(MKV / 128, cD / 128), 256, 0, stream>>>(
        kvb, wvT, vb, nullptr, nullptr, rs, cD, cD, cD);

    k_rope<<<dim3(2 * MKV), 256, 0, stream>>>(qb, kb, anchors, cpos);
    k_attn<<<dim3(cB * cNA * cH), 64, 0, stream>>>(qb, kb, vb);

    k_gemm4<ASRC_AOMAP, EPI_OEMB><<<dim3(MTOK / 128, cD / 128), 256, 0, stream>>>(
        qb, woT, nullptr, xb, keepA, rs, cD, cD, cD);

    k_rms<<<dim3(MTOK), 256, 0, stream>>>(xb, nmlp, hb);

    k_tconv<<<dim3(128, 32), 256, 0, stream>>>(wg, wgT, cD, cDFF);
    k_tconv<<<dim3(128, 32), 256, 0, stream>>>(wu, wuT, cD, cDFF);
    k_tconv<<<dim3(32, 128), 256, 0, stream>>>(wd, wdT, cDFF, cD);

    for (int cb = 0; cb < cDFF; cb += 4096) {
      k_gemm6<EPI_BF16><<<dim3(MTOK / 256, 16), 512, 0, stream>>>(
          hb, wgT + (size_t)cb * cD, cbuf, nullptr, nullptr, cD, 4096, 0);
      k_gemm6<EPI_SILU><<<dim3(MTOK / 256, 16), 512, 0, stream>>>(
          hb, wuT + (size_t)cb * cD, cbuf, cbuf, nullptr, cD, 4096, 0);
      k_gemm4<ASRC_BF16, EPI_DOWNACC><<<dim3(MTOK / 128, cD / 128), 256, 0, stream>>>(
          cbuf, wdT + cb, nullptr, xb, nullptr, rs, 4096, cDFF, cD);
    }

    k_rms<<<dim3(MTOK), 256, 0, stream>>>(xb, nout, houtb);

    k_tgt<<<dim3(MTOK / 4), 256, 0, stream>>>(houtb, wlm, ids, anchors, ttok, tlogit);

    // fp8 lm-head (permuted layout): h_out -> fp8, wlm -> fp8 x64; logits = acc/64
    k_cvt8 <<<dim3(1024), 256, 0, stream>>>(houtb, h8, (long)MTOK * cD);
    k_conv8<<<dim3(2048), 256, 0, stream>>>(wlm, wlm8, (long)cV * cD, 64.0f);
    k_gemm8<<<dim3(MTOK / 256, NCH2), 512, 0, stream>>>(h8, wlm8, parts, cD, NCH2);

    k_combine<<<dim3(MTOK), 256, 0, stream>>>(parts, ttok, tlogit, keepA, anchors, lmask, tokOut, NCH2);
    k_final  <<<dim3(1), 256, 0, stream>>>(tokOut, outp);
    return;
  }

  // ---------------- fallback tier (round-3 path, fp32 weights in GEMM)
  const int cwopts[4] = {4096, 2048, 1024, 512};
  int CW = 0;
  for (int ci = 0; ci < 4; ++ci) {
    int cw = cwopts[ci];
    size_t cbufsz = (size_t)MTOK * cw * 2;
    size_t s1 = 2 * szQ;
    size_t s2 = szX + cbufsz;
    size_t sz = s1 > s2 ? s1 : s2;
    size_t pmin = (size_t)MTOK * NCH * 16;
    if (pmin > sz) sz = pmin;
    if (a1off + sz <= ws_size) { CW = cw; break; }
  }
  if (CW == 0) { k_sentinel<<<dim3(1), 64, 0, stream>>>(outp); return; }

  u16*   kb    = (u16*)(wsb + a1off);
  u16*   vb    = (u16*)(wsb + a1off + szQ);
  float* xb    = (float*)(wsb + a1off);
  u16*   cbuf  = (u16*)(wsb + a1off + szX);
  v4f*   parts = (v4f*)(wsb + a1off);
  u16*   hb    = qb;
  u16*   houtb = qb;

  k_rowinv<<<dim3(MKV), 256, 0, stream>>>(hs, emb, ftok, cpos, rowinv);

  k_gemm<ASRC_RMS, 0, EPI_BF16><<<dim3(MKV / 128, cD / 128), 256, 0, stream>>>(
      nullptr, wq, qb, nullptr, nullptr, nullptr, nullptr, rs, cD, cD, cD);
  k_gemm<ASRC_RMS, 0, EPI_BF16><<<dim3(MKV / 128, cD / 128), 256, 0, stream>>>(
      nullptr, wk, kb, nullptr, nullptr, nullptr, nullptr, rs, cD, cD, cD);
  k_gemm<ASRC_RMS, 0, EPI_BF16><<<dim3(MKV / 128, cD / 128), 256, 0, stream>>>(
      nullptr, wv, vb, nullptr, nullptr, nullptr, nullptr, rs, cD, cD, cD);

  k_rope<<<dim3(2 * MKV), 256, 0, stream>>>(qb, kb, anchors, cpos);
  k_attn<<<dim3(cB * cNA * cH), 64, 0, stream>>>(qb, kb, vb);

  k_gemm<ASRC_AOMAP, 0, EPI_OEMB><<<dim3(MTOK / 128, cD / 128), 256, 0, stream>>>(
      qb, wo, nullptr, xb, nullptr, keepA, nullptr, rs, cD, cD, cD);

  k_rms<<<dim3(MTOK), 256, 0, stream>>>(xb, nmlp, hb);

  for (int cb = 0; cb < cDFF; cb += CW) {
    k_gemm<ASRC_BF16, 0, EPI_BF16><<<dim3(MTOK / 128, CW / 128), 256, 0, stream>>>(
        hb, wg + cb, cbuf, nullptr, nullptr, nullptr, nullptr, rs, cD, cDFF, CW);
    k_gemm<ASRC_BF16, 0, EPI_SILU><<<dim3(MTOK / 128, CW / 128), 256, 0, stream>>>(
        hb, wu + cb, cbuf, nullptr, cbuf, nullptr, nullptr, rs, cD, cDFF, CW);
    k_gemm<ASRC_BF16, 0, EPI_DOWNACC><<<dim3(MTOK / 128, cD / 128), 256, 0, stream>>>(
        cbuf, wd + (size_t)cb * cD, nullptr, xb, nullptr, nullptr, nullptr, rs, CW, cD, cD);
  }

  k_rms<<<dim3(MTOK), 256, 0, stream>>>(xb, nout, houtb);

  k_tgt<<<dim3(MTOK / 4), 256, 0, stream>>>(houtb, wlm, ids, anchors, ttok, tlogit);
  k_gemm<ASRC_BF16, 1, EPI_STATS><<<dim3(MTOK / 128, cV / 128), 256, 0, stream>>>(
      houtb, wlm, nullptr, nullptr, nullptr, nullptr, parts, rs, cD, cD, 0);

  k_combine<<<dim3(MTOK), 256, 0, stream>>>(parts, ttok, tlogit, keepA, anchors, lmask, tokOut, NCH);
  k_final  <<<dim3(1), 256, 0, stream>>>(tokOut, outp);
}

// Round 13
// 1545.081 us; speedup vs baseline: 1.0722x; 1.0074x over previous
//
#include <hip/hip_runtime.h>
#include <math.h>

typedef unsigned short u16;
typedef unsigned char u8;
typedef short v8s __attribute__((ext_vector_type(8)));
typedef u16   v4u __attribute__((ext_vector_type(4)));
typedef float v4f __attribute__((ext_vector_type(4)));
typedef int   v2i __attribute__((ext_vector_type(2)));
typedef int   v4i __attribute__((ext_vector_type(4)));

#define DEVFN static __device__ __forceinline__

constexpr int cB = 2, cS = 4096, cD = 2048, cV = 32000, cH = 16, cHD = 128;
constexpr int cBS = 16, cNA = 128, cMASK = 31999, cDFF = 8192;
constexpr int NCAND = cS - cBS + 1;   // 4081 anchor candidates
constexpr int MTOK  = cB * cNA * cBS; // 4096 query tokens
constexpr int MKV   = cB * cNA * 17;  // 4352 kv rows (ctx + 16)
constexpr int NCH   = cV / 128;       // 250 vocab chunks (128-wide, fallback)
constexpr int NCH2  = cV / 256;       // 125 vocab chunks (256-wide, fast)

constexpr int EPI_BF16 = 0, EPI_SILU = 1, EPI_OEMB = 2, EPI_DOWNACC = 3, EPI_STATS = 4, EPI_GLU = 5;
constexpr int ASRC_BF16 = 0, ASRC_RMS = 1, ASRC_AOMAP = 2;

struct RmsSrc {
  const float* hs; const float* emb; const float* nattn; const float* nchs;
  const float* rowinv; const int* ftok; const int* cpos;
};

DEVFN u16 f2bf(float f) {               // RNE fp32 -> bf16
  union { float f; unsigned u; } a; a.f = f;
  unsigned u = a.u;
  u = u + 0x7fffu + ((u >> 16) & 1u);
  return (u16)(u >> 16);
}
DEVFN float bf2f(u16 h) {
  union { unsigned u; float f; } a; a.u = ((unsigned)h) << 16;
  return a.f;
}
DEVFN float waveSum(float v) {
  #pragma unroll
  for (int o = 32; o >= 1; o >>= 1) v += __shfl_xor(v, o);
  return v;
}
DEVFN void gload16(void* lds, const void* g) {
  __builtin_amdgcn_global_load_lds(
      (const __attribute__((address_space(1))) unsigned*)g,
      (__attribute__((address_space(3))) unsigned*)lds, 16, 0, 0);
}
DEVFN int pack4fp8(float a, float b, float c, float d) {
  int p = __builtin_amdgcn_cvt_pk_fp8_f32(a, b, 0, 0);
  p = __builtin_amdgcn_cvt_pk_fp8_f32(c, d, p, 1);
  return p;
}
// permuted output offset for fp8 buffers: within each 64B K-group,
// newpos = lq*16 + kh*8 + j  for k = kh*32 + lq*8 + j  (i multiple of 8)
DEVFN long perm8(long i) {
  return (i & ~63L) | (((i >> 3) & 3) << 4) | (((i >> 5) & 1) << 3);
}

// ---------------------------------------------------------------------------
__global__ void k_select(const float* __restrict__ lmask, const float* __restrict__ rv_in,
                         int* __restrict__ self) {
  int b = blockIdx.x >> 4, chunk = blockIdx.x & 15;
  __shared__ float rvs[4096];
  for (int i = threadIdx.x; i < NCAND; i += 256) {
    bool valid = lmask[(size_t)b * cS + i] > 0.5f;
    rvs[i] = valid ? rv_in[(size_t)b * NCAND + i] : 2.0f;
  }
  __syncthreads();
  int i = chunk * 256 + threadIdx.x;
  if (i < NCAND) {
    float v = rvs[i];
    int rank = 0;
    for (int j = 0; j < NCAND; ++j) {
      float u = rvs[j];
      rank += (u < v) || (u == v && j < i);
    }
    self[(size_t)b * NCAND + i] = (rank < cNA) ? 1 : 0;
  }
}

__global__ void k_anchors(const float* __restrict__ lmask, const int* __restrict__ self,
                          const int* __restrict__ ids, int* __restrict__ anchors,
                          int* __restrict__ keepA, int* __restrict__ ftok, int* __restrict__ cpos) {
  int b = blockIdx.x;
  __shared__ int flags[4096];
  __shared__ int ssum[256];
  __shared__ int soff[257];
  __shared__ int abuf[cNA];
  for (int i = threadIdx.x; i < 4096; i += 256)
    flags[i] = (i < NCAND) ? (self[(size_t)b * NCAND + i] && (lmask[(size_t)b * cS + i] > 0.5f)) : 0;
  if (threadIdx.x < cNA) abuf[threadIdx.x] = 0;
  __syncthreads();
  int s = 0;
  #pragma unroll
  for (int j = 0; j < 16; ++j) s += flags[threadIdx.x * 16 + j];
  ssum[threadIdx.x] = s;
  __syncthreads();
  if (threadIdx.x == 0) {
    int a = 0;
    for (int t = 0; t < 256; ++t) { soff[t] = a; a += ssum[t]; }
    soff[256] = a;
  }
  __syncthreads();
  int nsel = soff[256];
  int p = soff[threadIdx.x];
  for (int j = 0; j < 16; ++j) {
    int i = threadIdx.x * 16 + j;
    if (flags[i]) { if (p < cNA) abuf[p] = i; ++p; }
  }
  __syncthreads();
  if (threadIdx.x < cNA) {
    int q = threadIdx.x;
    int kp = (q < nsel) ? 1 : 0;
    int a = kp ? abuf[q] : 0;
    anchors[b * cNA + q] = a;
    keepA[b * cNA + q] = kp;
    int av = a; if (av < 0) av = 0; if (av > cS - 1) av = cS - 1;
    int tok = ids[(size_t)b * cS + av];
    ftok[b * cNA + q] = kp ? tok : cMASK;
    cpos[b * cNA + q] = (a - 1 > 0) ? (a - 1) : 0;
  }
}

// per-kv-row 1/rms (fallback tier)
__global__ void k_rowinv(const float* __restrict__ hs, const float* __restrict__ emb,
                         const int* __restrict__ ftok, const int* __restrict__ cpos,
                         float* __restrict__ rowinv) {
  int r = blockIdx.x;
  int j = r % 17, bn = r / 17, b = bn >> 7;
  const float* src = (j == 0) ? hs + ((size_t)b * cS + cpos[bn]) * cD
                              : emb + (size_t)((j == 1) ? ftok[bn] : cMASK) * cD;
  float ss = 0.f;
  for (int d = threadIdx.x; d < cD; d += 256) { float v = src[d]; ss += v * v; }
  ss = waveSum(ss);
  __shared__ float red[4];
  if ((threadIdx.x & 63) == 0) red[threadIdx.x >> 6] = ss;
  __syncthreads();
  if (threadIdx.x == 0) {
    float tot = red[0] + red[1] + red[2] + red[3];
    rowinv[r] = 1.0f / sqrtf(tot / cD + 1e-6f);
  }
}

// kv_in = rms'd rows, materialized bf16 (fast tier). grid: MKV x 256
__global__ void k_build2(const float* __restrict__ hs, const float* __restrict__ emb,
                         const float* __restrict__ nattn, const float* __restrict__ nchs,
                         const int* __restrict__ ftok, const int* __restrict__ cpos,
                         u16* __restrict__ kv) {
  int r = blockIdx.x;
  int j = r % 17, bn = r / 17, b = bn >> 7;
  const float* src; const float* w;
  if (j == 0) { src = hs + ((size_t)b * cS + cpos[bn]) * cD; w = nchs; }
  else {
    int tok = (j == 1) ? ftok[bn] : cMASK;
    src = emb + (size_t)tok * cD; w = nattn;
  }
  float ss = 0.f;
  for (int d = threadIdx.x; d < cD; d += 256) { float v = src[d]; ss += v * v; }
  ss = waveSum(ss);
  __shared__ float red[4];
  if ((threadIdx.x & 63) == 0) red[threadIdx.x >> 6] = ss;
  __syncthreads();
  float tot = red[0] + red[1] + red[2] + red[3];
  float inv = 1.0f / sqrtf(tot / cD + 1e-6f);
  for (int d = threadIdx.x; d < cD; d += 256)
    kv[(size_t)r * cD + d] = f2bf(src[d] * inv * w[d]);
}

// RMS over fp32 rows -> bf16
__global__ void k_rms(const float* __restrict__ xin, const float* __restrict__ w,
                      u16* __restrict__ outp) {
  int m = blockIdx.x;
  const float* row = xin + (size_t)m * cD;
  float ss = 0.f;
  for (int d = threadIdx.x; d < cD; d += 256) { float v = row[d]; ss += v * v; }
  ss = waveSum(ss);
  __shared__ float red[4];
  if ((threadIdx.x & 63) == 0) red[threadIdx.x >> 6] = ss;
  __syncthreads();
  float tot = red[0] + red[1] + red[2] + red[3];
  float inv = 1.0f / sqrtf(tot / cD + 1e-6f);
  for (int d = threadIdx.x; d < cD; d += 256)
    outp[(size_t)m * cD + d] = f2bf(row[d] * inv * w[d]);
}

// fp32 -> fp8 e4m3 with scale, PERMUTED 64B-group layout. 8 elems/thread
__global__ void k_conv8(const float* __restrict__ in, u8* __restrict__ out, long n, float scale) {
  long i = ((long)blockIdx.x * 256 + threadIdx.x) * 8;
  long stride = (long)gridDim.x * 256 * 8;
  for (; i < n; i += stride) {
    v4f a = *(const v4f*)(in + i), b = *(const v4f*)(in + i + 4);
    v2i pk;
    pk[0] = pack4fp8(a[0] * scale, a[1] * scale, a[2] * scale, a[3] * scale);
    pk[1] = pack4fp8(b[0] * scale, b[1] * scale, b[2] * scale, b[3] * scale);
    *(v2i*)(out + perm8(i)) = pk;
  }
}

// bf16 -> fp8 e4m3, PERMUTED 64B-group layout. 8 elems/thread
__global__ void k_cvt8(const u16* __restrict__ in, u8* __restrict__ out, long n) {
  long i = ((long)blockIdx.x * 256 + threadIdx.x) * 8;
  long stride = (long)gridDim.x * 256 * 8;
  for (; i < n; i += stride) {
    v8s a = *(const v8s*)(in + i);
    v2i pk;
    pk[0] = pack4fp8(bf2f((u16)a[0]), bf2f((u16)a[1]), bf2f((u16)a[2]), bf2f((u16)a[3]));
    pk[1] = pack4fp8(bf2f((u16)a[4]), bf2f((u16)a[5]), bf2f((u16)a[6]), bf2f((u16)a[7]));
    *(v2i*)(out + perm8(i)) = pk;
  }
}

// transpose-convert: W [K][N] fp32 -> WT [N][K] bf16. 64x64 tiles, grid (N/64, K/64)
__global__ void k_tconv(const float* __restrict__ W, u16* __restrict__ WT, int K, int N) {
  __shared__ u16 t[64][72];
  int n0 = blockIdx.x * 64, k0 = blockIdx.y * 64;
  int tid = threadIdx.x;
  int c4 = (tid & 15) * 4, r0 = tid >> 4;
  #pragma unroll
  for (int rr = 0; rr < 64; rr += 16) {
    int k = r0 + rr;
    v4f v = *(const v4f*)(W + (size_t)(k0 + k) * N + n0 + c4);
    #pragma unroll
    for (int e = 0; e < 4; ++e) t[c4 + e][k] = f2bf(v[e]);
  }
  __syncthreads();
  int n = tid >> 2, kq = (tid & 3) * 16;
  v8s o0, o1;
  #pragma unroll
  for (int e = 0; e < 8; ++e) { o0[e] = (short)t[n][kq + e]; o1[e] = (short)t[n][kq + 8 + e]; }
  *(v8s*)(WT + (size_t)(n0 + n) * K + k0 + kq) = o0;
  *(v8s*)(WT + (size_t)(n0 + n) * K + k0 + kq + 8) = o1;
}

// transpose-convert with gate/up column interleave: col j -> row (j>>4)*32 + goff + (j&15)
__global__ void k_tconv2(const float* __restrict__ W, u16* __restrict__ WT, int K, int N, int goff) {
  __shared__ u16 t[64][72];
  int n0 = blockIdx.x * 64, k0 = blockIdx.y * 64;
  int tid = threadIdx.x;
  int c4 = (tid & 15) * 4, r0 = tid >> 4;
  #pragma unroll
  for (int rr = 0; rr < 64; rr += 16) {
    int k = r0 + rr;
    v4f v = *(const v4f*)(W + (size_t)(k0 + k) * N + n0 + c4);
    #pragma unroll
    for (int e = 0; e < 4; ++e) t[c4 + e][k] = f2bf(v[e]);
  }
  __syncthreads();
  int n = tid >> 2, kq = (tid & 3) * 16;
  int gn = n0 + n;
  size_t rout = ((size_t)(gn >> 4) << 5) + goff + (gn & 15);
  v8s o0, o1;
  #pragma unroll
  for (int e = 0; e < 8; ++e) { o0[e] = (short)t[n][kq + e]; o1[e] = (short)t[n][kq + 8 + e]; }
  *(v8s*)(WT + rout * K + k0 + kq) = o0;
  *(v8s*)(WT + rout * K + k0 + kq + 8) = o1;
}

// ---------------------------------------------------------------------------
// 8-PHASE PIPELINED 256x256 GEMM bf16 (round-10 verified). K-split half-tiles.
// EPI_GLU: B is column-interleaved gate/up; out = up * silu(gate), 32 cols/wave.
template <int EPI>
__launch_bounds__(512, 1)
__global__ void k_gemm6(const u16* __restrict__ Abf, const u16* __restrict__ Bbf,
                        u16* __restrict__ Cbf, const u16* __restrict__ Gaux,
                        v4f* __restrict__ partials, int K, int ldc, int nch) {
  __shared__ __align__(16) u16 lds[65536];
  const int tid = threadIdx.x;
  const int lane = tid & 63, wid = tid >> 6;
  const int wm = wid >> 2, wn = wid & 3;
  const int lc = lane & 15, lq = lane >> 4;
  const int m0 = blockIdx.x * 256, n0 = blockIdx.y * 256;

  const u16* srcA[2]; const u16* srcB[2];
  #pragma unroll
  for (int i = 0; i < 2; ++i) {
    int s = i * 512 + tid;
    int row = s >> 2;
    int c2 = (s & 3) ^ ((row >> 1) & 3);
    srcA[i] = Abf + (size_t)(m0 + row) * K + c2 * 8;
    srcB[i] = Bbf + (size_t)(n0 + row) * K + c2 * 8;
  }

  v4f acc[8][4];
  #pragma unroll
  for (int i = 0; i < 8; ++i)
    #pragma unroll
    for (int j = 0; j < 4; ++j) acc[i][j] = (v4f){0.f, 0.f, 0.f, 0.f};

  const int fsw = lq ^ ((lc >> 1) & 3);
  int aoff[8], boff[4];
  #pragma unroll
  for (int mi = 0; mi < 8; ++mi) aoff[mi] = ((wm * 128 + mi * 16 + lc) * 4 + fsw) * 8;
  #pragma unroll
  for (int ni = 0; ni < 4; ++ni) boff[ni] = ((wn * 64 + ni * 16 + lc) * 4 + fsw) * 8;

  auto stageA = [&](int t, int kh) {
    int reg = (t & 1) * 32768 + kh * 8192;
    int koff = t * 64 + kh * 32;
    #pragma unroll
    for (int i = 0; i < 2; ++i)
      gload16(&lds[reg + i * 4096 + wid * 512], srcA[i] + koff);
  };
  auto stageB = [&](int t, int kh) {
    int reg = (t & 1) * 32768 + 16384 + kh * 8192;
    int koff = t * 64 + kh * 32;
    #pragma unroll
    for (int i = 0; i < 2; ++i)
      gload16(&lds[reg + i * 4096 + wid * 512], srcB[i] + koff);
  };

  stageA(0, 0); stageB(0, 0);
  stageA(0, 1); stageB(0, 1);
  stageA(1, 0); stageB(1, 0);
  asm volatile("s_waitcnt vmcnt(8)" ::: "memory");
  __builtin_amdgcn_s_barrier();

  const int NT = K >> 6;
  for (int t = 0; t < NT; ++t) {
    const int bufb = (t & 1) * 32768;
    const u16* Ab0 = &lds[bufb];
    const u16* Ab1 = &lds[bufb + 8192];
    const u16* Bb0 = &lds[bufb + 16384];
    const u16* Bb1 = &lds[bufb + 24576];
    v8s a_[4], b_[4];

    #pragma unroll
    for (int ni = 0; ni < 4; ++ni) b_[ni] = *(const v8s*)(Bb0 + boff[ni]);
    #pragma unroll
    for (int mi = 0; mi < 4; ++mi) a_[mi] = *(const v8s*)(Ab0 + aoff[mi]);
    if (t + 1 < NT) stageA(t + 1, 1);
    asm volatile("s_waitcnt lgkmcnt(0)" ::: "memory");
    __builtin_amdgcn_sched_barrier(0);
    __builtin_amdgcn_s_setprio(1);
    #pragma unroll
    for (int mi = 0; mi < 4; ++mi)
      #pragma unroll
      for (int ni = 0; ni < 4; ++ni)
        acc[mi][ni] = __builtin_amdgcn_mfma_f32_16x16x32_bf16(a_[mi], b_[ni], acc[mi][ni], 0, 0, 0);
    __builtin_amdgcn_s_setprio(0);
    __builtin_amdgcn_s_barrier();

    #pragma unroll
    for (int mi = 0; mi < 4; ++mi) a_[mi] = *(const v8s*)(Ab0 + aoff[mi + 4]);
    if (t + 1 < NT) stageB(t + 1, 1);
    asm volatile("s_waitcnt lgkmcnt(0)" ::: "memory");
    __builtin_amdgcn_sched_barrier(0);
    __builtin_amdgcn_s_setprio(1);
    #pragma unroll
    for (int mi = 0; mi < 4; ++mi)
      #pragma unroll
      for (int ni = 0; ni < 4; ++ni)
        acc[mi + 4][ni] = __builtin_amdgcn_mfma_f32_16x16x32_bf16(a_[mi], b_[ni], acc[mi + 4][ni], 0, 0, 0);
    __builtin_amdgcn_s_setprio(0);
    if (t + 1 < NT) { asm volatile("s_waitcnt vmcnt(4)" ::: "memory"); }
    else            { asm volatile("s_waitcnt vmcnt(0)" ::: "memory"); }
    __builtin_amdgcn_s_barrier();

    #pragma unroll
    for (int ni = 0; ni < 4; ++ni) b_[ni] = *(const v8s*)(Bb1 + boff[ni]);
    #pragma unroll
    for (int mi = 0; mi < 4; ++mi) a_[mi] = *(const v8s*)(Ab1 + aoff[mi]);
    if (t + 2 < NT) stageA(t + 2, 0);
    asm volatile("s_waitcnt lgkmcnt(0)" ::: "memory");
    __builtin_amdgcn_sched_barrier(0);
    __builtin_amdgcn_s_setprio(1);
    #pragma unroll
    for (int mi = 0; mi < 4; ++mi)
      #pragma unroll
      for (int ni = 0; ni < 4; ++ni)
        acc[mi][ni] = __builtin_amdgcn_mfma_f32_16x16x32_bf16(a_[mi], b_[ni], acc[mi][ni], 0, 0, 0);
    __builtin_amdgcn_s_setprio(0);
    __builtin_amdgcn_s_barrier();

    #pragma unroll
    for (int mi = 0; mi < 4; ++mi) a_[mi] = *(const v8s*)(Ab1 + aoff[mi + 4]);
    if (t + 2 < NT) stageB(t + 2, 0);
    asm volatile("s_waitcnt lgkmcnt(0)" ::: "memory");
    __builtin_amdgcn_sched_barrier(0);
    __builtin_amdgcn_s_setprio(1);
    #pragma unroll
    for (int mi = 0; mi < 4; ++mi)
      #pragma unroll
      for (int ni = 0; ni < 4; ++ni)
        acc[mi + 4][ni] = __builtin_amdgcn_mfma_f32_16x16x32_bf16(a_[mi], b_[ni], acc[mi + 4][ni], 0, 0, 0);
    __builtin_amdgcn_s_setprio(0);
    __builtin_amdgcn_s_barrier();
  }
  asm volatile("s_waitcnt vmcnt(0)" ::: "memory");

  if constexpr (EPI == EPI_GLU) {
    // ni even = gate fragment, ni odd = up fragment (column-interleaved B)
    #pragma unroll
    for (int mi = 0; mi < 8; ++mi)
      #pragma unroll
      for (int np = 0; np < 2; ++np)
        #pragma unroll
        for (int r = 0; r < 4; ++r) {
          int grow = m0 + wm * 128 + mi * 16 + lq * 4 + r;
          int gcol = (n0 >> 1) + wn * 32 + np * 16 + lc;
          float g = acc[mi][2 * np][r];
          float u = acc[mi][2 * np + 1][r];
          Cbf[(size_t)grow * ldc + gcol] = f2bf(u * g / (1.0f + __expf(-g)));
        }
  } else {
    #pragma unroll
    for (int mi = 0; mi < 8; ++mi)
      #pragma unroll
      for (int ni = 0; ni < 4; ++ni)
        #pragma unroll
        for (int r = 0; r < 4; ++r) {
          int grow = m0 + wm * 128 + mi * 16 + lq * 4 + r;
          int gcol = n0 + wn * 64 + ni * 16 + lc;
          size_t idx = (size_t)grow * ldc + gcol;
          float vv = acc[mi][ni][r];
          if constexpr (EPI == EPI_BF16) {
            Cbf[idx] = f2bf(vv);
          } else {  // EPI_SILU
            float g = bf2f(Gaux[idx]);
            Cbf[idx] = f2bf(vv * g / (1.0f + __expf(-g)));
          }
        }
  }
  (void)partials; (void)nch;
}

// ---------------------------------------------------------------------------
// 8-PHASE PIPELINED 256x256 GEMM fp8 e4m3, b128 fragment reads, TRIPLE-buffered
// LDS (96KB), 3-tile lookahead, per-tile vmcnt(8). STATS epilogue. logits=acc/64.
__launch_bounds__(512, 1)
__global__ void k_gemm8(const u8* __restrict__ A8, const u8* __restrict__ B8,
                        v4f* __restrict__ partials, int K, int nch) {
  // 96 KB: buf b at b*32768; A region 16KB at +0, B at +16384
  __shared__ __align__(16) u8 lds8[98304];
  const int tid = threadIdx.x;
  const int lane = tid & 63, wid = tid >> 6;
  const int wm = wid >> 2, wn = wid & 3;        // per-wave out 128x64
  const int lc = lane & 15, lq = lane >> 4;
  const int m0 = blockIdx.x * 256, n0 = blockIdx.y * 256;

  const u8* srcA[2]; const u8* srcB[2];
  #pragma unroll
  for (int i = 0; i < 2; ++i) {
    int ci = i * 512 + tid;
    int r = ci >> 2;
    int logc = (ci & 3) ^ ((r >> 1) & 3);
    srcA[i] = A8 + (size_t)(m0 + r) * K + logc * 16;
    srcB[i] = B8 + (size_t)(n0 + r) * K + logc * 16;
  }

  v4f acc[8][4];
  #pragma unroll
  for (int i = 0; i < 8; ++i)
    #pragma unroll
    for (int j = 0; j < 4; ++j) acc[i][j] = (v4f){0.f, 0.f, 0.f, 0.f};

  const int csw = (lc >> 1) & 3;
  int aoff[8], boff[4];
  #pragma unroll
  for (int mi = 0; mi < 8; ++mi) aoff[mi] = (wm * 128 + mi * 16 + lc) * 64 + ((lq ^ csw) << 4);
  #pragma unroll
  for (int ni = 0; ni < 4; ++ni) boff[ni] = (wn * 64 + ni * 16 + lc) * 64 + ((lq ^ csw) << 4);

  auto stageA = [&](int buf, int t, int i) {
    gload16(&lds8[buf * 32768 + i * 8192 + wid * 1024], srcA[i] + t * 64);
  };
  auto stageB = [&](int buf, int t, int i) {
    gload16(&lds8[buf * 32768 + 16384 + i * 8192 + wid * 1024], srcB[i] + t * 64);
  };

  // prologue: tiles 0,1,2 -> bufs 0,1,2 (12 issues); wait tile0 -> vmcnt(8)
  stageA(0, 0, 0); stageA(0, 0, 1); stageB(0, 0, 0); stageB(0, 0, 1);
  stageA(1, 1, 0); stageA(1, 1, 1); stageB(1, 1, 0); stageB(1, 1, 1);
  stageA(2, 2, 0); stageA(2, 2, 1); stageB(2, 2, 0); stageB(2, 2, 1);
  asm volatile("s_waitcnt vmcnt(8)" ::: "memory");
  __builtin_amdgcn_s_barrier();

  union Frag { v4i v; long long ll[2]; };
  const int NT = K >> 6;
  int cur = 0;
  for (int t = 0; t < NT; ++t) {
    const u8* Ab = &lds8[cur * 32768];
    const u8* Bb = Ab + 16384;
    Frag fa[8], fb[4];

    // q0: read all B + A0-3 (b128 each, both K-halves); MFMA kh0 mi0-3
    #pragma unroll
    for (int ni = 0; ni < 4; ++ni) fb[ni].v = *(const v4i*)(Bb + boff[ni]);
    #pragma unroll
    for (int mi = 0; mi < 4; ++mi) fa[mi].v = *(const v4i*)(Ab + aoff[mi]);
    asm volatile("s_waitcnt lgkmcnt(0)" ::: "memory");
    __builtin_amdgcn_sched_barrier(0);
    __builtin_amdgcn_s_setprio(1);
    #pragma unroll
    for (int mi = 0; mi < 4; ++mi)
      #pragma unroll
      for (int ni = 0; ni < 4; ++ni)
        acc[mi][ni] = __builtin_amdgcn_mfma_f32_16x16x32_fp8_fp8(fa[mi].ll[0], fb[ni].ll[0], acc[mi][ni], 0, 0, 0);
    __builtin_amdgcn_s_setprio(0);
    __builtin_amdgcn_s_barrier();

    // q1: read A4-7; stage B(t+3).0 into cur B-region (dead after q0 barrier)
    #pragma unroll
    for (int mi = 0; mi < 4; ++mi) fa[mi + 4].v = *(const v4i*)(Ab + aoff[mi + 4]);
    if (t + 3 < NT) stageB(cur, t + 3, 0);
    asm volatile("s_waitcnt lgkmcnt(0)" ::: "memory");
    __builtin_amdgcn_sched_barrier(0);
    __builtin_amdgcn_s_setprio(1);
    #pragma unroll
    for (int mi = 0; mi < 4; ++mi)
      #pragma unroll
      for (int ni = 0; ni < 4; ++ni)
        acc[mi + 4][ni] = __builtin_amdgcn_mfma_f32_16x16x32_fp8_fp8(fa[mi + 4].ll[0], fb[ni].ll[0], acc[mi + 4][ni], 0, 0, 0);
    __builtin_amdgcn_s_setprio(0);
    __builtin_amdgcn_s_barrier();

    // q2: no reads (kh1 from regs); stage B(t+3).1, A(t+3).0 (A dead after q1 barrier)
    if (t + 3 < NT) { stageB(cur, t + 3, 1); stageA(cur, t + 3, 0); }
    __builtin_amdgcn_s_setprio(1);
    #pragma unroll
    for (int mi = 0; mi < 4; ++mi)
      #pragma unroll
      for (int ni = 0; ni < 4; ++ni)
        acc[mi][ni] = __builtin_amdgcn_mfma_f32_16x16x32_fp8_fp8(fa[mi].ll[1], fb[ni].ll[1], acc[mi][ni], 0, 0, 0);
    __builtin_amdgcn_s_setprio(0);
    __builtin_amdgcn_s_barrier();

    // q3: stage A(t+3).1; MFMA kh1 mi4-7; counted vmcnt (t+1 landed)
    if (t + 3 < NT) stageA(cur, t + 3, 1);
    __builtin_amdgcn_s_setprio(1);
    #pragma unroll
    for (int mi = 0; mi < 4; ++mi)
      #pragma unroll
      for (int ni = 0; ni < 4; ++ni)
        acc[mi + 4][ni] = __builtin_amdgcn_mfma_f32_16x16x32_fp8_fp8(fa[mi + 4].ll[1], fb[ni].ll[1], acc[mi + 4][ni], 0, 0, 0);
    __builtin_amdgcn_s_setprio(0);
    if (t + 3 < NT) { asm volatile("s_waitcnt vmcnt(8)" ::: "memory"); }
    else            { asm volatile("s_waitcnt vmcnt(0)" ::: "memory"); }
    __builtin_amdgcn_s_barrier();
    cur = (cur == 2) ? 0 : cur + 1;
  }
  asm volatile("s_waitcnt vmcnt(0)" ::: "memory");

  // undo the x64 weight scale
  #pragma unroll
  for (int mi = 0; mi < 8; ++mi)
    #pragma unroll
    for (int ni = 0; ni < 4; ++ni)
      acc[mi][ni] *= 0.015625f;

  // epilogue scratch aliased onto (dead) staging LDS
  float* s_mx = (float*)lds8;
  float* s_sm = (float*)(lds8 + 4096);
  int*   s_ax = (int*)(lds8 + 8192);
  __syncthreads();
  #pragma unroll
  for (int mi = 0; mi < 8; ++mi) {
    #pragma unroll
    for (int r = 0; r < 4; ++r) {
      float v0 = acc[mi][0][r], v1 = acc[mi][1][r], v2 = acc[mi][2][r], v3 = acc[mi][3][r];
      float mx = v0; int ax = lc;
      if (v1 > mx) { mx = v1; ax = 16 + lc; }
      if (v2 > mx) { mx = v2; ax = 32 + lc; }
      if (v3 > mx) { mx = v3; ax = 48 + lc; }
      #pragma unroll
      for (int off = 1; off < 16; off <<= 1) {
        float om = __shfl_xor(mx, off); int oa = __shfl_xor(ax, off);
        if (om > mx || (om == mx && oa < ax)) { mx = om; ax = oa; }
      }
      float se = __expf(v0 - mx) + __expf(v1 - mx) + __expf(v2 - mx) + __expf(v3 - mx);
      #pragma unroll
      for (int off = 1; off < 16; off <<= 1) se += __shfl_xor(se, off);
      if (lc == 0) {
        int row = wm * 128 + mi * 16 + lq * 4 + r;
        s_mx[row * 4 + wn] = mx; s_sm[row * 4 + wn] = se; s_ax[row * 4 + wn] = wn * 64 + ax;
      }
    }
  }
  __syncthreads();
  if (tid < 256) {
    float gm = s_mx[tid * 4]; int ga = s_ax[tid * 4];
    #pragma unroll
    for (int w = 1; w < 4; ++w) {
      float m = s_mx[tid * 4 + w];
      if (m > gm) { gm = m; ga = s_ax[tid * 4 + w]; }
    }
    float gs = 0.f;
    #pragma unroll
    for (int w = 0; w < 4; ++w) gs += s_sm[tid * 4 + w] * __expf(s_mx[tid * 4 + w] - gm);
    v4f rec; rec[0] = gm; rec[1] = gs; rec[2] = __int_as_float(n0 + ga); rec[3] = 0.f;
    partials[(size_t)(m0 + tid) * nch + blockIdx.y] = rec;
  }
}

// ---------------------------------------------------------------------------
// PIPELINED 128x128 GEMM bf16: BK=64, 4 waves, dbuf LDS (2 blk/CU).
template <int ASRC, int EPI>
__launch_bounds__(256, 2)
__global__ void k_gemm4(const u16* __restrict__ Abf, const u16* __restrict__ Bbf,
                        u16* __restrict__ Cbf, float* __restrict__ Cf32,
                        const int* __restrict__ keepArr, RmsSrc rs, int K, int ldb, int ldc) {
  __shared__ __align__(16) u16 lds[2][16384];
  const int tid = threadIdx.x;
  const int lane = tid & 63, wid = tid >> 6;
  const int wm = wid >> 1, wn = wid & 1;
  const int lc = lane & 15, lq = lane >> 4;
  const int m0 = blockIdx.x * 128, n0 = blockIdx.y * 128;

  const u16* srcA[4]; const u16* srcB[4];
  #pragma unroll
  for (int i = 0; i < 4; ++i) {
    int s = i * 256 + tid;
    int row = s >> 3;
    int c3 = (s & 7) ^ (row & 7);
    int ar = m0 + row;
    if constexpr (ASRC == ASRC_AOMAP) ar = (ar >> 4) * 17 + 1 + (ar & 15);
    srcA[i] = Abf + (size_t)ar * K + c3 * 8;
    srcB[i] = Bbf + (size_t)(n0 + row) * ldb + c3 * 8;
  }

  v4f acc[4][4];
  #pragma unroll
  for (int i = 0; i < 4; ++i)
    #pragma unroll
    for (int j = 0; j < 4; ++j) acc[i][j] = (v4f){0.f, 0.f, 0.f, 0.f};

  const int sw = lc & 7;
  const int aoff0 = (((wm * 64 + lc) * 8 + 0 + lq) ^ sw) * 8;
  const int aoff1 = (((wm * 64 + lc) * 8 + 4 + lq) ^ sw) * 8;
  const int boff0 = (((wn * 64 + lc) * 8 + 0 + lq) ^ sw) * 8;
  const int boff1 = (((wn * 64 + lc) * 8 + 4 + lq) ^ sw) * 8;

  auto stageTo = [&](int b) {
    u16* dA = &lds[b][0] + wid * 512;
    u16* dB = &lds[b][8192] + wid * 512;
    #pragma unroll
    for (int i = 0; i < 4; ++i) { gload16(dA + i * 2048, srcA[i]); srcA[i] += 64; }
    #pragma unroll
    for (int i = 0; i < 4; ++i) { gload16(dB + i * 2048, srcB[i]); srcB[i] += 64; }
  };

  stageTo(0);
  const int NT = K >> 6;
  for (int t = 0; t < NT; ++t) {
    const int cur = t & 1;
    if (t + 1 < NT) {
      stageTo(cur ^ 1);
      asm volatile("s_waitcnt vmcnt(8)" ::: "memory");
    } else {
      asm volatile("s_waitcnt vmcnt(0)" ::: "memory");
    }
    __builtin_amdgcn_s_barrier();
    const u16* Ab = &lds[cur][0];
    const u16* Bb = &lds[cur][8192];
    v8s a0[4], a1[4], b0[4], b1[4];
    #pragma unroll
    for (int mi = 0; mi < 4; ++mi) a0[mi] = *(const v8s*)(Ab + aoff0 + mi * 1024);
    #pragma unroll
    for (int ni = 0; ni < 4; ++ni) b0[ni] = *(const v8s*)(Bb + boff0 + ni * 1024);
    #pragma unroll
    for (int mi = 0; mi < 4; ++mi) a1[mi] = *(const v8s*)(Ab + aoff1 + mi * 1024);
    #pragma unroll
    for (int ni = 0; ni < 4; ++ni) b1[ni] = *(const v8s*)(Bb + boff1 + ni * 1024);
    __builtin_amdgcn_s_setprio(1);
    #pragma unroll
    for (int mi = 0; mi < 4; ++mi)
      #pragma unroll
      for (int ni = 0; ni < 4; ++ni)
        acc[mi][ni] = __builtin_amdgcn_mfma_f32_16x16x32_bf16(a0[mi], b0[ni], acc[mi][ni], 0, 0, 0);
    __builtin_amdgcn_s_setprio(0);
    asm volatile("s_waitcnt lgkmcnt(0)" ::: "memory");
    __builtin_amdgcn_sched_barrier(0);
    __builtin_amdgcn_s_barrier();
    __builtin_amdgcn_s_setprio(1);
    #pragma unroll
    for (int mi = 0; mi < 4; ++mi)
      #pragma unroll
      for (int ni = 0; ni < 4; ++ni)
        acc[mi][ni] = __builtin_amdgcn_mfma_f32_16x16x32_bf16(a1[mi], b1[ni], acc[mi][ni], 0, 0, 0);
    __builtin_amdgcn_s_setprio(0);
  }

  #pragma unroll
  for (int mi = 0; mi < 4; ++mi)
    #pragma unroll
    for (int ni = 0; ni < 4; ++ni)
      #pragma unroll
      for (int r = 0; r < 4; ++r) {
        int grow = m0 + wm * 64 + mi * 16 + lq * 4 + r;
        int gcol = n0 + wn * 64 + ni * 16 + lc;
        size_t idx = (size_t)grow * ldc + gcol;
        float vv = acc[mi][ni][r];
        if constexpr (EPI == EPI_BF16) {
          Cbf[idx] = f2bf(vv);
        } else if constexpr (EPI == EPI_OEMB) {
          int t_ = grow & 15, bn = grow >> 4;
          int tok = (t_ == 0) ? rs.ftok[bn] : cMASK;
          float kf = (float)keepArr[bn];
          Cf32[idx] = rs.emb[(size_t)tok * cD + gcol] + vv * kf;
        } else {  // EPI_DOWNACC
          Cf32[idx] += vv;
        }
      }
}

// ---------------------------------------------------------------------------
// FALLBACK GEMM (round-3): fp32 B converted during staging.
template <int ASRC, int BLAYOUT, int EPI>
__launch_bounds__(256)
__global__ void k_gemm(const u16* __restrict__ Abf, const float* __restrict__ Bw,
                       u16* Cbf, float* Cf32, const u16* Gaux,
                       const int* __restrict__ keepArr, v4f* __restrict__ partials,
                       RmsSrc rs, int K, int ldb, int ldc) {
  __shared__ __align__(16) u16 As[128][40];
  __shared__ __align__(16) u16 Bs[128][40];
  const int tid = threadIdx.x;
  const int m0 = blockIdx.x * 128, n0 = blockIdx.y * 128;
  const int lane = tid & 63, wid = tid >> 6;
  const int wm = wid >> 1, wn = wid & 1;
  const int lc = lane & 15, lk8 = (lane >> 4) * 8;
  const int srow = tid >> 2, sk8 = (tid & 3) * 8;
  v4f acc[4][4];
  #pragma unroll
  for (int i = 0; i < 4; ++i)
    #pragma unroll
    for (int j = 0; j < 4; ++j) acc[i][j] = (v4f){0.f, 0.f, 0.f, 0.f};

  for (int kt = 0; kt < K; kt += 32) {
    __syncthreads();
    for (int mm = srow; mm < 128; mm += 64) {
      if constexpr (ASRC == ASRC_BF16) {
        *(v8s*)&As[mm][sk8] = *(const v8s*)(Abf + (size_t)(m0 + mm) * K + kt + sk8);
      } else if constexpr (ASRC == ASRC_AOMAP) {
        int m = m0 + mm, bn = m >> 4, t = m & 15;
        *(v8s*)&As[mm][sk8] = *(const v8s*)(Abf + (size_t)(bn * 17 + 1 + t) * K + kt + sk8);
      } else {
        int R = m0 + mm;
        int j = R % 17, bn = R / 17, b = bn >> 7;
        const float* src; const float* nw;
        if (j == 0) { src = rs.hs + ((size_t)b * cS + rs.cpos[bn]) * cD; nw = rs.nchs; }
        else {
          int tok = (j == 1) ? rs.ftok[bn] : cMASK;
          src = rs.emb + (size_t)tok * cD; nw = rs.nattn;
        }
        float inv = rs.rowinv[R];
        const v4f* sp = (const v4f*)(src + kt + sk8);
        const v4f* np_ = (const v4f*)(nw + kt + sk8);
        v4f s0 = sp[0], s1 = sp[1], w0 = np_[0], w1 = np_[1];
        v8s pk;
        #pragma unroll
        for (int e = 0; e < 4; ++e) pk[e] = (short)f2bf(s0[e] * inv * w0[e]);
        #pragma unroll
        for (int e = 0; e < 4; ++e) pk[4 + e] = (short)f2bf(s1[e] * inv * w1[e]);
        *(v8s*)&As[mm][sk8] = pk;
      }
    }
    if constexpr (BLAYOUT == 1) {
      for (int nn = srow; nn < 128; nn += 64) {
        const v4f* bp = (const v4f*)(Bw + (size_t)(n0 + nn) * ldb + kt + sk8);
        v4f b0 = bp[0], b1 = bp[1];
        v8s pk;
        #pragma unroll
        for (int e = 0; e < 4; ++e) { pk[e] = (short)f2bf(b0[e]); pk[4 + e] = (short)f2bf(b1[e]); }
        *(v8s*)&Bs[nn][sk8] = pk;
      }
    } else {
      const int bn_ = tid & 127, kq = tid >> 7;
      for (int kk = kq; kk < 8; kk += 2) {
        const int k4 = kk * 4;
        const float* bp = Bw + (size_t)(kt + k4) * ldb + n0 + bn_;
        v4u pk;
        #pragma unroll
        for (int e = 0; e < 4; ++e) pk[e] = f2bf(bp[(size_t)e * ldb]);
        *(v4u*)&Bs[bn_][k4] = pk;
      }
    }
    __syncthreads();
    v8s af[4], bf_[4];
    #pragma unroll
    for (int i = 0; i < 4; ++i) af[i] = *(const v8s*)&As[wm * 64 + i * 16 + lc][lk8];
    #pragma unroll
    for (int i = 0; i < 4; ++i) bf_[i] = *(const v8s*)&Bs[wn * 64 + i * 16 + lc][lk8];
    #pragma unroll
    for (int mi = 0; mi < 4; ++mi)
      #pragma unroll
      for (int ni = 0; ni < 4; ++ni)
        acc[mi][ni] = __builtin_amdgcn_mfma_f32_16x16x32_bf16(af[mi], bf_[ni], acc[mi][ni], 0, 0, 0);
  }

  if constexpr (EPI == EPI_STATS) {
    __shared__ float s_mx[128][2], s_sm[128][2];
    __shared__ int s_ax[128][2];
    #pragma unroll
    for (int mi = 0; mi < 4; ++mi) {
      #pragma unroll
      for (int r = 0; r < 4; ++r) {
        float v0 = acc[mi][0][r], v1 = acc[mi][1][r], v2 = acc[mi][2][r], v3 = acc[mi][3][r];
        float mx = v0; int ax = lc;
        if (v1 > mx) { mx = v1; ax = 16 + lc; }
        if (v2 > mx) { mx = v2; ax = 32 + lc; }
        if (v3 > mx) { mx = v3; ax = 48 + lc; }
        #pragma unroll
        for (int off = 1; off < 16; off <<= 1) {
          float om = __shfl_xor(mx, off); int oa = __shfl_xor(ax, off);
          if (om > mx || (om == mx && oa < ax)) { mx = om; ax = oa; }
        }
        float se = __expf(v0 - mx) + __expf(v1 - mx) + __expf(v2 - mx) + __expf(v3 - mx);
        #pragma unroll
        for (int off = 1; off < 16; off <<= 1) se += __shfl_xor(se, off);
        if (lc == 0) {
          int lr = wm * 64 + mi * 16 + (lane >> 4) * 4 + r;
          s_mx[lr][wn] = mx; s_sm[lr][wn] = se; s_ax[lr][wn] = wn * 64 + ax;
        }
      }
    }
    __syncthreads();
    if (tid < 128) {
      float ma = s_mx[tid][0], mb = s_mx[tid][1];
      float gm = fmaxf(ma, mb);
      float gs = s_sm[tid][0] * __expf(ma - gm) + s_sm[tid][1] * __expf(mb - gm);
      int ga = (ma >= mb) ? s_ax[tid][0] : s_ax[tid][1];
      v4f rec; rec[0] = gm; rec[1] = gs; rec[2] = __int_as_float(n0 + ga); rec[3] = 0.f;
      partials[(size_t)(m0 + tid) * NCH + blockIdx.y] = rec;
    }
    return;
  } else {
    #pragma unroll
    for (int mi = 0; mi < 4; ++mi)
      #pragma unroll
      for (int ni = 0; ni < 4; ++ni)
        #pragma unroll
        for (int r = 0; r < 4; ++r) {
          int grow = m0 + wm * 64 + mi * 16 + (lane >> 4) * 4 + r;
          int gcol = n0 + wn * 64 + ni * 16 + lc;
          size_t idx = (size_t)grow * ldc + gcol;
          float vv = acc[mi][ni][r];
          if constexpr (EPI == EPI_BF16) {
            Cbf[idx] = f2bf(vv);
          } else if constexpr (EPI == EPI_SILU) {
            float g = bf2f(Gaux[idx]);
            Cbf[idx] = f2bf(vv * g / (1.0f + __expf(-g)));
          } else if constexpr (EPI == EPI_OEMB) {
            int t = grow & 15, bn = grow >> 4;
            int tok = (t == 0) ? rs.ftok[bn] : cMASK;
            float kf = (float)keepArr[bn];
            Cf32[idx] = rs.emb[(size_t)tok * cD + gcol] + vv * kf;
          } else {
            Cf32[idx] += vv;
          }
        }
  }
}

// ---------------------------------------------------------------------------
__global__ void k_rope(u16* __restrict__ qb, u16* __restrict__ kb,
                       const int* __restrict__ anchors, const int* __restrict__ cpos) {
  int r = blockIdx.x;
  int which = (r >= MKV);
  int rr = which ? r - MKV : r;
  int j = rr % 17, bn = rr / 17;
  if (!which && j == 0) return;
  u16* buf = which ? kb : qb;
  int pos = (which && j == 0) ? cpos[bn] : (anchors[bn] + j - 1);
  float fp = (float)pos;
  for (int p = threadIdx.x; p < cH * 64; p += 256) {
    int h = p >> 6, i = p & 63;
    size_t base = (size_t)rr * cD + h * cHD;
    float x1 = bf2f(buf[base + i]);
    float x2 = bf2f(buf[base + 64 + i]);
    float freq = powf(10000.0f, -((float)(2 * i)) / 128.0f);
    float ang = fp * freq;
    float sn = sinf(ang), cn = cosf(ang);
    buf[base + i]      = f2bf(x1 * cn - x2 * sn);
    buf[base + 64 + i] = f2bf(x2 * cn + x1 * sn);
  }
}

__global__ void k_attn(u16* __restrict__ qb, const u16* __restrict__ kb,
                       const u16* __restrict__ vb) {
  int blk = blockIdx.x;
  int h = blk % cH, bn = blk / cH;
  __shared__ float qs[16][128], ks[17][128], vs[17][128], ps[16][18];
  int lane = threadIdx.x;
  for (int e = lane; e < 16 * 128; e += 64) {
    int r = e >> 7, d = e & 127;
    qs[r][d] = bf2f(qb[((size_t)(bn * 17 + 1 + r)) * cD + h * cHD + d]);
  }
  for (int e = lane; e < 17 * 128; e += 64) {
    int r = e >> 7, d = e & 127;
    ks[r][d] = bf2f(kb[((size_t)(bn * 17 + r)) * cD + h * cHD + d]);
    vs[r][d] = bf2f(vb[((size_t)(bn * 17 + r)) * cD + h * cHD + d]);
  }
  __syncthreads();
  for (int e = lane; e < 16 * 17; e += 64) {
    int qi = e / 17, ki = e % 17;
    float s = 0.f;
    for (int d = 0; d < 128; ++d) s += qs[qi][d] * ks[ki][d];
    ps[qi][ki] = s * 0.08838834764831845f;
  }
  __syncthreads();
  if (lane < 16) {
    float m = -3e38f;
    for (int kk = 0; kk < 17; ++kk) m = fmaxf(m, ps[lane][kk]);
    float s = 0.f;
    for (int kk = 0; kk < 17; ++kk) { float e_ = __expf(ps[lane][kk] - m); ps[lane][kk] = e_; s += e_; }
    float is = 1.0f / s;
    for (int kk = 0; kk < 17; ++kk) ps[lane][kk] *= is;
  }
  __syncthreads();
  for (int e = lane; e < 16 * 128; e += 64) {
    int qi = e >> 7, d = e & 127;
    float s = 0.f;
    for (int kk = 0; kk < 17; ++kk) s += ps[qi][kk] * vs[kk][d];
    qb[((size_t)(bn * 17 + 1 + qi)) * cD + h * cHD + d] = f2bf(s);
  }
}

__global__ void k_tgt(const u16* __restrict__ hout, const float* __restrict__ Wlm,
                      const int* __restrict__ ids, const int* __restrict__ anchors,
                      int* __restrict__ tgt_tok, float* __restrict__ tgt_logit) {
  int w = threadIdx.x >> 6, lane = threadIdx.x & 63;
  int m = blockIdx.x * 4 + w;
  int bn = m >> 4, t = m & 15, b = bn / cNA;
  int label = anchors[bn] + t;
  int sl = (label < cS - 1) ? label : (cS - 1);
  int tok = ids[(size_t)b * cS + sl];
  const u16* hr = hout + (size_t)m * cD;
  const float* wr = Wlm + (size_t)tok * cD;
  float s = 0.f;
  for (int d = lane; d < cD; d += 64) s += bf2f(hr[d]) * wr[d];
  s = waveSum(s);
  if (lane == 0) { tgt_tok[m] = tok; tgt_logit[m] = s; }
}

__global__ void k_combine(const v4f* __restrict__ partials, const int* __restrict__ tgt_tok,
                          const float* __restrict__ tgt_logit, const int* __restrict__ keepArr,
                          const int* __restrict__ anchors, const float* __restrict__ lmask,
                          float* __restrict__ tokOut, int nch) {
  int m = blockIdx.x;
  int tid = threadIdx.x, lane = tid & 63, w = tid >> 6;
  float cm = -3.0e38f, cs = 0.f; int ca = 0x7fffffff;
  if (tid < nch) {
    v4f rec = partials[(size_t)m * nch + tid];
    cm = rec[0]; cs = rec[1]; ca = __float_as_int(rec[2]);
  }
  float gm = cm; int ga = ca;
  #pragma unroll
  for (int off = 1; off < 64; off <<= 1) {
    float om = __shfl_xor(gm, off); int oa = __shfl_xor(ga, off);
    if (om > gm || (om == gm && oa < ga)) { gm = om; ga = oa; }
  }
  __shared__ float wmx[4]; __shared__ int wax[4]; __shared__ float wsm[4];
  if (lane == 0) { wmx[w] = gm; wax[w] = ga; }
  __syncthreads();
  if (tid == 0) {
    for (int i = 1; i < 4; ++i)
      if (wmx[i] > wmx[0] || (wmx[i] == wmx[0] && wax[i] < wax[0])) { wmx[0] = wmx[i]; wax[0] = wax[i]; }
  }
  __syncthreads();
  gm = wmx[0]; ga = wax[0];
  float s = (tid < nch) ? cs * __expf(cm - gm) : 0.f;
  s = waveSum(s);
  if (lane == 0) wsm[w] = s;
  __syncthreads();
  if (tid == 0) {
    float gs = wsm[0] + wsm[1] + wsm[2] + wsm[3];
    float logZ = gm + logf(gs);
    int bn = m >> 4, t = m & 15, b = bn / cNA;
    int label = anchors[bn] + t;
    int sl = (label < cS - 1) ? label : (cS - 1);
    float wgt = (float)keepArr[bn] * ((t > 0) ? 1.f : 0.f) * ((label < cS) ? 1.f : 0.f) *
                lmask[(size_t)b * cS + sl];
    float lp = tgt_logit[m] - logZ;
    int tg = tgt_tok[m];
    tokOut[m * 4 + 0] = lp * wgt;
    tokOut[m * 4 + 1] = wgt;
    tokOut[m * 4 + 2] = ((ga == tg) && (wgt > 0.5f)) ? 1.f : 0.f;
    tokOut[m * 4 + 3] = 0.f;
  }
}

__global__ void k_final(const float* __restrict__ tokOut, float* __restrict__ outp) {
  int tid = threadIdx.x;
  float swl = 0.f, sw = 0.f, sm = 0.f;
  for (int m = tid; m < MTOK; m += 256) {
    swl += tokOut[m * 4 + 0];
    sw  += tokOut[m * 4 + 1];
    sm  += tokOut[m * 4 + 2];
  }
  swl = waveSum(swl); sw = waveSum(sw); sm = waveSum(sm);
  __shared__ float r0[4], r1[4], r2[4];
  int lane = tid & 63, w = tid >> 6;
  if (lane == 0) { r0[w] = swl; r1[w] = sw; r2[w] = sm; }
  __syncthreads();
  if (tid == 0) {
    float a = r0[0] + r0[1] + r0[2] + r0[3];
    float b = r1[0] + r1[1] + r1[2] + r1[3];
    float c = r2[0] + r2[1] + r2[2] + r2[3];
    float denom = b + 1e-6f;
    float loss = -a / denom;
    float acc  = c / denom;
    if (b == 0.0f) loss = -300.0f;
    outp[0] = loss;
    outp[1] = acc;
  }
}

__global__ void k_heartbeat(float* outp) {
  if (threadIdx.x == 0) { outp[0] = -55.0f; outp[1] = -55.0f; }
}
__global__ void k_sentinel(float* outp) {
  if (threadIdx.x == 0) { outp[0] = -777.0f; outp[1] = -777.0f; }
}

// ---------------------------------------------------------------------------
extern "C" void kernel_launch(void* const* d_in, const int* in_sizes, int n_in,
                              void* d_out, int out_size, void* d_ws, size_t ws_size,
                              hipStream_t stream) {
  const int*   ids   = (const int*)  d_in[0];
  const float* hs    = (const float*)d_in[1];
  const float* lmask = (const float*)d_in[2];
  const float* rv    = (const float*)d_in[3];
  const float* emb   = (const float*)d_in[4];
  const float* wlm   = (const float*)d_in[5];
  const float* wq    = (const float*)d_in[6];
  const float* wk    = (const float*)d_in[7];
  const float* wv    = (const float*)d_in[8];
  const float* wo    = (const float*)d_in[9];
  const float* wg    = (const float*)d_in[10];
  const float* wu    = (const float*)d_in[11];
  const float* wd    = (const float*)d_in[12];
  const float* nattn = (const float*)d_in[13];
  const float* nmlp  = (const float*)d_in[14];
  const float* nout  = (const float*)d_in[15];
  const float* nchs  = (const float*)d_in[16];
  (void)in_sizes; (void)n_in; (void)out_size;

  float* outp = (float*)d_out;
  k_heartbeat<<<dim3(1), 64, 0, stream>>>(outp);

  char* wsb = (char*)d_ws;
  size_t off = 0;
  auto alloc = [&](size_t bytes) -> void* {
    void* p = wsb + off;
    off = (off + bytes + 255) & ~(size_t)255;
    return p;
  };
  int*   anchors = (int*)  alloc((size_t)cB * cNA * 4);
  int*   keepA   = (int*)  alloc((size_t)cB * cNA * 4);
  int*   ftok    = (int*)  alloc((size_t)cB * cNA * 4);
  int*   cpos    = (int*)  alloc((size_t)cB * cNA * 4);
  int*   self    = (int*)  alloc((size_t)cB * NCAND * 4);
  float* rowinv  = (float*)alloc((size_t)MKV * 4);
  int*   ttok    = (int*)  alloc((size_t)MTOK * 4);
  float* tlogit  = (float*)alloc((size_t)MTOK * 4);
  float* tokOut  = (float*)alloc((size_t)MTOK * 4 * 4);

  const size_t szQ  = (size_t)MKV * cD * 2;           // 17.8 MB (q/attn-out/h/h_out)
  const size_t szX  = (size_t)MTOK * cD * 4;          // 33.6 MB (fp32 residual)
  u16* qb = (u16*)alloc(szQ);
  const size_t a1off = off;

  RmsSrc rs{hs, emb, nattn, nchs, rowinv, ftok, cpos};

  // common head
  k_select <<<dim3(cB * 16), 256, 0, stream>>>(lmask, rv, self);
  k_anchors<<<dim3(cB),      256, 0, stream>>>(lmask, self, ids, anchors, keepA, ftok, cpos);

  // ---------------- fast tier
  const size_t szKV   = szQ;
  const size_t szCbuf = (size_t)MTOK * 4096 * 2;      // CW = 4096
  size_t kvb_off  = a1off;
  size_t a1f_off  = (kvb_off + szKV + 255) & ~(size_t)255;
  size_t a1f_sz   = 2 * szQ > (szX + szCbuf) ? 2 * szQ : (szX + szCbuf);  // 67 MB
  size_t wreg_off = (a1f_off + a1f_sz + 255) & ~(size_t)255;
  size_t wreg_sz  = (size_t)cV * cD * 2;              // 131 MB (largest stage)
  size_t need_fast = wreg_off + wreg_sz;

  if (need_fast <= ws_size) {
    u16*   kvb   = (u16*)(wsb + kvb_off);
    u16*   kb    = (u16*)(wsb + a1f_off);
    u16*   vb    = (u16*)(wsb + a1f_off + szQ);
    float* xb    = (float*)(wsb + a1f_off);
    u16*   cbuf  = (u16*)(wsb + a1f_off + szX);
    v4f*   parts = (v4f*)(wsb + a1f_off);             // 8.2 MB (lm-head stage)
    u8*    h8    = (u8*)(wsb + a1f_off + (size_t)16 * 1024 * 1024);  // 8.4 MB
    u16*   hb    = qb;
    u16*   houtb = qb;
    u16*   wT    = (u16*)(wsb + wreg_off);
    const size_t szDD = (size_t)cD * cD;
    u16* wqT = wT;            u16* wkT = wT + szDD;
    u16* wvT = wT + 2 * szDD; u16* woT = wT + 3 * szDD;
    const size_t szDF = (size_t)cD * cDFF;
    u16* wguT = wT;                                   // gate/up interleaved, 2*szDF
    u16* wdT  = wT + 2 * szDF;
    u8*  wlm8 = (u8*)wT;                              // 65.5 MB (lm-head stage)

    k_build2<<<dim3(MKV), 256, 0, stream>>>(hs, emb, nattn, nchs, ftok, cpos, kvb);

    k_tconv<<<dim3(32, 32), 256, 0, stream>>>(wq, wqT, cD, cD);
    k_tconv<<<dim3(32, 32), 256, 0, stream>>>(wk, wkT, cD, cD);
    k_tconv<<<dim3(32, 32), 256, 0, stream>>>(wv, wvT, cD, cD);
    k_tconv<<<dim3(32, 32), 256, 0, stream>>>(wo, woT, cD, cD);

    k_gemm4<ASRC_BF16, EPI_BF16><<<dim3(MKV / 128, cD / 128), 256, 0, stream>>>(
        kvb, wqT, qb, nullptr, nullptr, rs, cD, cD, cD);
    k_gemm4<ASRC_BF16, EPI_BF16><<<dim3(MKV / 128, cD / 128), 256, 0, stream>>>(
        kvb, wkT, kb, nullptr, nullptr, rs, cD, cD, cD);
    k_gemm4<ASRC_BF16, EPI_BF16><<<dim3(MKV / 128, cD / 128), 256, 0, stream>>>(
        kvb, wvT, vb, nullptr, nullptr, rs, cD, cD, cD);

    k_rope<<<dim3(2 * MKV), 256, 0, stream>>>(qb, kb, anchors, cpos);
    k_attn<<<dim3(cB * cNA * cH), 64, 0, stream>>>(qb, kb, vb);

    k_gemm4<ASRC_AOMAP, EPI_OEMB><<<dim3(MTOK / 128, cD / 128), 256, 0, stream>>>(
        qb, woT, nullptr, xb, keepA, rs, cD, cD, cD);

    k_rms<<<dim3(MTOK), 256, 0, stream>>>(xb, nmlp, hb);

    // gate/up interleaved transpose-convert; down normal
    k_tconv2<<<dim3(128, 32), 256, 0, stream>>>(wg, wguT, cD, cDFF, 0);
    k_tconv2<<<dim3(128, 32), 256, 0, stream>>>(wu, wguT, cD, cDFF, 16);
    k_tconv <<<dim3(32, 128), 256, 0, stream>>>(wd, wdT, cDFF, cD);

    for (int cb = 0; cb < cDFF; cb += 4096) {
      // fused gate+up: N' = 8192 interleaved cols -> 4096 outputs
      k_gemm6<EPI_GLU><<<dim3(MTOK / 256, 32), 512, 0, stream>>>(
          hb, wguT + (size_t)cb * 2 * cD, cbuf, nullptr, nullptr, cD, 4096, 0);
      k_gemm4<ASRC_BF16, EPI_DOWNACC><<<dim3(MTOK / 128, cD / 128), 256, 0, stream>>>(
          cbuf, wdT + cb, nullptr, xb, nullptr, rs, 4096, cDFF, cD);
    }

    k_rms<<<dim3(MTOK), 256, 0, stream>>>(xb, nout, houtb);

    k_tgt<<<dim3(MTOK / 4), 256, 0, stream>>>(houtb, wlm, ids, anchors, ttok, tlogit);

    // fp8 lm-head (permuted layout): h_out -> fp8, wlm -> fp8 x64; logits = acc/64
    k_cvt8 <<<dim3(1024), 256, 0, stream>>>(houtb, h8, (long)MTOK * cD);
    k_conv8<<<dim3(2048), 256, 0, stream>>>(wlm, wlm8, (long)cV * cD, 64.0f);
    k_gemm8<<<dim3(MTOK / 256, NCH2), 512, 0, stream>>>(h8, wlm8, parts, cD, NCH2);

    k_combine<<<dim3(MTOK), 256, 0, stream>>>(parts, ttok, tlogit, keepA, anchors, lmask, tokOut, NCH2);
    k_final  <<<dim3(1), 256, 0, stream>>>(tokOut, outp);
    return;
  }

  // ---------------- fallback tier (round-3 path, fp32 weights in GEMM)
  const int cwopts[4] = {4096, 2048, 1024, 512};
  int CW = 0;
  for (int ci = 0; ci < 4; ++ci) {
    int cw = cwopts[ci];
    size_t cbufsz = (size_t)MTOK * cw * 2;
    size_t s1 = 2 * szQ;
    size_t s2 = szX + cbufsz;
    size_t sz = s1 > s2 ? s1 : s2;
    size_t pmin = (size_t)MTOK * NCH * 16;
    if (pmin > sz) sz = pmin;
    if (a1off + sz <= ws_size) { CW = cw; break; }
  }
  if (CW == 0) { k_sentinel<<<dim3(1), 64, 0, stream>>>(outp); return; }

  u16*   kb    = (u16*)(wsb + a1off);
  u16*   vb    = (u16*)(wsb + a1off + szQ);
  float* xb    = (float*)(wsb + a1off);
  u16*   cbuf  = (u16*)(wsb + a1off + szX);
  v4f*   parts = (v4f*)(wsb + a1off);
  u16*   hb    = qb;
  u16*   houtb = qb;

  k_rowinv<<<dim3(MKV), 256, 0, stream>>>(hs, emb, ftok, cpos, rowinv);

  k_gemm<ASRC_RMS, 0, EPI_BF16><<<dim3(MKV / 128, cD / 128), 256, 0, stream>>>(
      nullptr, wq, qb, nullptr, nullptr, nullptr, nullptr, rs, cD, cD, cD);
  k_gemm<ASRC_RMS, 0, EPI_BF16><<<dim3(MKV / 128, cD / 128), 256, 0, stream>>>(
      nullptr, wk, kb, nullptr, nullptr, nullptr, nullptr, rs, cD, cD, cD);
  k_gemm<ASRC_RMS, 0, EPI_BF16><<<dim3(MKV / 128, cD / 128), 256, 0, stream>>>(
      nullptr, wv, vb, nullptr, nullptr, nullptr, nullptr, rs, cD, cD, cD);

  k_rope<<<dim3(2 * MKV), 256, 0, stream>>>(qb, kb, anchors, cpos);
  k_attn<<<dim3(cB * cNA * cH), 64, 0, stream>>>(qb, kb, vb);

  k_gemm<ASRC_AOMAP, 0, EPI_OEMB><<<dim3(MTOK / 128, cD / 128), 256, 0, stream>>>(
      qb, wo, nullptr, xb, nullptr, keepA, nullptr, rs, cD, cD, cD);

  k_rms<<<dim3(MTOK), 256, 0, stream>>>(xb, nmlp, hb);

  for (int cb = 0; cb < cDFF; cb += CW) {
    k_gemm<ASRC_BF16, 0, EPI_BF16><<<dim3(MTOK / 128, CW / 128), 256, 0, stream>>>(
        hb, wg + cb, cbuf, nullptr, nullptr, nullptr, nullptr, rs, cD, cDFF, CW);
    k_gemm<ASRC_BF16, 0, EPI_SILU><<<dim3(MTOK / 128, CW / 128), 256, 0, stream>>>(
        hb, wu + cb, cbuf, nullptr, cbuf, nullptr, nullptr, rs, cD, cDFF, CW);
    k_gemm<ASRC_BF16, 0, EPI_DOWNACC><<<dim3(MTOK / 128, cD / 128), 256, 0, stream>>>(
        cbuf, wd + (size_t)cb * cD, nullptr, xb, nullptr, nullptr, nullptr, rs, CW, cD, cD);
  }

  k_rms<<<dim3(MTOK), 256, 0, stream>>>(xb, nout, houtb);

  k_tgt<<<dim3(MTOK / 4), 256, 0, stream>>>(houtb, wlm, ids, anchors, ttok, tlogit);
  k_gemm<ASRC_BF16, 1, EPI_STATS><<<dim3(MTOK / 128, cV / 128), 256, 0, stream>>>(
      houtb, wlm, nullptr, nullptr, nullptr, nullptr, parts, rs, cD, cD, 0);

  k_combine<<<dim3(MTOK), 256, 0, stream>>>(parts, ttok, tlogit, keepA, anchors, lmask, tokOut, NCH);
  k_final  <<<dim3(1), 256, 0, stream>>>(tokOut, outp);
}

// Round 14
// 1497.322 us; speedup vs baseline: 1.1064x; 1.0319x over previous
//
#include <hip/hip_runtime.h>
#include <math.h>

typedef unsigned short u16;
typedef unsigned char u8;
typedef short v8s __attribute__((ext_vector_type(8)));
typedef u16   v4u __attribute__((ext_vector_type(4)));
typedef float v4f __attribute__((ext_vector_type(4)));
typedef int   v2i __attribute__((ext_vector_type(2)));
typedef int   v4i __attribute__((ext_vector_type(4)));

#define DEVFN static __device__ __forceinline__

constexpr int cB = 2, cS = 4096, cD = 2048, cV = 32000, cH = 16, cHD = 128;
constexpr int cBS = 16, cNA = 128, cMASK = 31999, cDFF = 8192;
constexpr int NCAND = cS - cBS + 1;   // 4081 anchor candidates
constexpr int MTOK  = cB * cNA * cBS; // 4096 query tokens
constexpr int MKV   = cB * cNA * 17;  // 4352 kv rows (ctx + 16)
constexpr int NCH   = cV / 128;       // 250 vocab chunks (128-wide, fallback)
constexpr int NCH2  = cV / 256;       // 125 vocab chunks (256-wide, fast)

constexpr int EPI_BF16 = 0, EPI_SILU = 1, EPI_OEMB = 2, EPI_DOWNACC = 3, EPI_STATS = 4, EPI_GLU = 5;
constexpr int ASRC_BF16 = 0, ASRC_RMS = 1, ASRC_AOMAP = 2;

struct RmsSrc {
  const float* hs; const float* emb; const float* nattn; const float* nchs;
  const float* rowinv; const int* ftok; const int* cpos;
};

DEVFN u16 f2bf(float f) {               // RNE fp32 -> bf16
  union { float f; unsigned u; } a; a.f = f;
  unsigned u = a.u;
  u = u + 0x7fffu + ((u >> 16) & 1u);
  return (u16)(u >> 16);
}
DEVFN float bf2f(u16 h) {
  union { unsigned u; float f; } a; a.u = ((unsigned)h) << 16;
  return a.f;
}
DEVFN float waveSum(float v) {
  #pragma unroll
  for (int o = 32; o >= 1; o >>= 1) v += __shfl_xor(v, o);
  return v;
}
DEVFN void gload16(void* lds, const void* g) {
  __builtin_amdgcn_global_load_lds(
      (const __attribute__((address_space(1))) unsigned*)g,
      (__attribute__((address_space(3))) unsigned*)lds, 16, 0, 0);
}
DEVFN int pack4fp8(float a, float b, float c, float d) {
  int p = __builtin_amdgcn_cvt_pk_fp8_f32(a, b, 0, 0);
  p = __builtin_amdgcn_cvt_pk_fp8_f32(c, d, p, 1);
  return p;
}
// permuted output offset for fp8 buffers: within each 64B K-group,
// newpos = lq*16 + kh*8 + j  for k = kh*32 + lq*8 + j  (i multiple of 8)
DEVFN long perm8(long i) {
  return (i & ~63L) | (((i >> 3) & 3) << 4) | (((i >> 5) & 1) << 3);
}

// ---------------------------------------------------------------------------
__global__ void k_select(const float* __restrict__ lmask, const float* __restrict__ rv_in,
                         int* __restrict__ self) {
  int b = blockIdx.x >> 4, chunk = blockIdx.x & 15;
  __shared__ float rvs[4096];
  for (int i = threadIdx.x; i < NCAND; i += 256) {
    bool valid = lmask[(size_t)b * cS + i] > 0.5f;
    rvs[i] = valid ? rv_in[(size_t)b * NCAND + i] : 2.0f;
  }
  __syncthreads();
  int i = chunk * 256 + threadIdx.x;
  if (i < NCAND) {
    float v = rvs[i];
    int rank = 0;
    for (int j = 0; j < NCAND; ++j) {
      float u = rvs[j];
      rank += (u < v) || (u == v && j < i);
    }
    self[(size_t)b * NCAND + i] = (rank < cNA) ? 1 : 0;
  }
}

__global__ void k_anchors(const float* __restrict__ lmask, const int* __restrict__ self,
                          const int* __restrict__ ids, int* __restrict__ anchors,
                          int* __restrict__ keepA, int* __restrict__ ftok, int* __restrict__ cpos) {
  int b = blockIdx.x;
  __shared__ int flags[4096];
  __shared__ int ssum[256];
  __shared__ int soff[257];
  __shared__ int abuf[cNA];
  for (int i = threadIdx.x; i < 4096; i += 256)
    flags[i] = (i < NCAND) ? (self[(size_t)b * NCAND + i] && (lmask[(size_t)b * cS + i] > 0.5f)) : 0;
  if (threadIdx.x < cNA) abuf[threadIdx.x] = 0;
  __syncthreads();
  int s = 0;
  #pragma unroll
  for (int j = 0; j < 16; ++j) s += flags[threadIdx.x * 16 + j];
  ssum[threadIdx.x] = s;
  __syncthreads();
  if (threadIdx.x == 0) {
    int a = 0;
    for (int t = 0; t < 256; ++t) { soff[t] = a; a += ssum[t]; }
    soff[256] = a;
  }
  __syncthreads();
  int nsel = soff[256];
  int p = soff[threadIdx.x];
  for (int j = 0; j < 16; ++j) {
    int i = threadIdx.x * 16 + j;
    if (flags[i]) { if (p < cNA) abuf[p] = i; ++p; }
  }
  __syncthreads();
  if (threadIdx.x < cNA) {
    int q = threadIdx.x;
    int kp = (q < nsel) ? 1 : 0;
    int a = kp ? abuf[q] : 0;
    anchors[b * cNA + q] = a;
    keepA[b * cNA + q] = kp;
    int av = a; if (av < 0) av = 0; if (av > cS - 1) av = cS - 1;
    int tok = ids[(size_t)b * cS + av];
    ftok[b * cNA + q] = kp ? tok : cMASK;
    cpos[b * cNA + q] = (a - 1 > 0) ? (a - 1) : 0;
  }
}

// per-kv-row 1/rms (fallback tier)
__global__ void k_rowinv(const float* __restrict__ hs, const float* __restrict__ emb,
                         const int* __restrict__ ftok, const int* __restrict__ cpos,
                         float* __restrict__ rowinv) {
  int r = blockIdx.x;
  int j = r % 17, bn = r / 17, b = bn >> 7;
  const float* src = (j == 0) ? hs + ((size_t)b * cS + cpos[bn]) * cD
                              : emb + (size_t)((j == 1) ? ftok[bn] : cMASK) * cD;
  float ss = 0.f;
  for (int d = threadIdx.x; d < cD; d += 256) { float v = src[d]; ss += v * v; }
  ss = waveSum(ss);
  __shared__ float red[4];
  if ((threadIdx.x & 63) == 0) red[threadIdx.x >> 6] = ss;
  __syncthreads();
  if (threadIdx.x == 0) {
    float tot = red[0] + red[1] + red[2] + red[3];
    rowinv[r] = 1.0f / sqrtf(tot / cD + 1e-6f);
  }
}

// kv_in = rms'd rows, materialized bf16 (fast tier). grid: MKV x 256
__global__ void k_build2(const float* __restrict__ hs, const float* __restrict__ emb,
                         const float* __restrict__ nattn, const float* __restrict__ nchs,
                         const int* __restrict__ ftok, const int* __restrict__ cpos,
                         u16* __restrict__ kv) {
  int r = blockIdx.x;
  int j = r % 17, bn = r / 17, b = bn >> 7;
  const float* src; const float* w;
  if (j == 0) { src = hs + ((size_t)b * cS + cpos[bn]) * cD; w = nchs; }
  else {
    int tok = (j == 1) ? ftok[bn] : cMASK;
    src = emb + (size_t)tok * cD; w = nattn;
  }
  float ss = 0.f;
  for (int d = threadIdx.x; d < cD; d += 256) { float v = src[d]; ss += v * v; }
  ss = waveSum(ss);
  __shared__ float red[4];
  if ((threadIdx.x & 63) == 0) red[threadIdx.x >> 6] = ss;
  __syncthreads();
  float tot = red[0] + red[1] + red[2] + red[3];
  float inv = 1.0f / sqrtf(tot / cD + 1e-6f);
  for (int d = threadIdx.x; d < cD; d += 256)
    kv[(size_t)r * cD + d] = f2bf(src[d] * inv * w[d]);
}

// RMS over fp32 rows -> bf16
__global__ void k_rms(const float* __restrict__ xin, const float* __restrict__ w,
                      u16* __restrict__ outp) {
  int m = blockIdx.x;
  const float* row = xin + (size_t)m * cD;
  float ss = 0.f;
  for (int d = threadIdx.x; d < cD; d += 256) { float v = row[d]; ss += v * v; }
  ss = waveSum(ss);
  __shared__ float red[4];
  if ((threadIdx.x & 63) == 0) red[threadIdx.x >> 6] = ss;
  __syncthreads();
  float tot = red[0] + red[1] + red[2] + red[3];
  float inv = 1.0f / sqrtf(tot / cD + 1e-6f);
  for (int d = threadIdx.x; d < cD; d += 256)
    outp[(size_t)m * cD + d] = f2bf(row[d] * inv * w[d]);
}

// fp32 -> fp8 e4m3 with scale, PERMUTED 64B-group layout. 8 elems/thread
__global__ void k_conv8(const float* __restrict__ in, u8* __restrict__ out, long n, float scale) {
  long i = ((long)blockIdx.x * 256 + threadIdx.x) * 8;
  long stride = (long)gridDim.x * 256 * 8;
  for (; i < n; i += stride) {
    v4f a = *(const v4f*)(in + i), b = *(const v4f*)(in + i + 4);
    v2i pk;
    pk[0] = pack4fp8(a[0] * scale, a[1] * scale, a[2] * scale, a[3] * scale);
    pk[1] = pack4fp8(b[0] * scale, b[1] * scale, b[2] * scale, b[3] * scale);
    *(v2i*)(out + perm8(i)) = pk;
  }
}

// bf16 -> fp8 e4m3, PERMUTED 64B-group layout. 8 elems/thread
__global__ void k_cvt8(const u16* __restrict__ in, u8* __restrict__ out, long n) {
  long i = ((long)blockIdx.x * 256 + threadIdx.x) * 8;
  long stride = (long)gridDim.x * 256 * 8;
  for (; i < n; i += stride) {
    v8s a = *(const v8s*)(in + i);
    v2i pk;
    pk[0] = pack4fp8(bf2f((u16)a[0]), bf2f((u16)a[1]), bf2f((u16)a[2]), bf2f((u16)a[3]));
    pk[1] = pack4fp8(bf2f((u16)a[4]), bf2f((u16)a[5]), bf2f((u16)a[6]), bf2f((u16)a[7]));
    *(v2i*)(out + perm8(i)) = pk;
  }
}

// transpose-convert: W [K][N] fp32 -> WT [N][K] bf16. 64x64 tiles, grid (N/64, K/64)
__global__ void k_tconv(const float* __restrict__ W, u16* __restrict__ WT, int K, int N) {
  __shared__ u16 t[64][72];
  int n0 = blockIdx.x * 64, k0 = blockIdx.y * 64;
  int tid = threadIdx.x;
  int c4 = (tid & 15) * 4, r0 = tid >> 4;
  #pragma unroll
  for (int rr = 0; rr < 64; rr += 16) {
    int k = r0 + rr;
    v4f v = *(const v4f*)(W + (size_t)(k0 + k) * N + n0 + c4);
    #pragma unroll
    for (int e = 0; e < 4; ++e) t[c4 + e][k] = f2bf(v[e]);
  }
  __syncthreads();
  int n = tid >> 2, kq = (tid & 3) * 16;
  v8s o0, o1;
  #pragma unroll
  for (int e = 0; e < 8; ++e) { o0[e] = (short)t[n][kq + e]; o1[e] = (short)t[n][kq + 8 + e]; }
  *(v8s*)(WT + (size_t)(n0 + n) * K + k0 + kq) = o0;
  *(v8s*)(WT + (size_t)(n0 + n) * K + k0 + kq + 8) = o1;
}

// transpose + gate/up interleave + fp8(scale) + perm8: col j -> row (j>>4)*32+goff+(j&15)
__global__ void k_tconv8(const float* __restrict__ W, u8* __restrict__ WT8,
                         int K, int N, int goff, float scale) {
  __shared__ float tf[64][65];
  int n0 = blockIdx.x * 64, k0 = blockIdx.y * 64;
  int tid = threadIdx.x;
  int c4 = (tid & 15) * 4, r0 = tid >> 4;
  #pragma unroll
  for (int rr = 0; rr < 64; rr += 16) {
    int k = r0 + rr;
    v4f v = *(const v4f*)(W + (size_t)(k0 + k) * N + n0 + c4);
    #pragma unroll
    for (int e = 0; e < 4; ++e) tf[c4 + e][k] = v[e];
  }
  __syncthreads();
  int n = tid >> 2, kq = (tid & 3) * 16;
  int gn = n0 + n;
  size_t rout = ((size_t)(gn >> 4) << 5) + goff + (gn & 15);
  long base = (long)rout * K + k0 + kq;
  v2i p0, p1;
  p0[0] = pack4fp8(tf[n][kq + 0] * scale, tf[n][kq + 1] * scale, tf[n][kq + 2] * scale, tf[n][kq + 3] * scale);
  p0[1] = pack4fp8(tf[n][kq + 4] * scale, tf[n][kq + 5] * scale, tf[n][kq + 6] * scale, tf[n][kq + 7] * scale);
  p1[0] = pack4fp8(tf[n][kq + 8] * scale, tf[n][kq + 9] * scale, tf[n][kq + 10] * scale, tf[n][kq + 11] * scale);
  p1[1] = pack4fp8(tf[n][kq + 12] * scale, tf[n][kq + 13] * scale, tf[n][kq + 14] * scale, tf[n][kq + 15] * scale);
  *(v2i*)(WT8 + perm8(base)) = p0;
  *(v2i*)(WT8 + perm8(base + 8)) = p1;
}

// ---------------------------------------------------------------------------
// 8-PHASE PIPELINED 256x256 GEMM bf16 (round-10 verified). K-split half-tiles.
// EPI_GLU: B is column-interleaved gate/up; out = up * silu(gate), 32 cols/wave.
template <int EPI>
__launch_bounds__(512, 1)
__global__ void k_gemm6(const u16* __restrict__ Abf, const u16* __restrict__ Bbf,
                        u16* __restrict__ Cbf, const u16* __restrict__ Gaux,
                        v4f* __restrict__ partials, int K, int ldc, int nch) {
  __shared__ __align__(16) u16 lds[65536];
  const int tid = threadIdx.x;
  const int lane = tid & 63, wid = tid >> 6;
  const int wm = wid >> 2, wn = wid & 3;
  const int lc = lane & 15, lq = lane >> 4;
  const int m0 = blockIdx.x * 256, n0 = blockIdx.y * 256;

  const u16* srcA[2]; const u16* srcB[2];
  #pragma unroll
  for (int i = 0; i < 2; ++i) {
    int s = i * 512 + tid;
    int row = s >> 2;
    int c2 = (s & 3) ^ ((row >> 1) & 3);
    srcA[i] = Abf + (size_t)(m0 + row) * K + c2 * 8;
    srcB[i] = Bbf + (size_t)(n0 + row) * K + c2 * 8;
  }

  v4f acc[8][4];
  #pragma unroll
  for (int i = 0; i < 8; ++i)
    #pragma unroll
    for (int j = 0; j < 4; ++j) acc[i][j] = (v4f){0.f, 0.f, 0.f, 0.f};

  const int fsw = lq ^ ((lc >> 1) & 3);
  int aoff[8], boff[4];
  #pragma unroll
  for (int mi = 0; mi < 8; ++mi) aoff[mi] = ((wm * 128 + mi * 16 + lc) * 4 + fsw) * 8;
  #pragma unroll
  for (int ni = 0; ni < 4; ++ni) boff[ni] = ((wn * 64 + ni * 16 + lc) * 4 + fsw) * 8;

  auto stageA = [&](int t, int kh) {
    int reg = (t & 1) * 32768 + kh * 8192;
    int koff = t * 64 + kh * 32;
    #pragma unroll
    for (int i = 0; i < 2; ++i)
      gload16(&lds[reg + i * 4096 + wid * 512], srcA[i] + koff);
  };
  auto stageB = [&](int t, int kh) {
    int reg = (t & 1) * 32768 + 16384 + kh * 8192;
    int koff = t * 64 + kh * 32;
    #pragma unroll
    for (int i = 0; i < 2; ++i)
      gload16(&lds[reg + i * 4096 + wid * 512], srcB[i] + koff);
  };

  stageA(0, 0); stageB(0, 0);
  stageA(0, 1); stageB(0, 1);
  stageA(1, 0); stageB(1, 0);
  asm volatile("s_waitcnt vmcnt(8)" ::: "memory");
  __builtin_amdgcn_s_barrier();

  const int NT = K >> 6;
  for (int t = 0; t < NT; ++t) {
    const int bufb = (t & 1) * 32768;
    const u16* Ab0 = &lds[bufb];
    const u16* Ab1 = &lds[bufb + 8192];
    const u16* Bb0 = &lds[bufb + 16384];
    const u16* Bb1 = &lds[bufb + 24576];
    v8s a_[4], b_[4];

    #pragma unroll
    for (int ni = 0; ni < 4; ++ni) b_[ni] = *(const v8s*)(Bb0 + boff[ni]);
    #pragma unroll
    for (int mi = 0; mi < 4; ++mi) a_[mi] = *(const v8s*)(Ab0 + aoff[mi]);
    if (t + 1 < NT) stageA(t + 1, 1);
    asm volatile("s_waitcnt lgkmcnt(0)" ::: "memory");
    __builtin_amdgcn_sched_barrier(0);
    __builtin_amdgcn_s_setprio(1);
    #pragma unroll
    for (int mi = 0; mi < 4; ++mi)
      #pragma unroll
      for (int ni = 0; ni < 4; ++ni)
        acc[mi][ni] = __builtin_amdgcn_mfma_f32_16x16x32_bf16(a_[mi], b_[ni], acc[mi][ni], 0, 0, 0);
    __builtin_amdgcn_s_setprio(0);
    __builtin_amdgcn_s_barrier();

    #pragma unroll
    for (int mi = 0; mi < 4; ++mi) a_[mi] = *(const v8s*)(Ab0 + aoff[mi + 4]);
    if (t + 1 < NT) stageB(t + 1, 1);
    asm volatile("s_waitcnt lgkmcnt(0)" ::: "memory");
    __builtin_amdgcn_sched_barrier(0);
    __builtin_amdgcn_s_setprio(1);
    #pragma unroll
    for (int mi = 0; mi < 4; ++mi)
      #pragma unroll
      for (int ni = 0; ni < 4; ++ni)
        acc[mi + 4][ni] = __builtin_amdgcn_mfma_f32_16x16x32_bf16(a_[mi], b_[ni], acc[mi + 4][ni], 0, 0, 0);
    __builtin_amdgcn_s_setprio(0);
    if (t + 1 < NT) { asm volatile("s_waitcnt vmcnt(4)" ::: "memory"); }
    else            { asm volatile("s_waitcnt vmcnt(0)" ::: "memory"); }
    __builtin_amdgcn_s_barrier();

    #pragma unroll
    for (int ni = 0; ni < 4; ++ni) b_[ni] = *(const v8s*)(Bb1 + boff[ni]);
    #pragma unroll
    for (int mi = 0; mi < 4; ++mi) a_[mi] = *(const v8s*)(Ab1 + aoff[mi]);
    if (t + 2 < NT) stageA(t + 2, 0);
    asm volatile("s_waitcnt lgkmcnt(0)" ::: "memory");
    __builtin_amdgcn_sched_barrier(0);
    __builtin_amdgcn_s_setprio(1);
    #pragma unroll
    for (int mi = 0; mi < 4; ++mi)
      #pragma unroll
      for (int ni = 0; ni < 4; ++ni)
        acc[mi][ni] = __builtin_amdgcn_mfma_f32_16x16x32_bf16(a_[mi], b_[ni], acc[mi][ni], 0, 0, 0);
    __builtin_amdgcn_s_setprio(0);
    __builtin_amdgcn_s_barrier();

    #pragma unroll
    for (int mi = 0; mi < 4; ++mi) a_[mi] = *(const v8s*)(Ab1 + aoff[mi + 4]);
    if (t + 2 < NT) stageB(t + 2, 0);
    asm volatile("s_waitcnt lgkmcnt(0)" ::: "memory");
    __builtin_amdgcn_sched_barrier(0);
    __builtin_amdgcn_s_setprio(1);
    #pragma unroll
    for (int mi = 0; mi < 4; ++mi)
      #pragma unroll
      for (int ni = 0; ni < 4; ++ni)
        acc[mi + 4][ni] = __builtin_amdgcn_mfma_f32_16x16x32_bf16(a_[mi], b_[ni], acc[mi + 4][ni], 0, 0, 0);
    __builtin_amdgcn_s_setprio(0);
    __builtin_amdgcn_s_barrier();
  }
  asm volatile("s_waitcnt vmcnt(0)" ::: "memory");

  if constexpr (EPI == EPI_GLU) {
    #pragma unroll
    for (int mi = 0; mi < 8; ++mi)
      #pragma unroll
      for (int np = 0; np < 2; ++np)
        #pragma unroll
        for (int r = 0; r < 4; ++r) {
          int grow = m0 + wm * 128 + mi * 16 + lq * 4 + r;
          int gcol = (n0 >> 1) + wn * 32 + np * 16 + lc;
          float g = acc[mi][2 * np][r];
          float u = acc[mi][2 * np + 1][r];
          Cbf[(size_t)grow * ldc + gcol] = f2bf(u * g / (1.0f + __expf(-g)));
        }
  } else {
    #pragma unroll
    for (int mi = 0; mi < 8; ++mi)
      #pragma unroll
      for (int ni = 0; ni < 4; ++ni)
        #pragma unroll
        for (int r = 0; r < 4; ++r) {
          int grow = m0 + wm * 128 + mi * 16 + lq * 4 + r;
          int gcol = n0 + wn * 64 + ni * 16 + lc;
          size_t idx = (size_t)grow * ldc + gcol;
          float vv = acc[mi][ni][r];
          if constexpr (EPI == EPI_BF16) {
            Cbf[idx] = f2bf(vv);
          } else {  // EPI_SILU
            float g = bf2f(Gaux[idx]);
            Cbf[idx] = f2bf(vv * g / (1.0f + __expf(-g)));
          }
        }
  }
  (void)partials; (void)nch;
}

// ---------------------------------------------------------------------------
// 8-PHASE PIPELINED 256x256 GEMM fp8 e4m3 (round-12 verified double-buffer
// form): b128 fragment reads, 64KB LDS (2 blk/CU), t+2 lookahead, vmcnt(4).
// EPI_STATS: softmax partials (logits = acc/64). EPI_GLU: interleaved gate/up,
// out bf16 = up * silu(gate) (weights pre-scaled x64 -> acc/64).
template <int EPI>
__launch_bounds__(512, 2)
__global__ void k_gemm8(const u8* __restrict__ A8, const u8* __restrict__ B8,
                        u16* __restrict__ Cbf, v4f* __restrict__ partials,
                        int K, int ldc, int nch) {
  // 64 KB: buf b at b*32768; A region 16KB at +0, B at +16384
  __shared__ __align__(16) u8 lds8[65536];
  const int tid = threadIdx.x;
  const int lane = tid & 63, wid = tid >> 6;
  const int wm = wid >> 2, wn = wid & 3;        // per-wave out 128x64
  const int lc = lane & 15, lq = lane >> 4;
  const int m0 = blockIdx.x * 256, n0 = blockIdx.y * 256;

  const u8* srcA[2]; const u8* srcB[2];
  #pragma unroll
  for (int i = 0; i < 2; ++i) {
    int ci = i * 512 + tid;
    int r = ci >> 2;
    int logc = (ci & 3) ^ ((r >> 1) & 3);
    srcA[i] = A8 + (size_t)(m0 + r) * K + logc * 16;
    srcB[i] = B8 + (size_t)(n0 + r) * K + logc * 16;
  }

  v4f acc[8][4];
  #pragma unroll
  for (int i = 0; i < 8; ++i)
    #pragma unroll
    for (int j = 0; j < 4; ++j) acc[i][j] = (v4f){0.f, 0.f, 0.f, 0.f};

  const int csw = (lc >> 1) & 3;
  int aoff[8], boff[4];
  #pragma unroll
  for (int mi = 0; mi < 8; ++mi) aoff[mi] = (wm * 128 + mi * 16 + lc) * 64 + ((lq ^ csw) << 4);
  #pragma unroll
  for (int ni = 0; ni < 4; ++ni) boff[ni] = (wn * 64 + ni * 16 + lc) * 64 + ((lq ^ csw) << 4);

  auto stageA = [&](int t, int i) {
    gload16(&lds8[(t & 1) * 32768 + i * 8192 + wid * 1024], srcA[i] + t * 64);
  };
  auto stageB = [&](int t, int i) {
    gload16(&lds8[(t & 1) * 32768 + 16384 + i * 8192 + wid * 1024], srcB[i] + t * 64);
  };

  // prologue: tiles 0 and 1 (8 issues); wait tile0's 4 -> vmcnt(4)
  stageA(0, 0); stageA(0, 1); stageB(0, 0); stageB(0, 1);
  stageA(1, 0); stageA(1, 1); stageB(1, 0); stageB(1, 1);
  asm volatile("s_waitcnt vmcnt(4)" ::: "memory");
  __builtin_amdgcn_s_barrier();

  union Frag { v4i v; long long ll[2]; };
  const int NT = K >> 6;
  for (int t = 0; t < NT; ++t) {
    const u8* Ab = &lds8[(t & 1) * 32768];
    const u8* Bb = Ab + 16384;
    Frag fa[8], fb[4];

    // q0: read all B + A0-3 (b128 each, both K-halves); MFMA kh0 mi0-3
    #pragma unroll
    for (int ni = 0; ni < 4; ++ni) fb[ni].v = *(const v4i*)(Bb + boff[ni]);
    #pragma unroll
    for (int mi = 0; mi < 4; ++mi) fa[mi].v = *(const v4i*)(Ab + aoff[mi]);
    asm volatile("s_waitcnt lgkmcnt(0)" ::: "memory");
    __builtin_amdgcn_sched_barrier(0);
    __builtin_amdgcn_s_setprio(1);
    #pragma unroll
    for (int mi = 0; mi < 4; ++mi)
      #pragma unroll
      for (int ni = 0; ni < 4; ++ni)
        acc[mi][ni] = __builtin_amdgcn_mfma_f32_16x16x32_fp8_fp8(fa[mi].ll[0], fb[ni].ll[0], acc[mi][ni], 0, 0, 0);
    __builtin_amdgcn_s_setprio(0);
    __builtin_amdgcn_s_barrier();

    // q1: read A4-7; stage B(t+2).0 into cur B-region (dead after q0 barrier)
    #pragma unroll
    for (int mi = 0; mi < 4; ++mi) fa[mi + 4].v = *(const v4i*)(Ab + aoff[mi + 4]);
    if (t + 2 < NT) stageB(t + 2, 0);
    asm volatile("s_waitcnt lgkmcnt(0)" ::: "memory");
    __builtin_amdgcn_sched_barrier(0);
    __builtin_amdgcn_s_setprio(1);
    #pragma unroll
    for (int mi = 0; mi < 4; ++mi)
      #pragma unroll
      for (int ni = 0; ni < 4; ++ni)
        acc[mi + 4][ni] = __builtin_amdgcn_mfma_f32_16x16x32_fp8_fp8(fa[mi + 4].ll[0], fb[ni].ll[0], acc[mi + 4][ni], 0, 0, 0);
    __builtin_amdgcn_s_setprio(0);
    __builtin_amdgcn_s_barrier();

    // q2: no reads (kh1 from regs); stage B(t+2).1, A(t+2).0 (A dead after q1 barrier)
    if (t + 2 < NT) { stageB(t + 2, 1); stageA(t + 2, 0); }
    __builtin_amdgcn_s_setprio(1);
    #pragma unroll
    for (int mi = 0; mi < 4; ++mi)
      #pragma unroll
      for (int ni = 0; ni < 4; ++ni)
        acc[mi][ni] = __builtin_amdgcn_mfma_f32_16x16x32_fp8_fp8(fa[mi].ll[1], fb[ni].ll[1], acc[mi][ni], 0, 0, 0);
    __builtin_amdgcn_s_setprio(0);
    __builtin_amdgcn_s_barrier();

    // q3: stage A(t+2).1; MFMA kh1 mi4-7; per-tile counted vmcnt
    if (t + 2 < NT) stageA(t + 2, 1);
    __builtin_amdgcn_s_setprio(1);
    #pragma unroll
    for (int mi = 0; mi < 4; ++mi)
      #pragma unroll
      for (int ni = 0; ni < 4; ++ni)
        acc[mi + 4][ni] = __builtin_amdgcn_mfma_f32_16x16x32_fp8_fp8(fa[mi + 4].ll[1], fb[ni].ll[1], acc[mi + 4][ni], 0, 0, 0);
    __builtin_amdgcn_s_setprio(0);
    if (t + 2 < NT) { asm volatile("s_waitcnt vmcnt(4)" ::: "memory"); }
    else            { asm volatile("s_waitcnt vmcnt(0)" ::: "memory"); }
    __builtin_amdgcn_s_barrier();
  }
  asm volatile("s_waitcnt vmcnt(0)" ::: "memory");

  // undo the x64 weight scale
  #pragma unroll
  for (int mi = 0; mi < 8; ++mi)
    #pragma unroll
    for (int ni = 0; ni < 4; ++ni)
      acc[mi][ni] *= 0.015625f;

  if constexpr (EPI == EPI_GLU) {
    #pragma unroll
    for (int mi = 0; mi < 8; ++mi)
      #pragma unroll
      for (int np = 0; np < 2; ++np)
        #pragma unroll
        for (int r = 0; r < 4; ++r) {
          int grow = m0 + wm * 128 + mi * 16 + lq * 4 + r;
          int gcol = (n0 >> 1) + wn * 32 + np * 16 + lc;
          float g = acc[mi][2 * np][r];
          float u = acc[mi][2 * np + 1][r];
          Cbf[(size_t)grow * ldc + gcol] = f2bf(u * g / (1.0f + __expf(-g)));
        }
    return;
  } else {
    // EPI_STATS: epilogue scratch aliased onto (dead) staging LDS
    float* s_mx = (float*)lds8;
    float* s_sm = (float*)(lds8 + 4096);
    int*   s_ax = (int*)(lds8 + 8192);
    __syncthreads();
    #pragma unroll
    for (int mi = 0; mi < 8; ++mi) {
      #pragma unroll
      for (int r = 0; r < 4; ++r) {
        float v0 = acc[mi][0][r], v1 = acc[mi][1][r], v2 = acc[mi][2][r], v3 = acc[mi][3][r];
        float mx = v0; int ax = lc;
        if (v1 > mx) { mx = v1; ax = 16 + lc; }
        if (v2 > mx) { mx = v2; ax = 32 + lc; }
        if (v3 > mx) { mx = v3; ax = 48 + lc; }
        #pragma unroll
        for (int off = 1; off < 16; off <<= 1) {
          float om = __shfl_xor(mx, off); int oa = __shfl_xor(ax, off);
          if (om > mx || (om == mx && oa < ax)) { mx = om; ax = oa; }
        }
        float se = __expf(v0 - mx) + __expf(v1 - mx) + __expf(v2 - mx) + __expf(v3 - mx);
        #pragma unroll
        for (int off = 1; off < 16; off <<= 1) se += __shfl_xor(se, off);
        if (lc == 0) {
          int row = wm * 128 + mi * 16 + lq * 4 + r;
          s_mx[row * 4 + wn] = mx; s_sm[row * 4 + wn] = se; s_ax[row * 4 + wn] = wn * 64 + ax;
        }
      }
    }
    __syncthreads();
    if (tid < 256) {
      float gm = s_mx[tid * 4]; int ga = s_ax[tid * 4];
      #pragma unroll
      for (int w = 1; w < 4; ++w) {
        float m = s_mx[tid * 4 + w];
        if (m > gm) { gm = m; ga = s_ax[tid * 4 + w]; }
      }
      float gs = 0.f;
      #pragma unroll
      for (int w = 0; w < 4; ++w) gs += s_sm[tid * 4 + w] * __expf(s_mx[tid * 4 + w] - gm);
      v4f rec; rec[0] = gm; rec[1] = gs; rec[2] = __int_as_float(n0 + ga); rec[3] = 0.f;
      partials[(size_t)(m0 + tid) * nch + blockIdx.y] = rec;
    }
  }
}

// ---------------------------------------------------------------------------
// PIPELINED 128x128 GEMM bf16: BK=64, 4 waves, dbuf LDS (2 blk/CU).
template <int ASRC, int EPI>
__launch_bounds__(256, 2)
__global__ void k_gemm4(const u16* __restrict__ Abf, const u16* __restrict__ Bbf,
                        u16* __restrict__ Cbf, float* __restrict__ Cf32,
                        const int* __restrict__ keepArr, RmsSrc rs, int K, int ldb, int ldc) {
  __shared__ __align__(16) u16 lds[2][16384];
  const int tid = threadIdx.x;
  const int lane = tid & 63, wid = tid >> 6;
  const int wm = wid >> 1, wn = wid & 1;
  const int lc = lane & 15, lq = lane >> 4;
  const int m0 = blockIdx.x * 128, n0 = blockIdx.y * 128;

  const u16* srcA[4]; const u16* srcB[4];
  #pragma unroll
  for (int i = 0; i < 4; ++i) {
    int s = i * 256 + tid;
    int row = s >> 3;
    int c3 = (s & 7) ^ (row & 7);
    int ar = m0 + row;
    if constexpr (ASRC == ASRC_AOMAP) ar = (ar >> 4) * 17 + 1 + (ar & 15);
    srcA[i] = Abf + (size_t)ar * K + c3 * 8;
    srcB[i] = Bbf + (size_t)(n0 + row) * ldb + c3 * 8;
  }

  v4f acc[4][4];
  #pragma unroll
  for (int i = 0; i < 4; ++i)
    #pragma unroll
    for (int j = 0; j < 4; ++j) acc[i][j] = (v4f){0.f, 0.f, 0.f, 0.f};

  const int sw = lc & 7;
  const int aoff0 = (((wm * 64 + lc) * 8 + 0 + lq) ^ sw) * 8;
  const int aoff1 = (((wm * 64 + lc) * 8 + 4 + lq) ^ sw) * 8;
  const int boff0 = (((wn * 64 + lc) * 8 + 0 + lq) ^ sw) * 8;
  const int boff1 = (((wn * 64 + lc) * 8 + 4 + lq) ^ sw) * 8;

  auto stageTo = [&](int b) {
    u16* dA = &lds[b][0] + wid * 512;
    u16* dB = &lds[b][8192] + wid * 512;
    #pragma unroll
    for (int i = 0; i < 4; ++i) { gload16(dA + i * 2048, srcA[i]); srcA[i] += 64; }
    #pragma unroll
    for (int i = 0; i < 4; ++i) { gload16(dB + i * 2048, srcB[i]); srcB[i] += 64; }
  };

  stageTo(0);
  const int NT = K >> 6;
  for (int t = 0; t < NT; ++t) {
    const int cur = t & 1;
    if (t + 1 < NT) {
      stageTo(cur ^ 1);
      asm volatile("s_waitcnt vmcnt(8)" ::: "memory");
    } else {
      asm volatile("s_waitcnt vmcnt(0)" ::: "memory");
    }
    __builtin_amdgcn_s_barrier();
    const u16* Ab = &lds[cur][0];
    const u16* Bb = &lds[cur][8192];
    v8s a0[4], a1[4], b0[4], b1[4];
    #pragma unroll
    for (int mi = 0; mi < 4; ++mi) a0[mi] = *(const v8s*)(Ab + aoff0 + mi * 1024);
    #pragma unroll
    for (int ni = 0; ni < 4; ++ni) b0[ni] = *(const v8s*)(Bb + boff0 + ni * 1024);
    #pragma unroll
    for (int mi = 0; mi < 4; ++mi) a1[mi] = *(const v8s*)(Ab + aoff1 + mi * 1024);
    #pragma unroll
    for (int ni = 0; ni < 4; ++ni) b1[ni] = *(const v8s*)(Bb + boff1 + ni * 1024);
    __builtin_amdgcn_s_setprio(1);
    #pragma unroll
    for (int mi = 0; mi < 4; ++mi)
      #pragma unroll
      for (int ni = 0; ni < 4; ++ni)
        acc[mi][ni] = __builtin_amdgcn_mfma_f32_16x16x32_bf16(a0[mi], b0[ni], acc[mi][ni], 0, 0, 0);
    __builtin_amdgcn_s_setprio(0);
    asm volatile("s_waitcnt lgkmcnt(0)" ::: "memory");
    __builtin_amdgcn_sched_barrier(0);
    __builtin_amdgcn_s_barrier();
    __builtin_amdgcn_s_setprio(1);
    #pragma unroll
    for (int mi = 0; mi < 4; ++mi)
      #pragma unroll
      for (int ni = 0; ni < 4; ++ni)
        acc[mi][ni] = __builtin_amdgcn_mfma_f32_16x16x32_bf16(a1[mi], b1[ni], acc[mi][ni], 0, 0, 0);
    __builtin_amdgcn_s_setprio(0);
  }

  #pragma unroll
  for (int mi = 0; mi < 4; ++mi)
    #pragma unroll
    for (int ni = 0; ni < 4; ++ni)
      #pragma unroll
      for (int r = 0; r < 4; ++r) {
        int grow = m0 + wm * 64 + mi * 16 + lq * 4 + r;
        int gcol = n0 + wn * 64 + ni * 16 + lc;
        size_t idx = (size_t)grow * ldc + gcol;
        float vv = acc[mi][ni][r];
        if constexpr (EPI == EPI_BF16) {
          Cbf[idx] = f2bf(vv);
        } else if constexpr (EPI == EPI_OEMB) {
          int t_ = grow & 15, bn = grow >> 4;
          int tok = (t_ == 0) ? rs.ftok[bn] : cMASK;
          float kf = (float)keepArr[bn];
          Cf32[idx] = rs.emb[(size_t)tok * cD + gcol] + vv * kf;
        } else {  // EPI_DOWNACC
          Cf32[idx] += vv;
        }
      }
}

// ---------------------------------------------------------------------------
// FALLBACK GEMM (round-3): fp32 B converted during staging.
template <int ASRC, int BLAYOUT, int EPI>
__launch_bounds__(256)
__global__ void k_gemm(const u16* __restrict__ Abf, const float* __restrict__ Bw,
                       u16* Cbf, float* Cf32, const u16* Gaux,
                       const int* __restrict__ keepArr, v4f* __restrict__ partials,
                       RmsSrc rs, int K, int ldb, int ldc) {
  __shared__ __align__(16) u16 As[128][40];
  __shared__ __align__(16) u16 Bs[128][40];
  const int tid = threadIdx.x;
  const int m0 = blockIdx.x * 128, n0 = blockIdx.y * 128;
  const int lane = tid & 63, wid = tid >> 6;
  const int wm = wid >> 1, wn = wid & 1;
  const int lc = lane & 15, lk8 = (lane >> 4) * 8;
  const int srow = tid >> 2, sk8 = (tid & 3) * 8;
  v4f acc[4][4];
  #pragma unroll
  for (int i = 0; i < 4; ++i)
    #pragma unroll
    for (int j = 0; j < 4; ++j) acc[i][j] = (v4f){0.f, 0.f, 0.f, 0.f};

  for (int kt = 0; kt < K; kt += 32) {
    __syncthreads();
    for (int mm = srow; mm < 128; mm += 64) {
      if constexpr (ASRC == ASRC_BF16) {
        *(v8s*)&As[mm][sk8] = *(const v8s*)(Abf + (size_t)(m0 + mm) * K + kt + sk8);
      } else if constexpr (ASRC == ASRC_AOMAP) {
        int m = m0 + mm, bn = m >> 4, t = m & 15;
        *(v8s*)&As[mm][sk8] = *(const v8s*)(Abf + (size_t)(bn * 17 + 1 + t) * K + kt + sk8);
      } else {
        int R = m0 + mm;
        int j = R % 17, bn = R / 17, b = bn >> 7;
        const float* src; const float* nw;
        if (j == 0) { src = rs.hs + ((size_t)b * cS + rs.cpos[bn]) * cD; nw = rs.nchs; }
        else {
          int tok = (j == 1) ? rs.ftok[bn] : cMASK;
          src = rs.emb + (size_t)tok * cD; nw = rs.nattn;
        }
        float inv = rs.rowinv[R];
        const v4f* sp = (const v4f*)(src + kt + sk8);
        const v4f* np_ = (const v4f*)(nw + kt + sk8);
        v4f s0 = sp[0], s1 = sp[1], w0 = np_[0], w1 = np_[1];
        v8s pk;
        #pragma unroll
        for (int e = 0; e < 4; ++e) pk[e] = (short)f2bf(s0[e] * inv * w0[e]);
        #pragma unroll
        for (int e = 0; e < 4; ++e) pk[4 + e] = (short)f2bf(s1[e] * inv * w1[e]);
        *(v8s*)&As[mm][sk8] = pk;
      }
    }
    if constexpr (BLAYOUT == 1) {
      for (int nn = srow; nn < 128; nn += 64) {
        const v4f* bp = (const v4f*)(Bw + (size_t)(n0 + nn) * ldb + kt + sk8);
        v4f b0 = bp[0], b1 = bp[1];
        v8s pk;
        #pragma unroll
        for (int e = 0; e < 4; ++e) { pk[e] = (short)f2bf(b0[e]); pk[4 + e] = (short)f2bf(b1[e]); }
        *(v8s*)&Bs[nn][sk8] = pk;
      }
    } else {
      const int bn_ = tid & 127, kq = tid >> 7;
      for (int kk = kq; kk < 8; kk += 2) {
        const int k4 = kk * 4;
        const float* bp = Bw + (size_t)(kt + k4) * ldb + n0 + bn_;
        v4u pk;
        #pragma unroll
        for (int e = 0; e < 4; ++e) pk[e] = f2bf(bp[(size_t)e * ldb]);
        *(v4u*)&Bs[bn_][k4] = pk;
      }
    }
    __syncthreads();
    v8s af[4], bf_[4];
    #pragma unroll
    for (int i = 0; i < 4; ++i) af[i] = *(const v8s*)&As[wm * 64 + i * 16 + lc][lk8];
    #pragma unroll
    for (int i = 0; i < 4; ++i) bf_[i] = *(const v8s*)&Bs[wn * 64 + i * 16 + lc][lk8];
    #pragma unroll
    for (int mi = 0; mi < 4; ++mi)
      #pragma unroll
      for (int ni = 0; ni < 4; ++ni)
        acc[mi][ni] = __builtin_amdgcn_mfma_f32_16x16x32_bf16(af[mi], bf_[ni], acc[mi][ni], 0, 0, 0);
  }

  if constexpr (EPI == EPI_STATS) {
    __shared__ float s_mx[128][2], s_sm[128][2];
    __shared__ int s_ax[128][2];
    #pragma unroll
    for (int mi = 0; mi < 4; ++mi) {
      #pragma unroll
      for (int r = 0; r < 4; ++r) {
        float v0 = acc[mi][0][r], v1 = acc[mi][1][r], v2 = acc[mi][2][r], v3 = acc[mi][3][r];
        float mx = v0; int ax = lc;
        if (v1 > mx) { mx = v1; ax = 16 + lc; }
        if (v2 > mx) { mx = v2; ax = 32 + lc; }
        if (v3 > mx) { mx = v3; ax = 48 + lc; }
        #pragma unroll
        for (int off = 1; off < 16; off <<= 1) {
          float om = __shfl_xor(mx, off); int oa = __shfl_xor(ax, off);
          if (om > mx || (om == mx && oa < ax)) { mx = om; ax = oa; }
        }
        float se = __expf(v0 - mx) + __expf(v1 - mx) + __expf(v2 - mx) + __expf(v3 - mx);
        #pragma unroll
        for (int off = 1; off < 16; off <<= 1) se += __shfl_xor(se, off);
        if (lc == 0) {
          int lr = wm * 64 + mi * 16 + (lane >> 4) * 4 + r;
          s_mx[lr][wn] = mx; s_sm[lr][wn] = se; s_ax[lr][wn] = wn * 64 + ax;
        }
      }
    }
    __syncthreads();
    if (tid < 128) {
      float ma = s_mx[tid][0], mb = s_mx[tid][1];
      float gm = fmaxf(ma, mb);
      float gs = s_sm[tid][0] * __expf(ma - gm) + s_sm[tid][1] * __expf(mb - gm);
      int ga = (ma >= mb) ? s_ax[tid][0] : s_ax[tid][1];
      v4f rec; rec[0] = gm; rec[1] = gs; rec[2] = __int_as_float(n0 + ga); rec[3] = 0.f;
      partials[(size_t)(m0 + tid) * NCH + blockIdx.y] = rec;
    }
    return;
  } else {
    #pragma unroll
    for (int mi = 0; mi < 4; ++mi)
      #pragma unroll
      for (int ni = 0; ni < 4; ++ni)
        #pragma unroll
        for (int r = 0; r < 4; ++r) {
          int grow = m0 + wm * 64 + mi * 16 + (lane >> 4) * 4 + r;
          int gcol = n0 + wn * 64 + ni * 16 + lc;
          size_t idx = (size_t)grow * ldc + gcol;
          float vv = acc[mi][ni][r];
          if constexpr (EPI == EPI_BF16) {
            Cbf[idx] = f2bf(vv);
          } else if constexpr (EPI == EPI_SILU) {
            float g = bf2f(Gaux[idx]);
            Cbf[idx] = f2bf(vv * g / (1.0f + __expf(-g)));
          } else if constexpr (EPI == EPI_OEMB) {
            int t = grow & 15, bn = grow >> 4;
            int tok = (t == 0) ? rs.ftok[bn] : cMASK;
            float kf = (float)keepArr[bn];
            Cf32[idx] = rs.emb[(size_t)tok * cD + gcol] + vv * kf;
          } else {
            Cf32[idx] += vv;
          }
        }
  }
}

// ---------------------------------------------------------------------------
__global__ void k_rope(u16* __restrict__ qb, u16* __restrict__ kb,
                       const int* __restrict__ anchors, const int* __restrict__ cpos) {
  int r = blockIdx.x;
  int which = (r >= MKV);
  int rr = which ? r - MKV : r;
  int j = rr % 17, bn = rr / 17;
  if (!which && j == 0) return;
  u16* buf = which ? kb : qb;
  int pos = (which && j == 0) ? cpos[bn] : (anchors[bn] + j - 1);
  float fp = (float)pos;
  for (int p = threadIdx.x; p < cH * 64; p += 256) {
    int h = p >> 6, i = p & 63;
    size_t base = (size_t)rr * cD + h * cHD;
    float x1 = bf2f(buf[base + i]);
    float x2 = bf2f(buf[base + 64 + i]);
    float freq = powf(10000.0f, -((float)(2 * i)) / 128.0f);
    float ang = fp * freq;
    float sn = sinf(ang), cn = cosf(ang);
    buf[base + i]      = f2bf(x1 * cn - x2 * sn);
    buf[base + 64 + i] = f2bf(x2 * cn + x1 * sn);
  }
}

__global__ void k_attn(u16* __restrict__ qb, const u16* __restrict__ kb,
                       const u16* __restrict__ vb) {
  int blk = blockIdx.x;
  int h = blk % cH, bn = blk / cH;
  __shared__ float qs[16][128], ks[17][128], vs[17][128], ps[16][18];
  int lane = threadIdx.x;
  for (int e = lane; e < 16 * 128; e += 64) {
    int r = e >> 7, d = e & 127;
    qs[r][d] = bf2f(qb[((size_t)(bn * 17 + 1 + r)) * cD + h * cHD + d]);
  }
  for (int e = lane; e < 17 * 128; e += 64) {
    int r = e >> 7, d = e & 127;
    ks[r][d] = bf2f(kb[((size_t)(bn * 17 + r)) * cD + h * cHD + d]);
    vs[r][d] = bf2f(vb[((size_t)(bn * 17 + r)) * cD + h * cHD + d]);
  }
  __syncthreads();
  for (int e = lane; e < 16 * 17; e += 64) {
    int qi = e / 17, ki = e % 17;
    float s = 0.f;
    for (int d = 0; d < 128; ++d) s += qs[qi][d] * ks[ki][d];
    ps[qi][ki] = s * 0.08838834764831845f;
  }
  __syncthreads();
  if (lane < 16) {
    float m = -3e38f;
    for (int kk = 0; kk < 17; ++kk) m = fmaxf(m, ps[lane][kk]);
    float s = 0.f;
    for (int kk = 0; kk < 17; ++kk) { float e_ = __expf(ps[lane][kk] - m); ps[lane][kk] = e_; s += e_; }
    float is = 1.0f / s;
    for (int kk = 0; kk < 17; ++kk) ps[lane][kk] *= is;
  }
  __syncthreads();
  for (int e = lane; e < 16 * 128; e += 64) {
    int qi = e >> 7, d = e & 127;
    float s = 0.f;
    for (int kk = 0; kk < 17; ++kk) s += ps[qi][kk] * vs[kk][d];
    qb[((size_t)(bn * 17 + 1 + qi)) * cD + h * cHD + d] = f2bf(s);
  }
}

__global__ void k_tgt(const u16* __restrict__ hout, const float* __restrict__ Wlm,
                      const int* __restrict__ ids, const int* __restrict__ anchors,
                      int* __restrict__ tgt_tok, float* __restrict__ tgt_logit) {
  int w = threadIdx.x >> 6, lane = threadIdx.x & 63;
  int m = blockIdx.x * 4 + w;
  int bn = m >> 4, t = m & 15, b = bn / cNA;
  int label = anchors[bn] + t;
  int sl = (label < cS - 1) ? label : (cS - 1);
  int tok = ids[(size_t)b * cS + sl];
  const u16* hr = hout + (size_t)m * cD;
  const float* wr = Wlm + (size_t)tok * cD;
  float s = 0.f;
  for (int d = lane; d < cD; d += 64) s += bf2f(hr[d]) * wr[d];
  s = waveSum(s);
  if (lane == 0) { tgt_tok[m] = tok; tgt_logit[m] = s; }
}

__global__ void k_combine(const v4f* __restrict__ partials, const int* __restrict__ tgt_tok,
                          const float* __restrict__ tgt_logit, const int* __restrict__ keepArr,
                          const int* __restrict__ anchors, const float* __restrict__ lmask,
                          float* __restrict__ tokOut, int nch) {
  int m = blockIdx.x;
  int tid = threadIdx.x, lane = tid & 63, w = tid >> 6;
  float cm = -3.0e38f, cs = 0.f; int ca = 0x7fffffff;
  if (tid < nch) {
    v4f rec = partials[(size_t)m * nch + tid];
    cm = rec[0]; cs = rec[1]; ca = __float_as_int(rec[2]);
  }
  float gm = cm; int ga = ca;
  #pragma unroll
  for (int off = 1; off < 64; off <<= 1) {
    float om = __shfl_xor(gm, off); int oa = __shfl_xor(ga, off);
    if (om > gm || (om == gm && oa < ga)) { gm = om; ga = oa; }
  }
  __shared__ float wmx[4]; __shared__ int wax[4]; __shared__ float wsm[4];
  if (lane == 0) { wmx[w] = gm; wax[w] = ga; }
  __syncthreads();
  if (tid == 0) {
    for (int i = 1; i < 4; ++i)
      if (wmx[i] > wmx[0] || (wmx[i] == wmx[0] && wax[i] < wax[0])) { wmx[0] = wmx[i]; wax[0] = wax[i]; }
  }
  __syncthreads();
  gm = wmx[0]; ga = wax[0];
  float s = (tid < nch) ? cs * __expf(cm - gm) : 0.f;
  s = waveSum(s);
  if (lane == 0) wsm[w] = s;
  __syncthreads();
  if (tid == 0) {
    float gs = wsm[0] + wsm[1] + wsm[2] + wsm[3];
    float logZ = gm + logf(gs);
    int bn = m >> 4, t = m & 15, b = bn / cNA;
    int label = anchors[bn] + t;
    int sl = (label < cS - 1) ? label : (cS - 1);
    float wgt = (float)keepArr[bn] * ((t > 0) ? 1.f : 0.f) * ((label < cS) ? 1.f : 0.f) *
                lmask[(size_t)b * cS + sl];
    float lp = tgt_logit[m] - logZ;
    int tg = tgt_tok[m];
    tokOut[m * 4 + 0] = lp * wgt;
    tokOut[m * 4 + 1] = wgt;
    tokOut[m * 4 + 2] = ((ga == tg) && (wgt > 0.5f)) ? 1.f : 0.f;
    tokOut[m * 4 + 3] = 0.f;
  }
}

__global__ void k_final(const float* __restrict__ tokOut, float* __restrict__ outp) {
  int tid = threadIdx.x;
  float swl = 0.f, sw = 0.f, sm = 0.f;
  for (int m = tid; m < MTOK; m += 256) {
    swl += tokOut[m * 4 + 0];
    sw  += tokOut[m * 4 + 1];
    sm  += tokOut[m * 4 + 2];
  }
  swl = waveSum(swl); sw = waveSum(sw); sm = waveSum(sm);
  __shared__ float r0[4], r1[4], r2[4];
  int lane = tid & 63, w = tid >> 6;
  if (lane == 0) { r0[w] = swl; r1[w] = sw; r2[w] = sm; }
  __syncthreads();
  if (tid == 0) {
    float a = r0[0] + r0[1] + r0[2] + r0[3];
    float b = r1[0] + r1[1] + r1[2] + r1[3];
    float c = r2[0] + r2[1] + r2[2] + r2[3];
    float denom = b + 1e-6f;
    float loss = -a / denom;
    float acc  = c / denom;
    if (b == 0.0f) loss = -300.0f;
    outp[0] = loss;
    outp[1] = acc;
  }
}

__global__ void k_heartbeat(float* outp) {
  if (threadIdx.x == 0) { outp[0] = -55.0f; outp[1] = -55.0f; }
}
__global__ void k_sentinel(float* outp) {
  if (threadIdx.x == 0) { outp[0] = -777.0f; outp[1] = -777.0f; }
}

// ---------------------------------------------------------------------------
extern "C" void kernel_launch(void* const* d_in, const int* in_sizes, int n_in,
                              void* d_out, int out_size, void* d_ws, size_t ws_size,
                              hipStream_t stream) {
  const int*   ids   = (const int*)  d_in[0];
  const float* hs    = (const float*)d_in[1];
  const float* lmask = (const float*)d_in[2];
  const float* rv    = (const float*)d_in[3];
  const float* emb   = (const float*)d_in[4];
  const float* wlm   = (const float*)d_in[5];
  const float* wq    = (const float*)d_in[6];
  const float* wk    = (const float*)d_in[7];
  const float* wv    = (const float*)d_in[8];
  const float* wo    = (const float*)d_in[9];
  const float* wg    = (const float*)d_in[10];
  const float* wu    = (const float*)d_in[11];
  const float* wd    = (const float*)d_in[12];
  const float* nattn = (const float*)d_in[13];
  const float* nmlp  = (const float*)d_in[14];
  const float* nout  = (const float*)d_in[15];
  const float* nchs  = (const float*)d_in[16];
  (void)in_sizes; (void)n_in; (void)out_size;

  float* outp = (float*)d_out;
  k_heartbeat<<<dim3(1), 64, 0, stream>>>(outp);

  char* wsb = (char*)d_ws;
  size_t off = 0;
  auto alloc = [&](size_t bytes) -> void* {
    void* p = wsb + off;
    off = (off + bytes + 255) & ~(size_t)255;
    return p;
  };
  int*   anchors = (int*)  alloc((size_t)cB * cNA * 4);
  int*   keepA   = (int*)  alloc((size_t)cB * cNA * 4);
  int*   ftok    = (int*)  alloc((size_t)cB * cNA * 4);
  int*   cpos    = (int*)  alloc((size_t)cB * cNA * 4);
  int*   self    = (int*)  alloc((size_t)cB * NCAND * 4);
  float* rowinv  = (float*)alloc((size_t)MKV * 4);
  int*   ttok    = (int*)  alloc((size_t)MTOK * 4);
  float* tlogit  = (float*)alloc((size_t)MTOK * 4);
  float* tokOut  = (float*)alloc((size_t)MTOK * 4 * 4);

  const size_t szQ  = (size_t)MKV * cD * 2;           // 17.8 MB (q/attn-out/h/h_out)
  const size_t szX  = (size_t)MTOK * cD * 4;          // 33.6 MB (fp32 residual)
  u16* qb = (u16*)alloc(szQ);
  const size_t a1off = off;

  RmsSrc rs{hs, emb, nattn, nchs, rowinv, ftok, cpos};

  // common head
  k_select <<<dim3(cB * 16), 256, 0, stream>>>(lmask, rv, self);
  k_anchors<<<dim3(cB),      256, 0, stream>>>(lmask, self, ids, anchors, keepA, ftok, cpos);

  // ---------------- fast tier
  const size_t szKV   = szQ;
  const size_t szCbuf = (size_t)MTOK * 4096 * 2;      // CW = 4096
  size_t kvb_off  = a1off;
  size_t a1f_off  = (kvb_off + szKV + 255) & ~(size_t)255;
  size_t a1f_sz   = 2 * szQ > (szX + szCbuf) ? 2 * szQ : (szX + szCbuf);  // 67 MB
  size_t wreg_off = (a1f_off + a1f_sz + 255) & ~(size_t)255;
  size_t wreg_sz  = (size_t)cV * cD * 2;              // 131 MB (largest stage)
  size_t need_fast = wreg_off + wreg_sz;

  if (need_fast <= ws_size) {
    u16*   kvb   = (u16*)(wsb + kvb_off);
    u16*   kb    = (u16*)(wsb + a1f_off);
    u16*   vb    = (u16*)(wsb + a1f_off + szQ);
    float* xb    = (float*)(wsb + a1f_off);
    u16*   cbuf  = (u16*)(wsb + a1f_off + szX);
    v4f*   parts = (v4f*)(wsb + a1f_off);             // 8.2 MB (lm-head stage)
    u8*    h8    = (u8*)(wsb + a1f_off + (size_t)16 * 1024 * 1024);  // 8.4 MB (lm-head stage)
    u16*   hb    = qb;
    u16*   houtb = qb;
    u16*   wT    = (u16*)(wsb + wreg_off);
    const size_t szDD = (size_t)cD * cD;
    u16* wqT = wT;            u16* wkT = wT + szDD;
    u16* wvT = wT + 2 * szDD; u16* woT = wT + 3 * szDD;
    const size_t szDF = (size_t)cD * cDFF;
    u8*  wgu8 = (u8*)wT;                              // gate/up interleaved fp8, 33.5 MB
    u16* wdT  = wT + 2 * szDF;                        // byte offset 64 MiB
    u8*  h8m  = (u8*)(wT + 3 * szDF);                 // byte offset 96 MiB, 8.4 MB
    u8*  wlm8 = (u8*)wT;                              // 65.5 MB (lm-head stage)

    k_build2<<<dim3(MKV), 256, 0, stream>>>(hs, emb, nattn, nchs, ftok, cpos, kvb);

    k_tconv<<<dim3(32, 32), 256, 0, stream>>>(wq, wqT, cD, cD);
    k_tconv<<<dim3(32, 32), 256, 0, stream>>>(wk, wkT, cD, cD);
    k_tconv<<<dim3(32, 32), 256, 0, stream>>>(wv, wvT, cD, cD);
    k_tconv<<<dim3(32, 32), 256, 0, stream>>>(wo, woT, cD, cD);

    k_gemm4<ASRC_BF16, EPI_BF16><<<dim3(MKV / 128, cD / 128), 256, 0, stream>>>(
        kvb, wqT, qb, nullptr, nullptr, rs, cD, cD, cD);
    k_gemm4<ASRC_BF16, EPI_BF16><<<dim3(MKV / 128, cD / 128), 256, 0, stream>>>(
        kvb, wkT, kb, nullptr, nullptr, rs, cD, cD, cD);
    k_gemm4<ASRC_BF16, EPI_BF16><<<dim3(MKV / 128, cD / 128), 256, 0, stream>>>(
        kvb, wvT, vb, nullptr, nullptr, rs, cD, cD, cD);

    k_rope<<<dim3(2 * MKV), 256, 0, stream>>>(qb, kb, anchors, cpos);
    k_attn<<<dim3(cB * cNA * cH), 64, 0, stream>>>(qb, kb, vb);

    k_gemm4<ASRC_AOMAP, EPI_OEMB><<<dim3(MTOK / 128, cD / 128), 256, 0, stream>>>(
        qb, woT, nullptr, xb, keepA, rs, cD, cD, cD);

    k_rms<<<dim3(MTOK), 256, 0, stream>>>(xb, nmlp, hb);
    k_cvt8<<<dim3(1024), 256, 0, stream>>>(hb, h8m, (long)MTOK * cD);

    // gate/up: transpose + interleave + fp8 (x64) + perm; down: bf16
    k_tconv8<<<dim3(128, 32), 256, 0, stream>>>(wg, wgu8, cD, cDFF, 0, 64.0f);
    k_tconv8<<<dim3(128, 32), 256, 0, stream>>>(wu, wgu8, cD, cDFF, 16, 64.0f);
    k_tconv <<<dim3(32, 128), 256, 0, stream>>>(wd, wdT, cDFF, cD);

    for (int cb = 0; cb < cDFF; cb += 4096) {
      // fused fp8 gate+up: 8192 interleaved rows -> 4096 bf16 outputs
      k_gemm8<EPI_GLU><<<dim3(MTOK / 256, 32), 512, 0, stream>>>(
          h8m, wgu8 + (size_t)cb * 2 * cD, cbuf, nullptr, cD, 4096, 0);
      k_gemm4<ASRC_BF16, EPI_DOWNACC><<<dim3(MTOK / 128, cD / 128), 256, 0, stream>>>(
          cbuf, wdT + cb, nullptr, xb, nullptr, rs, 4096, cDFF, cD);
    }

    k_rms<<<dim3(MTOK), 256, 0, stream>>>(xb, nout, houtb);

    k_tgt<<<dim3(MTOK / 4), 256, 0, stream>>>(houtb, wlm, ids, anchors, ttok, tlogit);

    // fp8 lm-head (permuted layout): h_out -> fp8, wlm -> fp8 x64; logits = acc/64
    k_cvt8 <<<dim3(1024), 256, 0, stream>>>(houtb, h8, (long)MTOK * cD);
    k_conv8<<<dim3(2048), 256, 0, stream>>>(wlm, wlm8, (long)cV * cD, 64.0f);
    k_gemm8<EPI_STATS><<<dim3(MTOK / 256, NCH2), 512, 0, stream>>>(
        h8, wlm8, nullptr, parts, cD, 0, NCH2);

    k_combine<<<dim3(MTOK), 256, 0, stream>>>(parts, ttok, tlogit, keepA, anchors, lmask, tokOut, NCH2);
    k_final  <<<dim3(1), 256, 0, stream>>>(tokOut, outp);
    return;
  }

  // ---------------- fallback tier (round-3 path, fp32 weights in GEMM)
  const int cwopts[4] = {4096, 2048, 1024, 512};
  int CW = 0;
  for (int ci = 0; ci < 4; ++ci) {
    int cw = cwopts[ci];
    size_t cbufsz = (size_t)MTOK * cw * 2;
    size_t s1 = 2 * szQ;
    size_t s2 = szX + cbufsz;
    size_t sz = s1 > s2 ? s1 : s2;
    size_t pmin = (size_t)MTOK * NCH * 16;
    if (pmin > sz) sz = pmin;
    if (a1off + sz <= ws_size) { CW = cw; break; }
  }
  if (CW == 0) { k_sentinel<<<dim3(1), 64, 0, stream>>>(outp); return; }

  u16*   kb    = (u16*)(wsb + a1off);
  u16*   vb    = (u16*)(wsb + a1off + szQ);
  float* xb    = (float*)(wsb + a1off);
  u16*   cbuf  = (u16*)(wsb + a1off + szX);
  v4f*   parts = (v4f*)(wsb + a1off);
  u16*   hb    = qb;
  u16*   houtb = qb;

  k_rowinv<<<dim3(MKV), 256, 0, stream>>>(hs, emb, ftok, cpos, rowinv);

  k_gemm<ASRC_RMS, 0, EPI_BF16><<<dim3(MKV / 128, cD / 128), 256, 0, stream>>>(
      nullptr, wq, qb, nullptr, nullptr, nullptr, nullptr, rs, cD, cD, cD);
  k_gemm<ASRC_RMS, 0, EPI_BF16><<<dim3(MKV / 128, cD / 128), 256, 0, stream>>>(
      nullptr, wk, kb, nullptr, nullptr, nullptr, nullptr, rs, cD, cD, cD);
  k_gemm<ASRC_RMS, 0, EPI_BF16><<<dim3(MKV / 128, cD / 128), 256, 0, stream>>>(
      nullptr, wv, vb, nullptr, nullptr, nullptr, nullptr, rs, cD, cD, cD);

  k_rope<<<dim3(2 * MKV), 256, 0, stream>>>(qb, kb, anchors, cpos);
  k_attn<<<dim3(cB * cNA * cH), 64, 0, stream>>>(qb, kb, vb);

  k_gemm<ASRC_AOMAP, 0, EPI_OEMB><<<dim3(MTOK / 128, cD / 128), 256, 0, stream>>>(
      qb, wo, nullptr, xb, nullptr, keepA, nullptr, rs, cD, cD, cD);

  k_rms<<<dim3(MTOK), 256, 0, stream>>>(xb, nmlp, hb);

  for (int cb = 0; cb < cDFF; cb += CW) {
    k_gemm<ASRC_BF16, 0, EPI_BF16><<<dim3(MTOK / 128, CW / 128), 256, 0, stream>>>(
        hb, wg + cb, cbuf, nullptr, nullptr, nullptr, nullptr, rs, cD, cDFF, CW);
    k_gemm<ASRC_BF16, 0, EPI_SILU><<<dim3(MTOK / 128, CW / 128), 256, 0, stream>>>(
        hb, wu + cb, cbuf, nullptr, cbuf, nullptr, nullptr, rs, cD, cDFF, CW);
    k_gemm<ASRC_BF16, 0, EPI_DOWNACC><<<dim3(MTOK / 128, cD / 128), 256, 0, stream>>>(
        cbuf, wd + (size_t)cb * cD, nullptr, xb, nullptr, nullptr, nullptr, rs, CW, cD, cD);
  }

  k_rms<<<dim3(MTOK), 256, 0, stream>>>(xb, nout, houtb);

  k_tgt<<<dim3(MTOK / 4), 256, 0, stream>>>(houtb, wlm, ids, anchors, ttok, tlogit);
  k_gemm<ASRC_BF16, 1, EPI_STATS><<<dim3(MTOK / 128, cV / 128), 256, 0, stream>>>(
      houtb, wlm, nullptr, nullptr, nullptr, nullptr, parts, rs, cD, cD, 0);

  k_combine<<<dim3(MTOK), 256, 0, stream>>>(parts, ttok, tlogit, keepA, anchors, lmask, tokOut, NCH);
  k_final  <<<dim3(1), 256, 0, stream>>>(tokOut, outp);
}

// Round 15
// 1443.459 us; speedup vs baseline: 1.1477x; 1.0373x over previous
//
#include <hip/hip_runtime.h>
#include <math.h>

typedef unsigned short u16;
typedef unsigned char u8;
typedef short v8s __attribute__((ext_vector_type(8)));
typedef u16   v4u __attribute__((ext_vector_type(4)));
typedef float v4f __attribute__((ext_vector_type(4)));
typedef int   v2i __attribute__((ext_vector_type(2)));
typedef int   v4i __attribute__((ext_vector_type(4)));

#define DEVFN static __device__ __forceinline__

constexpr int cB = 2, cS = 4096, cD = 2048, cV = 32000, cH = 16, cHD = 128;
constexpr int cBS = 16, cNA = 128, cMASK = 31999, cDFF = 8192;
constexpr int NCAND = cS - cBS + 1;   // 4081 anchor candidates
constexpr int MTOK  = cB * cNA * cBS; // 4096 query tokens
constexpr int MKV   = cB * cNA * 17;  // 4352 kv rows (ctx + 16)
constexpr int NCH   = cV / 128;       // 250 vocab chunks (128-wide, fallback)
constexpr int NCH2  = cV / 256;       // 125 vocab chunks (256-wide, fast)

constexpr int EPI_BF16 = 0, EPI_SILU = 1, EPI_OEMB = 2, EPI_DOWNACC = 3, EPI_STATS = 4, EPI_GLU = 5;
constexpr int ASRC_BF16 = 0, ASRC_RMS = 1, ASRC_AOMAP = 2;

struct RmsSrc {
  const float* hs; const float* emb; const float* nattn; const float* nchs;
  const float* rowinv; const int* ftok; const int* cpos;
};

DEVFN u16 f2bf(float f) {               // RNE fp32 -> bf16
  union { float f; unsigned u; } a; a.f = f;
  unsigned u = a.u;
  u = u + 0x7fffu + ((u >> 16) & 1u);
  return (u16)(u >> 16);
}
DEVFN float bf2f(u16 h) {
  union { unsigned u; float f; } a; a.u = ((unsigned)h) << 16;
  return a.f;
}
DEVFN float waveSum(float v) {
  #pragma unroll
  for (int o = 32; o >= 1; o >>= 1) v += __shfl_xor(v, o);
  return v;
}
DEVFN void gload16(void* lds, const void* g) {
  __builtin_amdgcn_global_load_lds(
      (const __attribute__((address_space(1))) unsigned*)g,
      (__attribute__((address_space(3))) unsigned*)lds, 16, 0, 0);
}
DEVFN int pack4fp8(float a, float b, float c, float d) {
  int p = __builtin_amdgcn_cvt_pk_fp8_f32(a, b, 0, 0);
  p = __builtin_amdgcn_cvt_pk_fp8_f32(c, d, p, 1);
  return p;
}
DEVFN u8 f2fp8(float v) {
  return (u8)(__builtin_amdgcn_cvt_pk_fp8_f32(v, 0.f, 0, 0) & 0xff);
}
// permuted output offset for fp8 buffers: within each 64B K-group,
// newpos = lq*16 + kh*8 + j  for k = kh*32 + lq*8 + j
DEVFN long perm8(long i) {
  return (i & ~63L) | (((i >> 3) & 3) << 4) | (((i >> 5) & 1) << 3);
}

// ---------------------------------------------------------------------------
__global__ void k_select(const float* __restrict__ lmask, const float* __restrict__ rv_in,
                         int* __restrict__ self) {
  int b = blockIdx.x >> 4, chunk = blockIdx.x & 15;
  __shared__ float rvs[4096];
  for (int i = threadIdx.x; i < NCAND; i += 256) {
    bool valid = lmask[(size_t)b * cS + i] > 0.5f;
    rvs[i] = valid ? rv_in[(size_t)b * NCAND + i] : 2.0f;
  }
  __syncthreads();
  int i = chunk * 256 + threadIdx.x;
  if (i < NCAND) {
    float v = rvs[i];
    int rank = 0;
    for (int j = 0; j < NCAND; ++j) {
      float u = rvs[j];
      rank += (u < v) || (u == v && j < i);
    }
    self[(size_t)b * NCAND + i] = (rank < cNA) ? 1 : 0;
  }
}

__global__ void k_anchors(const float* __restrict__ lmask, const int* __restrict__ self,
                          const int* __restrict__ ids, int* __restrict__ anchors,
                          int* __restrict__ keepA, int* __restrict__ ftok, int* __restrict__ cpos) {
  int b = blockIdx.x;
  __shared__ int flags[4096];
  __shared__ int ssum[256];
  __shared__ int soff[257];
  __shared__ int abuf[cNA];
  for (int i = threadIdx.x; i < 4096; i += 256)
    flags[i] = (i < NCAND) ? (self[(size_t)b * NCAND + i] && (lmask[(size_t)b * cS + i] > 0.5f)) : 0;
  if (threadIdx.x < cNA) abuf[threadIdx.x] = 0;
  __syncthreads();
  int s = 0;
  #pragma unroll
  for (int j = 0; j < 16; ++j) s += flags[threadIdx.x * 16 + j];
  ssum[threadIdx.x] = s;
  __syncthreads();
  if (threadIdx.x == 0) {
    int a = 0;
    for (int t = 0; t < 256; ++t) { soff[t] = a; a += ssum[t]; }
    soff[256] = a;
  }
  __syncthreads();
  int nsel = soff[256];
  int p = soff[threadIdx.x];
  for (int j = 0; j < 16; ++j) {
    int i = threadIdx.x * 16 + j;
    if (flags[i]) { if (p < cNA) abuf[p] = i; ++p; }
  }
  __syncthreads();
  if (threadIdx.x < cNA) {
    int q = threadIdx.x;
    int kp = (q < nsel) ? 1 : 0;
    int a = kp ? abuf[q] : 0;
    anchors[b * cNA + q] = a;
    keepA[b * cNA + q] = kp;
    int av = a; if (av < 0) av = 0; if (av > cS - 1) av = cS - 1;
    int tok = ids[(size_t)b * cS + av];
    ftok[b * cNA + q] = kp ? tok : cMASK;
    cpos[b * cNA + q] = (a - 1 > 0) ? (a - 1) : 0;
  }
}

// per-kv-row 1/rms (fallback tier)
__global__ void k_rowinv(const float* __restrict__ hs, const float* __restrict__ emb,
                         const int* __restrict__ ftok, const int* __restrict__ cpos,
                         float* __restrict__ rowinv) {
  int r = blockIdx.x;
  int j = r % 17, bn = r / 17, b = bn >> 7;
  const float* src = (j == 0) ? hs + ((size_t)b * cS + cpos[bn]) * cD
                              : emb + (size_t)((j == 1) ? ftok[bn] : cMASK) * cD;
  float ss = 0.f;
  for (int d = threadIdx.x; d < cD; d += 256) { float v = src[d]; ss += v * v; }
  ss = waveSum(ss);
  __shared__ float red[4];
  if ((threadIdx.x & 63) == 0) red[threadIdx.x >> 6] = ss;
  __syncthreads();
  if (threadIdx.x == 0) {
    float tot = red[0] + red[1] + red[2] + red[3];
    rowinv[r] = 1.0f / sqrtf(tot / cD + 1e-6f);
  }
}

// kv_in = rms'd rows, materialized fp8 perm8 (fast tier). grid: MKV x 256
__global__ void k_build2(const float* __restrict__ hs, const float* __restrict__ emb,
                         const float* __restrict__ nattn, const float* __restrict__ nchs,
                         const int* __restrict__ ftok, const int* __restrict__ cpos,
                         u8* __restrict__ kv8) {
  int r = blockIdx.x;
  int j = r % 17, bn = r / 17, b = bn >> 7;
  const float* src; const float* w;
  if (j == 0) { src = hs + ((size_t)b * cS + cpos[bn]) * cD; w = nchs; }
  else {
    int tok = (j == 1) ? ftok[bn] : cMASK;
    src = emb + (size_t)tok * cD; w = nattn;
  }
  float ss = 0.f;
  for (int d = threadIdx.x; d < cD; d += 256) { float v = src[d]; ss += v * v; }
  ss = waveSum(ss);
  __shared__ float red[4];
  if ((threadIdx.x & 63) == 0) red[threadIdx.x >> 6] = ss;
  __syncthreads();
  float tot = red[0] + red[1] + red[2] + red[3];
  float inv = 1.0f / sqrtf(tot / cD + 1e-6f);
  for (int d = threadIdx.x; d < cD; d += 256)
    kv8[perm8((size_t)r * cD + d)] = f2fp8(src[d] * inv * w[d]);
}

// RMS over fp32 rows -> bf16
__global__ void k_rms(const float* __restrict__ xin, const float* __restrict__ w,
                      u16* __restrict__ outp) {
  int m = blockIdx.x;
  const float* row = xin + (size_t)m * cD;
  float ss = 0.f;
  for (int d = threadIdx.x; d < cD; d += 256) { float v = row[d]; ss += v * v; }
  ss = waveSum(ss);
  __shared__ float red[4];
  if ((threadIdx.x & 63) == 0) red[threadIdx.x >> 6] = ss;
  __syncthreads();
  float tot = red[0] + red[1] + red[2] + red[3];
  float inv = 1.0f / sqrtf(tot / cD + 1e-6f);
  for (int d = threadIdx.x; d < cD; d += 256)
    outp[(size_t)m * cD + d] = f2bf(row[d] * inv * w[d]);
}

// fp32 -> fp8 e4m3 with scale, PERMUTED 64B-group layout. 8 elems/thread
__global__ void k_conv8(const float* __restrict__ in, u8* __restrict__ out, long n, float scale) {
  long i = ((long)blockIdx.x * 256 + threadIdx.x) * 8;
  long stride = (long)gridDim.x * 256 * 8;
  for (; i < n; i += stride) {
    v4f a = *(const v4f*)(in + i), b = *(const v4f*)(in + i + 4);
    v2i pk;
    pk[0] = pack4fp8(a[0] * scale, a[1] * scale, a[2] * scale, a[3] * scale);
    pk[1] = pack4fp8(b[0] * scale, b[1] * scale, b[2] * scale, b[3] * scale);
    *(v2i*)(out + perm8(i)) = pk;
  }
}

// bf16 -> fp8 e4m3, PERMUTED 64B-group layout. 8 elems/thread
__global__ void k_cvt8(const u16* __restrict__ in, u8* __restrict__ out, long n) {
  long i = ((long)blockIdx.x * 256 + threadIdx.x) * 8;
  long stride = (long)gridDim.x * 256 * 8;
  for (; i < n; i += stride) {
    v8s a = *(const v8s*)(in + i);
    v2i pk;
    pk[0] = pack4fp8(bf2f((u16)a[0]), bf2f((u16)a[1]), bf2f((u16)a[2]), bf2f((u16)a[3]));
    pk[1] = pack4fp8(bf2f((u16)a[4]), bf2f((u16)a[5]), bf2f((u16)a[6]), bf2f((u16)a[7]));
    *(v2i*)(out + perm8(i)) = pk;
  }
}

// transpose-convert: W [K][N] fp32 -> WT [N][K] bf16. 64x64 tiles, grid (N/64, K/64)
__global__ void k_tconv(const float* __restrict__ W, u16* __restrict__ WT, int K, int N) {
  __shared__ u16 t[64][72];
  int n0 = blockIdx.x * 64, k0 = blockIdx.y * 64;
  int tid = threadIdx.x;
  int c4 = (tid & 15) * 4, r0 = tid >> 4;
  #pragma unroll
  for (int rr = 0; rr < 64; rr += 16) {
    int k = r0 + rr;
    v4f v = *(const v4f*)(W + (size_t)(k0 + k) * N + n0 + c4);
    #pragma unroll
    for (int e = 0; e < 4; ++e) t[c4 + e][k] = f2bf(v[e]);
  }
  __syncthreads();
  int n = tid >> 2, kq = (tid & 3) * 16;
  v8s o0, o1;
  #pragma unroll
  for (int e = 0; e < 8; ++e) { o0[e] = (short)t[n][kq + e]; o1[e] = (short)t[n][kq + 8 + e]; }
  *(v8s*)(WT + (size_t)(n0 + n) * K + k0 + kq) = o0;
  *(v8s*)(WT + (size_t)(n0 + n) * K + k0 + kq + 8) = o1;
}

// transpose + fp8(scale) + perm8; goff>=0: gate/up interleave (col j -> row
// (j>>4)*32+goff+(j&15)); goff<0: plain (row = col j)
__global__ void k_tconv8(const float* __restrict__ W, u8* __restrict__ WT8,
                         int K, int N, int goff, float scale) {
  __shared__ float tf[64][65];
  int n0 = blockIdx.x * 64, k0 = blockIdx.y * 64;
  int tid = threadIdx.x;
  int c4 = (tid & 15) * 4, r0 = tid >> 4;
  #pragma unroll
  for (int rr = 0; rr < 64; rr += 16) {
    int k = r0 + rr;
    v4f v = *(const v4f*)(W + (size_t)(k0 + k) * N + n0 + c4);
    #pragma unroll
    for (int e = 0; e < 4; ++e) tf[c4 + e][k] = v[e];
  }
  __syncthreads();
  int n = tid >> 2, kq = (tid & 3) * 16;
  int gn = n0 + n;
  size_t rout = (goff >= 0) ? (((size_t)(gn >> 4) << 5) + goff + (gn & 15)) : (size_t)gn;
  long base = (long)rout * K + k0 + kq;
  v2i p0, p1;
  p0[0] = pack4fp8(tf[n][kq + 0] * scale, tf[n][kq + 1] * scale, tf[n][kq + 2] * scale, tf[n][kq + 3] * scale);
  p0[1] = pack4fp8(tf[n][kq + 4] * scale, tf[n][kq + 5] * scale, tf[n][kq + 6] * scale, tf[n][kq + 7] * scale);
  p1[0] = pack4fp8(tf[n][kq + 8] * scale, tf[n][kq + 9] * scale, tf[n][kq + 10] * scale, tf[n][kq + 11] * scale);
  p1[1] = pack4fp8(tf[n][kq + 12] * scale, tf[n][kq + 13] * scale, tf[n][kq + 14] * scale, tf[n][kq + 15] * scale);
  *(v2i*)(WT8 + perm8(base)) = p0;
  *(v2i*)(WT8 + perm8(base + 8)) = p1;
}

// ---------------------------------------------------------------------------
// 8-PHASE PIPELINED 256x256 GEMM fp8 e4m3 (round-12 verified double-buffer):
// b128 fragment reads, 64KB LDS (2 blk/CU), t+2 lookahead, vmcnt(4).
// EPI_STATS: softmax partials (logits = acc/64). EPI_GLU: interleaved gate/up,
// out fp8 perm8 = up * silu(gate) (weights pre-scaled x64 -> acc/64).
template <int EPI>
__launch_bounds__(512, 2)
__global__ void k_gemm8(const u8* __restrict__ A8, const u8* __restrict__ B8,
                        u8* __restrict__ C8, v4f* __restrict__ partials,
                        int K, int ldc, int nch) {
  __shared__ __align__(16) u8 lds8[65536];
  const int tid = threadIdx.x;
  const int lane = tid & 63, wid = tid >> 6;
  const int wm = wid >> 2, wn = wid & 3;        // per-wave out 128x64
  const int lc = lane & 15, lq = lane >> 4;
  const int m0 = blockIdx.x * 256, n0 = blockIdx.y * 256;

  const u8* srcA[2]; const u8* srcB[2];
  #pragma unroll
  for (int i = 0; i < 2; ++i) {
    int ci = i * 512 + tid;
    int r = ci >> 2;
    int logc = (ci & 3) ^ ((r >> 1) & 3);
    srcA[i] = A8 + (size_t)(m0 + r) * K + logc * 16;
    srcB[i] = B8 + (size_t)(n0 + r) * K + logc * 16;
  }

  v4f acc[8][4];
  #pragma unroll
  for (int i = 0; i < 8; ++i)
    #pragma unroll
    for (int j = 0; j < 4; ++j) acc[i][j] = (v4f){0.f, 0.f, 0.f, 0.f};

  const int csw = (lc >> 1) & 3;
  int aoff[8], boff[4];
  #pragma unroll
  for (int mi = 0; mi < 8; ++mi) aoff[mi] = (wm * 128 + mi * 16 + lc) * 64 + ((lq ^ csw) << 4);
  #pragma unroll
  for (int ni = 0; ni < 4; ++ni) boff[ni] = (wn * 64 + ni * 16 + lc) * 64 + ((lq ^ csw) << 4);

  auto stageA = [&](int t, int i) {
    gload16(&lds8[(t & 1) * 32768 + i * 8192 + wid * 1024], srcA[i] + t * 64);
  };
  auto stageB = [&](int t, int i) {
    gload16(&lds8[(t & 1) * 32768 + 16384 + i * 8192 + wid * 1024], srcB[i] + t * 64);
  };

  stageA(0, 0); stageA(0, 1); stageB(0, 0); stageB(0, 1);
  stageA(1, 0); stageA(1, 1); stageB(1, 0); stageB(1, 1);
  asm volatile("s_waitcnt vmcnt(4)" ::: "memory");
  __builtin_amdgcn_s_barrier();

  union Frag { v4i v; long long ll[2]; };
  const int NT = K >> 6;
  for (int t = 0; t < NT; ++t) {
    const u8* Ab = &lds8[(t & 1) * 32768];
    const u8* Bb = Ab + 16384;
    Frag fa[8], fb[4];

    // q0: read all B + A0-3 (b128 each, both K-halves); MFMA kh0 mi0-3
    #pragma unroll
    for (int ni = 0; ni < 4; ++ni) fb[ni].v = *(const v4i*)(Bb + boff[ni]);
    #pragma unroll
    for (int mi = 0; mi < 4; ++mi) fa[mi].v = *(const v4i*)(Ab + aoff[mi]);
    asm volatile("s_waitcnt lgkmcnt(0)" ::: "memory");
    __builtin_amdgcn_sched_barrier(0);
    __builtin_amdgcn_s_setprio(1);
    #pragma unroll
    for (int mi = 0; mi < 4; ++mi)
      #pragma unroll
      for (int ni = 0; ni < 4; ++ni)
        acc[mi][ni] = __builtin_amdgcn_mfma_f32_16x16x32_fp8_fp8(fa[mi].ll[0], fb[ni].ll[0], acc[mi][ni], 0, 0, 0);
    __builtin_amdgcn_s_setprio(0);
    __builtin_amdgcn_s_barrier();

    // q1: read A4-7; stage B(t+2).0 into cur B-region (dead after q0 barrier)
    #pragma unroll
    for (int mi = 0; mi < 4; ++mi) fa[mi + 4].v = *(const v4i*)(Ab + aoff[mi + 4]);
    if (t + 2 < NT) stageB(t + 2, 0);
    asm volatile("s_waitcnt lgkmcnt(0)" ::: "memory");
    __builtin_amdgcn_sched_barrier(0);
    __builtin_amdgcn_s_setprio(1);
    #pragma unroll
    for (int mi = 0; mi < 4; ++mi)
      #pragma unroll
      for (int ni = 0; ni < 4; ++ni)
        acc[mi + 4][ni] = __builtin_amdgcn_mfma_f32_16x16x32_fp8_fp8(fa[mi + 4].ll[0], fb[ni].ll[0], acc[mi + 4][ni], 0, 0, 0);
    __builtin_amdgcn_s_setprio(0);
    __builtin_amdgcn_s_barrier();

    // q2: no reads (kh1 from regs); stage B(t+2).1, A(t+2).0
    if (t + 2 < NT) { stageB(t + 2, 1); stageA(t + 2, 0); }
    __builtin_amdgcn_s_setprio(1);
    #pragma unroll
    for (int mi = 0; mi < 4; ++mi)
      #pragma unroll
      for (int ni = 0; ni < 4; ++ni)
        acc[mi][ni] = __builtin_amdgcn_mfma_f32_16x16x32_fp8_fp8(fa[mi].ll[1], fb[ni].ll[1], acc[mi][ni], 0, 0, 0);
    __builtin_amdgcn_s_setprio(0);
    __builtin_amdgcn_s_barrier();

    // q3: stage A(t+2).1; MFMA kh1 mi4-7; per-tile counted vmcnt
    if (t + 2 < NT) stageA(t + 2, 1);
    __builtin_amdgcn_s_setprio(1);
    #pragma unroll
    for (int mi = 0; mi < 4; ++mi)
      #pragma unroll
      for (int ni = 0; ni < 4; ++ni)
        acc[mi + 4][ni] = __builtin_amdgcn_mfma_f32_16x16x32_fp8_fp8(fa[mi + 4].ll[1], fb[ni].ll[1], acc[mi + 4][ni], 0, 0, 0);
    __builtin_amdgcn_s_setprio(0);
    if (t + 2 < NT) { asm volatile("s_waitcnt vmcnt(4)" ::: "memory"); }
    else            { asm volatile("s_waitcnt vmcnt(0)" ::: "memory"); }
    __builtin_amdgcn_s_barrier();
  }
  asm volatile("s_waitcnt vmcnt(0)" ::: "memory");

  // undo the x64 weight scale
  #pragma unroll
  for (int mi = 0; mi < 8; ++mi)
    #pragma unroll
    for (int ni = 0; ni < 4; ++ni)
      acc[mi][ni] *= 0.015625f;

  if constexpr (EPI == EPI_GLU) {
    #pragma unroll
    for (int mi = 0; mi < 8; ++mi)
      #pragma unroll
      for (int np = 0; np < 2; ++np)
        #pragma unroll
        for (int r = 0; r < 4; ++r) {
          int grow = m0 + wm * 128 + mi * 16 + lq * 4 + r;
          int gcol = (n0 >> 1) + wn * 32 + np * 16 + lc;
          float g = acc[mi][2 * np][r];
          float u = acc[mi][2 * np + 1][r];
          C8[perm8((size_t)grow * ldc + gcol)] = f2fp8(u * g / (1.0f + __expf(-g)));
        }
    return;
  } else {
    // EPI_STATS: epilogue scratch aliased onto (dead) staging LDS
    float* s_mx = (float*)lds8;
    float* s_sm = (float*)(lds8 + 4096);
    int*   s_ax = (int*)(lds8 + 8192);
    __syncthreads();
    #pragma unroll
    for (int mi = 0; mi < 8; ++mi) {
      #pragma unroll
      for (int r = 0; r < 4; ++r) {
        float v0 = acc[mi][0][r], v1 = acc[mi][1][r], v2 = acc[mi][2][r], v3 = acc[mi][3][r];
        float mx = v0; int ax = lc;
        if (v1 > mx) { mx = v1; ax = 16 + lc; }
        if (v2 > mx) { mx = v2; ax = 32 + lc; }
        if (v3 > mx) { mx = v3; ax = 48 + lc; }
        #pragma unroll
        for (int off = 1; off < 16; off <<= 1) {
          float om = __shfl_xor(mx, off); int oa = __shfl_xor(ax, off);
          if (om > mx || (om == mx && oa < ax)) { mx = om; ax = oa; }
        }
        float se = __expf(v0 - mx) + __expf(v1 - mx) + __expf(v2 - mx) + __expf(v3 - mx);
        #pragma unroll
        for (int off = 1; off < 16; off <<= 1) se += __shfl_xor(se, off);
        if (lc == 0) {
          int row = wm * 128 + mi * 16 + lq * 4 + r;
          s_mx[row * 4 + wn] = mx; s_sm[row * 4 + wn] = se; s_ax[row * 4 + wn] = wn * 64 + ax;
        }
      }
    }
    __syncthreads();
    if (tid < 256) {
      float gm = s_mx[tid * 4]; int ga = s_ax[tid * 4];
      #pragma unroll
      for (int w = 1; w < 4; ++w) {
        float m = s_mx[tid * 4 + w];
        if (m > gm) { gm = m; ga = s_ax[tid * 4 + w]; }
      }
      float gs = 0.f;
      #pragma unroll
      for (int w = 0; w < 4; ++w) gs += s_sm[tid * 4 + w] * __expf(s_mx[tid * 4 + w] - gm);
      v4f rec; rec[0] = gm; rec[1] = gs; rec[2] = __int_as_float(n0 + ga); rec[3] = 0.f;
      partials[(size_t)(m0 + tid) * nch + blockIdx.y] = rec;
    }
  }
}

// ---------------------------------------------------------------------------
// PIPELINED 128x128 GEMM fp8 e4m3 (gemm4's verified 2-phase skeleton x gemm8's
// conflict-free fp8 geometry): BK=64B, 4 waves, 32KB dbuf LDS (4 blk/CU),
// counted vmcnt(4). acc scaled by 1/64 (B weights pre-x64).
template <int EPI>
__launch_bounds__(256, 4)
__global__ void k_gemm9(const u8* __restrict__ A8, const u8* __restrict__ B8,
                        u16* __restrict__ Cbf, float* __restrict__ Cf32,
                        const int* __restrict__ keepArr, RmsSrc rs,
                        int K, int ldb, int ldc) {
  __shared__ __align__(16) u8 lds8[32768];      // buf b at b*16384; A 8KB, B at +8192
  const int tid = threadIdx.x;
  const int lane = tid & 63, wid = tid >> 6;
  const int wm = wid >> 1, wn = wid & 1;        // per-wave out 64x64
  const int lc = lane & 15, lq = lane >> 4;
  const int m0 = blockIdx.x * 128, n0 = blockIdx.y * 128;

  const u8* srcA[2]; const u8* srcB[2];
  #pragma unroll
  for (int i = 0; i < 2; ++i) {
    int ci = i * 256 + tid;
    int r = ci >> 2;
    int logc = (ci & 3) ^ ((r >> 1) & 3);
    srcA[i] = A8 + (size_t)(m0 + r) * K + logc * 16;
    srcB[i] = B8 + (size_t)(n0 + r) * ldb + logc * 16;
  }

  v4f acc[4][4];
  #pragma unroll
  for (int i = 0; i < 4; ++i)
    #pragma unroll
    for (int j = 0; j < 4; ++j) acc[i][j] = (v4f){0.f, 0.f, 0.f, 0.f};

  const int csw = (lc >> 1) & 3;
  int aoff[4], boff[4];
  #pragma unroll
  for (int mi = 0; mi < 4; ++mi) aoff[mi] = (wm * 64 + mi * 16 + lc) * 64 + ((lq ^ csw) << 4);
  #pragma unroll
  for (int ni = 0; ni < 4; ++ni) boff[ni] = (wn * 64 + ni * 16 + lc) * 64 + ((lq ^ csw) << 4);

  auto stageTo = [&](int b, int t) {
    #pragma unroll
    for (int i = 0; i < 2; ++i) {
      gload16(&lds8[b * 16384 + i * 4096 + wid * 1024], srcA[i] + t * 64);
      gload16(&lds8[b * 16384 + 8192 + i * 4096 + wid * 1024], srcB[i] + t * 64);
    }
  };

  stageTo(0, 0);
  union Frag { v4i v; long long ll[2]; };
  const int NT = K >> 6;
  for (int t = 0; t < NT; ++t) {
    const int cur = t & 1;
    if (t + 1 < NT) {
      stageTo(cur ^ 1, t + 1);
      asm volatile("s_waitcnt vmcnt(4)" ::: "memory");
    } else {
      asm volatile("s_waitcnt vmcnt(0)" ::: "memory");
    }
    __builtin_amdgcn_s_barrier();
    const u8* Ab = &lds8[cur * 16384];
    const u8* Bb = Ab + 8192;
    Frag fa[4], fb[4];
    #pragma unroll
    for (int mi = 0; mi < 4; ++mi) fa[mi].v = *(const v4i*)(Ab + aoff[mi]);
    #pragma unroll
    for (int ni = 0; ni < 4; ++ni) fb[ni].v = *(const v4i*)(Bb + boff[ni]);
    __builtin_amdgcn_s_setprio(1);
    #pragma unroll
    for (int mi = 0; mi < 4; ++mi)
      #pragma unroll
      for (int ni = 0; ni < 4; ++ni)
        acc[mi][ni] = __builtin_amdgcn_mfma_f32_16x16x32_fp8_fp8(fa[mi].ll[0], fb[ni].ll[0], acc[mi][ni], 0, 0, 0);
    __builtin_amdgcn_s_setprio(0);
    asm volatile("s_waitcnt lgkmcnt(0)" ::: "memory");
    __builtin_amdgcn_sched_barrier(0);
    __builtin_amdgcn_s_barrier();
    __builtin_amdgcn_s_setprio(1);
    #pragma unroll
    for (int mi = 0; mi < 4; ++mi)
      #pragma unroll
      for (int ni = 0; ni < 4; ++ni)
        acc[mi][ni] = __builtin_amdgcn_mfma_f32_16x16x32_fp8_fp8(fa[mi].ll[1], fb[ni].ll[1], acc[mi][ni], 0, 0, 0);
    __builtin_amdgcn_s_setprio(0);
  }

  #pragma unroll
  for (int mi = 0; mi < 4; ++mi)
    #pragma unroll
    for (int ni = 0; ni < 4; ++ni)
      #pragma unroll
      for (int r = 0; r < 4; ++r) {
        int grow = m0 + wm * 64 + mi * 16 + lq * 4 + r;
        int gcol = n0 + wn * 64 + ni * 16 + lc;
        size_t idx = (size_t)grow * ldc + gcol;
        float vv = acc[mi][ni][r] * 0.015625f;
        if constexpr (EPI == EPI_BF16) {
          Cbf[idx] = f2bf(vv);
        } else if constexpr (EPI == EPI_OEMB) {
          int t_ = grow & 15, bn = grow >> 4;
          int tok = (t_ == 0) ? rs.ftok[bn] : cMASK;
          float kf = (float)keepArr[bn];
          Cf32[idx] = rs.emb[(size_t)tok * cD + gcol] + vv * kf;
        } else {  // EPI_DOWNACC
          Cf32[idx] += vv;
        }
      }
}

// ---------------------------------------------------------------------------
// FALLBACK GEMM (round-3): fp32 B converted during staging.
template <int ASRC, int BLAYOUT, int EPI>
__launch_bounds__(256)
__global__ void k_gemm(const u16* __restrict__ Abf, const float* __restrict__ Bw,
                       u16* Cbf, float* Cf32, const u16* Gaux,
                       const int* __restrict__ keepArr, v4f* __restrict__ partials,
                       RmsSrc rs, int K, int ldb, int ldc) {
  __shared__ __align__(16) u16 As[128][40];
  __shared__ __align__(16) u16 Bs[128][40];
  const int tid = threadIdx.x;
  const int m0 = blockIdx.x * 128, n0 = blockIdx.y * 128;
  const int lane = tid & 63, wid = tid >> 6;
  const int wm = wid >> 1, wn = wid & 1;
  const int lc = lane & 15, lk8 = (lane >> 4) * 8;
  const int srow = tid >> 2, sk8 = (tid & 3) * 8;
  v4f acc[4][4];
  #pragma unroll
  for (int i = 0; i < 4; ++i)
    #pragma unroll
    for (int j = 0; j < 4; ++j) acc[i][j] = (v4f){0.f, 0.f, 0.f, 0.f};

  for (int kt = 0; kt < K; kt += 32) {
    __syncthreads();
    for (int mm = srow; mm < 128; mm += 64) {
      if constexpr (ASRC == ASRC_BF16) {
        *(v8s*)&As[mm][sk8] = *(const v8s*)(Abf + (size_t)(m0 + mm) * K + kt + sk8);
      } else if constexpr (ASRC == ASRC_AOMAP) {
        int m = m0 + mm, bn = m >> 4, t = m & 15;
        *(v8s*)&As[mm][sk8] = *(const v8s*)(Abf + (size_t)(bn * 17 + 1 + t) * K + kt + sk8);
      } else {
        int R = m0 + mm;
        int j = R % 17, bn = R / 17, b = bn >> 7;
        const float* src; const float* nw;
        if (j == 0) { src = rs.hs + ((size_t)b * cS + rs.cpos[bn]) * cD; nw = rs.nchs; }
        else {
          int tok = (j == 1) ? rs.ftok[bn] : cMASK;
          src = rs.emb + (size_t)tok * cD; nw = rs.nattn;
        }
        float inv = rs.rowinv[R];
        const v4f* sp = (const v4f*)(src + kt + sk8);
        const v4f* np_ = (const v4f*)(nw + kt + sk8);
        v4f s0 = sp[0], s1 = sp[1], w0 = np_[0], w1 = np_[1];
        v8s pk;
        #pragma unroll
        for (int e = 0; e < 4; ++e) pk[e] = (short)f2bf(s0[e] * inv * w0[e]);
        #pragma unroll
        for (int e = 0; e < 4; ++e) pk[4 + e] = (short)f2bf(s1[e] * inv * w1[e]);
        *(v8s*)&As[mm][sk8] = pk;
      }
    }
    if constexpr (BLAYOUT == 1) {
      for (int nn = srow; nn < 128; nn += 64) {
        const v4f* bp = (const v4f*)(Bw + (size_t)(n0 + nn) * ldb + kt + sk8);
        v4f b0 = bp[0], b1 = bp[1];
        v8s pk;
        #pragma unroll
        for (int e = 0; e < 4; ++e) { pk[e] = (short)f2bf(b0[e]); pk[4 + e] = (short)f2bf(b1[e]); }
        *(v8s*)&Bs[nn][sk8] = pk;
      }
    } else {
      const int bn_ = tid & 127, kq = tid >> 7;
      for (int kk = kq; kk < 8; kk += 2) {
        const int k4 = kk * 4;
        const float* bp = Bw + (size_t)(kt + k4) * ldb + n0 + bn_;
        v4u pk;
        #pragma unroll
        for (int e = 0; e < 4; ++e) pk[e] = f2bf(bp[(size_t)e * ldb]);
        *(v4u*)&Bs[bn_][k4] = pk;
      }
    }
    __syncthreads();
    v8s af[4], bf_[4];
    #pragma unroll
    for (int i = 0; i < 4; ++i) af[i] = *(const v8s*)&As[wm * 64 + i * 16 + lc][lk8];
    #pragma unroll
    for (int i = 0; i < 4; ++i) bf_[i] = *(const v8s*)&Bs[wn * 64 + i * 16 + lc][lk8];
    #pragma unroll
    for (int mi = 0; mi < 4; ++mi)
      #pragma unroll
      for (int ni = 0; ni < 4; ++ni)
        acc[mi][ni] = __builtin_amdgcn_mfma_f32_16x16x32_bf16(af[mi], bf_[ni], acc[mi][ni], 0, 0, 0);
  }

  if constexpr (EPI == EPI_STATS) {
    __shared__ float s_mx[128][2], s_sm[128][2];
    __shared__ int s_ax[128][2];
    #pragma unroll
    for (int mi = 0; mi < 4; ++mi) {
      #pragma unroll
      for (int r = 0; r < 4; ++r) {
        float v0 = acc[mi][0][r], v1 = acc[mi][1][r], v2 = acc[mi][2][r], v3 = acc[mi][3][r];
        float mx = v0; int ax = lc;
        if (v1 > mx) { mx = v1; ax = 16 + lc; }
        if (v2 > mx) { mx = v2; ax = 32 + lc; }
        if (v3 > mx) { mx = v3; ax = 48 + lc; }
        #pragma unroll
        for (int off = 1; off < 16; off <<= 1) {
          float om = __shfl_xor(mx, off); int oa = __shfl_xor(ax, off);
          if (om > mx || (om == mx && oa < ax)) { mx = om; ax = oa; }
        }
        float se = __expf(v0 - mx) + __expf(v1 - mx) + __expf(v2 - mx) + __expf(v3 - mx);
        #pragma unroll
        for (int off = 1; off < 16; off <<= 1) se += __shfl_xor(se, off);
        if (lc == 0) {
          int lr = wm * 64 + mi * 16 + (lane >> 4) * 4 + r;
          s_mx[lr][wn] = mx; s_sm[lr][wn] = se; s_ax[lr][wn] = wn * 64 + ax;
        }
      }
    }
    __syncthreads();
    if (tid < 128) {
      float ma = s_mx[tid][0], mb = s_mx[tid][1];
      float gm = fmaxf(ma, mb);
      float gs = s_sm[tid][0] * __expf(ma - gm) + s_sm[tid][1] * __expf(mb - gm);
      int ga = (ma >= mb) ? s_ax[tid][0] : s_ax[tid][1];
      v4f rec; rec[0] = gm; rec[1] = gs; rec[2] = __int_as_float(n0 + ga); rec[3] = 0.f;
      partials[(size_t)(m0 + tid) * NCH + blockIdx.y] = rec;
    }
    return;
  } else {
    #pragma unroll
    for (int mi = 0; mi < 4; ++mi)
      #pragma unroll
      for (int ni = 0; ni < 4; ++ni)
        #pragma unroll
        for (int r = 0; r < 4; ++r) {
          int grow = m0 + wm * 64 + mi * 16 + (lane >> 4) * 4 + r;
          int gcol = n0 + wn * 64 + ni * 16 + lc;
          size_t idx = (size_t)grow * ldc + gcol;
          float vv = acc[mi][ni][r];
          if constexpr (EPI == EPI_BF16) {
            Cbf[idx] = f2bf(vv);
          } else if constexpr (EPI == EPI_SILU) {
            float g = bf2f(Gaux[idx]);
            Cbf[idx] = f2bf(vv * g / (1.0f + __expf(-g)));
          } else if constexpr (EPI == EPI_OEMB) {
            int t = grow & 15, bn = grow >> 4;
            int tok = (t == 0) ? rs.ftok[bn] : cMASK;
            float kf = (float)keepArr[bn];
            Cf32[idx] = rs.emb[(size_t)tok * cD + gcol] + vv * kf;
          } else {
            Cf32[idx] += vv;
          }
        }
  }
}

// ---------------------------------------------------------------------------
__global__ void k_rope(u16* __restrict__ qb, u16* __restrict__ kb,
                       const int* __restrict__ anchors, const int* __restrict__ cpos) {
  int r = blockIdx.x;
  int which = (r >= MKV);
  int rr = which ? r - MKV : r;
  int j = rr % 17, bn = rr / 17;
  if (!which && j == 0) return;
  u16* buf = which ? kb : qb;
  int pos = (which && j == 0) ? cpos[bn] : (anchors[bn] + j - 1);
  float fp = (float)pos;
  for (int p = threadIdx.x; p < cH * 64; p += 256) {
    int h = p >> 6, i = p & 63;
    size_t base = (size_t)rr * cD + h * cHD;
    float x1 = bf2f(buf[base + i]);
    float x2 = bf2f(buf[base + 64 + i]);
    float freq = powf(10000.0f, -((float)(2 * i)) / 128.0f);
    float ang = fp * freq;
    float sn = sinf(ang), cn = cosf(ang);
    buf[base + i]      = f2bf(x1 * cn - x2 * sn);
    buf[base + 64 + i] = f2bf(x2 * cn + x1 * sn);
  }
}

// Attention. If ao8 != nullptr, writes attn-out compact fp8 perm8 (token rows);
// else writes in place over q rows (fallback tier).
__global__ void k_attn(u16* __restrict__ qb, const u16* __restrict__ kb,
                       const u16* __restrict__ vb, u8* __restrict__ ao8) {
  int blk = blockIdx.x;
  int h = blk % cH, bn = blk / cH;
  __shared__ float qs[16][128], ks[17][128], vs[17][128], ps[16][18];
  int lane = threadIdx.x;
  for (int e = lane; e < 16 * 128; e += 64) {
    int r = e >> 7, d = e & 127;
    qs[r][d] = bf2f(qb[((size_t)(bn * 17 + 1 + r)) * cD + h * cHD + d]);
  }
  for (int e = lane; e < 17 * 128; e += 64) {
    int r = e >> 7, d = e & 127;
    ks[r][d] = bf2f(kb[((size_t)(bn * 17 + r)) * cD + h * cHD + d]);
    vs[r][d] = bf2f(vb[((size_t)(bn * 17 + r)) * cD + h * cHD + d]);
  }
  __syncthreads();
  for (int e = lane; e < 16 * 17; e += 64) {
    int qi = e / 17, ki = e % 17;
    float s = 0.f;
    for (int d = 0; d < 128; ++d) s += qs[qi][d] * ks[ki][d];
    ps[qi][ki] = s * 0.08838834764831845f;
  }
  __syncthreads();
  if (lane < 16) {
    float m = -3e38f;
    for (int kk = 0; kk < 17; ++kk) m = fmaxf(m, ps[lane][kk]);
    float s = 0.f;
    for (int kk = 0; kk < 17; ++kk) { float e_ = __expf(ps[lane][kk] - m); ps[lane][kk] = e_; s += e_; }
    float is = 1.0f / s;
    for (int kk = 0; kk < 17; ++kk) ps[lane][kk] *= is;
  }
  __syncthreads();
  for (int e = lane; e < 16 * 128; e += 64) {
    int qi = e >> 7, d = e & 127;
    float s = 0.f;
    for (int kk = 0; kk < 17; ++kk) s += ps[qi][kk] * vs[kk][d];
    if (ao8) ao8[perm8((size_t)(bn * 16 + qi) * cD + h * cHD + d)] = f2fp8(s);
    else     qb[((size_t)(bn * 17 + 1 + qi)) * cD + h * cHD + d] = f2bf(s);
  }
}

__global__ void k_tgt(const u16* __restrict__ hout, const float* __restrict__ Wlm,
                      const int* __restrict__ ids, const int* __restrict__ anchors,
                      int* __restrict__ tgt_tok, float* __restrict__ tgt_logit) {
  int w = threadIdx.x >> 6, lane = threadIdx.x & 63;
  int m = blockIdx.x * 4 + w;
  int bn = m >> 4, t = m & 15, b = bn / cNA;
  int label = anchors[bn] + t;
  int sl = (label < cS - 1) ? label : (cS - 1);
  int tok = ids[(size_t)b * cS + sl];
  const u16* hr = hout + (size_t)m * cD;
  const float* wr = Wlm + (size_t)tok * cD;
  float s = 0.f;
  for (int d = lane; d < cD; d += 64) s += bf2f(hr[d]) * wr[d];
  s = waveSum(s);
  if (lane == 0) { tgt_tok[m] = tok; tgt_logit[m] = s; }
}

__global__ void k_combine(const v4f* __restrict__ partials, const int* __restrict__ tgt_tok,
                          const float* __restrict__ tgt_logit, const int* __restrict__ keepArr,
                          const int* __restrict__ anchors, const float* __restrict__ lmask,
                          float* __restrict__ tokOut, int nch) {
  int m = blockIdx.x;
  int tid = threadIdx.x, lane = tid & 63, w = tid >> 6;
  float cm = -3.0e38f, cs = 0.f; int ca = 0x7fffffff;
  if (tid < nch) {
    v4f rec = partials[(size_t)m * nch + tid];
    cm = rec[0]; cs = rec[1]; ca = __float_as_int(rec[2]);
  }
  float gm = cm; int ga = ca;
  #pragma unroll
  for (int off = 1; off < 64; off <<= 1) {
    float om = __shfl_xor(gm, off); int oa = __shfl_xor(ga, off);
    if (om > gm || (om == gm && oa < ga)) { gm = om; ga = oa; }
  }
  __shared__ float wmx[4]; __shared__ int wax[4]; __shared__ float wsm[4];
  if (lane == 0) { wmx[w] = gm; wax[w] = ga; }
  __syncthreads();
  if (tid == 0) {
    for (int i = 1; i < 4; ++i)
      if (wmx[i] > wmx[0] || (wmx[i] == wmx[0] && wax[i] < wax[0])) { wmx[0] = wmx[i]; wax[0] = wax[i]; }
  }
  __syncthreads();
  gm = wmx[0]; ga = wax[0];
  float s = (tid < nch) ? cs * __expf(cm - gm) : 0.f;
  s = waveSum(s);
  if (lane == 0) wsm[w] = s;
  __syncthreads();
  if (tid == 0) {
    float gs = wsm[0] + wsm[1] + wsm[2] + wsm[3];
    float logZ = gm + logf(gs);
    int bn = m >> 4, t = m & 15, b = bn / cNA;
    int label = anchors[bn] + t;
    int sl = (label < cS - 1) ? label : (cS - 1);
    float wgt = (float)keepArr[bn] * ((t > 0) ? 1.f : 0.f) * ((label < cS) ? 1.f : 0.f) *
                lmask[(size_t)b * cS + sl];
    float lp = tgt_logit[m] - logZ;
    int tg = tgt_tok[m];
    tokOut[m * 4 + 0] = lp * wgt;
    tokOut[m * 4 + 1] = wgt;
    tokOut[m * 4 + 2] = ((ga == tg) && (wgt > 0.5f)) ? 1.f : 0.f;
    tokOut[m * 4 + 3] = 0.f;
  }
}

__global__ void k_final(const float* __restrict__ tokOut, float* __restrict__ outp) {
  int tid = threadIdx.x;
  float swl = 0.f, sw = 0.f, sm = 0.f;
  for (int m = tid; m < MTOK; m += 256) {
    swl += tokOut[m * 4 + 0];
    sw  += tokOut[m * 4 + 1];
    sm  += tokOut[m * 4 + 2];
  }
  swl = waveSum(swl); sw = waveSum(sw); sm = waveSum(sm);
  __shared__ float r0[4], r1[4], r2[4];
  int lane = tid & 63, w = tid >> 6;
  if (lane == 0) { r0[w] = swl; r1[w] = sw; r2[w] = sm; }
  __syncthreads();
  if (tid == 0) {
    float a = r0[0] + r0[1] + r0[2] + r0[3];
    float b = r1[0] + r1[1] + r1[2] + r1[3];
    float c = r2[0] + r2[1] + r2[2] + r2[3];
    float denom = b + 1e-6f;
    float loss = -a / denom;
    float acc  = c / denom;
    if (b == 0.0f) loss = -300.0f;
    outp[0] = loss;
    outp[1] = acc;
  }
}

__global__ void k_heartbeat(float* outp) {
  if (threadIdx.x == 0) { outp[0] = -55.0f; outp[1] = -55.0f; }
}
__global__ void k_sentinel(float* outp) {
  if (threadIdx.x == 0) { outp[0] = -777.0f; outp[1] = -777.0f; }
}

// ---------------------------------------------------------------------------
extern "C" void kernel_launch(void* const* d_in, const int* in_sizes, int n_in,
                              void* d_out, int out_size, void* d_ws, size_t ws_size,
                              hipStream_t stream) {
  const int*   ids   = (const int*)  d_in[0];
  const float* hs    = (const float*)d_in[1];
  const float* lmask = (const float*)d_in[2];
  const float* rv    = (const float*)d_in[3];
  const float* emb   = (const float*)d_in[4];
  const float* wlm   = (const float*)d_in[5];
  const float* wq    = (const float*)d_in[6];
  const float* wk    = (const float*)d_in[7];
  const float* wv    = (const float*)d_in[8];
  const float* wo    = (const float*)d_in[9];
  const float* wg    = (const float*)d_in[10];
  const float* wu    = (const float*)d_in[11];
  const float* wd    = (const float*)d_in[12];
  const float* nattn = (const float*)d_in[13];
  const float* nmlp  = (const float*)d_in[14];
  const float* nout  = (const float*)d_in[15];
  const float* nchs  = (const float*)d_in[16];
  (void)in_sizes; (void)n_in; (void)out_size;

  float* outp = (float*)d_out;
  k_heartbeat<<<dim3(1), 64, 0, stream>>>(outp);

  char* wsb = (char*)d_ws;
  size_t off = 0;
  auto alloc = [&](size_t bytes) -> void* {
    void* p = wsb + off;
    off = (off + bytes + 255) & ~(size_t)255;
    return p;
  };
  int*   anchors = (int*)  alloc((size_t)cB * cNA * 4);
  int*   keepA   = (int*)  alloc((size_t)cB * cNA * 4);
  int*   ftok    = (int*)  alloc((size_t)cB * cNA * 4);
  int*   cpos    = (int*)  alloc((size_t)cB * cNA * 4);
  int*   self    = (int*)  alloc((size_t)cB * NCAND * 4);
  float* rowinv  = (float*)alloc((size_t)MKV * 4);
  int*   ttok    = (int*)  alloc((size_t)MTOK * 4);
  float* tlogit  = (float*)alloc((size_t)MTOK * 4);
  float* tokOut  = (float*)alloc((size_t)MTOK * 4 * 4);

  const size_t szQ  = (size_t)MKV * cD * 2;           // 17.8 MB (q -> h -> h_out)
  const size_t szX  = (size_t)MTOK * cD * 4;          // 33.6 MB (fp32 residual)
  u16* qb = (u16*)alloc(szQ);
  const size_t a1off = off;

  RmsSrc rs{hs, emb, nattn, nchs, rowinv, ftok, cpos};

  // common head
  k_select <<<dim3(cB * 16), 256, 0, stream>>>(lmask, rv, self);
  k_anchors<<<dim3(cB),      256, 0, stream>>>(lmask, self, ids, anchors, keepA, ftok, cpos);

  // ---------------- fast tier
  size_t kvb_off  = a1off;                            // kv8 fp8: 8.9 MB
  size_t a1f_off  = (kvb_off + szQ + 255) & ~(size_t)255;  // reuse old region size
  size_t a1f_sz   = 2 * szQ > (szX + (size_t)MTOK * 4096 * 2) ? 2 * szQ
                                                             : (szX + (size_t)MTOK * 4096 * 2);
  size_t wreg_off = (a1f_off + a1f_sz + 255) & ~(size_t)255;
  size_t wreg_sz  = (size_t)cV * cD * 2;              // 131 MB (largest stage)
  size_t need_fast = wreg_off + wreg_sz;

  if (need_fast <= ws_size) {
    u8*    kv8   = (u8*)(wsb + kvb_off);
    u16*   kb    = (u16*)(wsb + a1f_off);
    u16*   vb    = (u16*)(wsb + a1f_off + szQ);
    float* xb    = (float*)(wsb + a1f_off);
    u8*    ao8   = (u8*)(wsb + a1f_off + 2 * szQ);    // 35.7..44.1 MB (after kb,vb)
    u8*    cbuf8 = (u8*)(wsb + a1f_off + 2 * szQ + (size_t)MTOK * cD);  // 44.1..60.9
    v4f*   parts = (v4f*)(wsb + a1f_off);             // lm-head stage (xb dead)
    u8*    h8    = (u8*)(wsb + a1f_off + (size_t)16 * 1024 * 1024);
    u16*   hb    = qb;
    u16*   houtb = qb;
    u16*   wT    = (u16*)(wsb + wreg_off);
    const size_t szDD = (size_t)cD * cD;
    u8* wq8 = (u8*)wT;        u8* wk8 = wq8 + szDD;
    u8* wv8 = wq8 + 2 * szDD; u8* wo8 = wq8 + 3 * szDD;   // 4 x 4.2 MB
    const size_t szDF = (size_t)cD * cDFF;
    u8* wgu8 = (u8*)wT;                               // stage 2: 33.5 MB
    u8* wd8  = (u8*)wT + 2 * szDF;                    // +33.5 MB, 16.8 MB
    u8* h8m  = (u8*)wT + 3 * szDF;                    // +50.3 MB, 8.4 MB
    u8* wlm8 = (u8*)wT;                               // stage 3: 65.5 MB

    k_build2<<<dim3(MKV), 256, 0, stream>>>(hs, emb, nattn, nchs, ftok, cpos, kv8);

    k_tconv8<<<dim3(32, 32), 256, 0, stream>>>(wq, wq8, cD, cD, -1, 64.0f);
    k_tconv8<<<dim3(32, 32), 256, 0, stream>>>(wk, wk8, cD, cD, -1, 64.0f);
    k_tconv8<<<dim3(32, 32), 256, 0, stream>>>(wv, wv8, cD, cD, -1, 64.0f);
    k_tconv8<<<dim3(32, 32), 256, 0, stream>>>(wo, wo8, cD, cD, -1, 64.0f);

    k_gemm9<EPI_BF16><<<dim3(MKV / 128, cD / 128), 256, 0, stream>>>(
        kv8, wq8, qb, nullptr, nullptr, rs, cD, cD, cD);
    k_gemm9<EPI_BF16><<<dim3(MKV / 128, cD / 128), 256, 0, stream>>>(
        kv8, wk8, kb, nullptr, nullptr, rs, cD, cD, cD);
    k_gemm9<EPI_BF16><<<dim3(MKV / 128, cD / 128), 256, 0, stream>>>(
        kv8, wv8, vb, nullptr, nullptr, rs, cD, cD, cD);

    k_rope<<<dim3(2 * MKV), 256, 0, stream>>>(qb, kb, anchors, cpos);
    k_attn<<<dim3(cB * cNA * cH), 64, 0, stream>>>(qb, kb, vb, ao8);

    k_gemm9<EPI_OEMB><<<dim3(MTOK / 128, cD / 128), 256, 0, stream>>>(
        ao8, wo8, nullptr, xb, keepA, rs, cD, cD, cD);

    k_rms<<<dim3(MTOK), 256, 0, stream>>>(xb, nmlp, hb);
    k_cvt8<<<dim3(1024), 256, 0, stream>>>(hb, h8m, (long)MTOK * cD);

    k_tconv8<<<dim3(128, 32), 256, 0, stream>>>(wg, wgu8, cD, cDFF, 0, 64.0f);
    k_tconv8<<<dim3(128, 32), 256, 0, stream>>>(wu, wgu8, cD, cDFF, 16, 64.0f);
    k_tconv8<<<dim3(32, 128), 256, 0, stream>>>(wd, wd8, cDFF, cD, -1, 64.0f);

    for (int cb = 0; cb < cDFF; cb += 4096) {
      k_gemm8<EPI_GLU><<<dim3(MTOK / 256, 32), 512, 0, stream>>>(
          h8m, wgu8 + (size_t)cb * 2 * cD, cbuf8, nullptr, cD, 4096, 0);
      k_gemm9<EPI_DOWNACC><<<dim3(MTOK / 128, cD / 128), 256, 0, stream>>>(
          cbuf8, wd8 + cb, nullptr, xb, nullptr, rs, 4096, cDFF, cD);
    }

    k_rms<<<dim3(MTOK), 256, 0, stream>>>(xb, nout, houtb);

    k_tgt<<<dim3(MTOK / 4), 256, 0, stream>>>(houtb, wlm, ids, anchors, ttok, tlogit);

    k_cvt8 <<<dim3(1024), 256, 0, stream>>>(houtb, h8, (long)MTOK * cD);
    k_conv8<<<dim3(2048), 256, 0, stream>>>(wlm, wlm8, (long)cV * cD, 64.0f);
    k_gemm8<EPI_STATS><<<dim3(MTOK / 256, NCH2), 512, 0, stream>>>(
        h8, wlm8, nullptr, parts, cD, 0, NCH2);

    k_combine<<<dim3(MTOK), 256, 0, stream>>>(parts, ttok, tlogit, keepA, anchors, lmask, tokOut, NCH2);
    k_final  <<<dim3(1), 256, 0, stream>>>(tokOut, outp);
    return;
  }

  // ---------------- fallback tier (round-3 path, fp32 weights in GEMM)
  const int cwopts[4] = {4096, 2048, 1024, 512};
  int CW = 0;
  for (int ci = 0; ci < 4; ++ci) {
    int cw = cwopts[ci];
    size_t cbufsz = (size_t)MTOK * cw * 2;
    size_t s1 = 2 * szQ;
    size_t s2 = szX + cbufsz;
    size_t sz = s1 > s2 ? s1 : s2;
    size_t pmin = (size_t)MTOK * NCH * 16;
    if (pmin > sz) sz = pmin;
    if (a1off + sz <= ws_size) { CW = cw; break; }
  }
  if (CW == 0) { k_sentinel<<<dim3(1), 64, 0, stream>>>(outp); return; }

  u16*   kb    = (u16*)(wsb + a1off);
  u16*   vb    = (u16*)(wsb + a1off + szQ);
  float* xb    = (float*)(wsb + a1off);
  u16*   cbuf  = (u16*)(wsb + a1off + szX);
  v4f*   parts = (v4f*)(wsb + a1off);
  u16*   hb    = qb;
  u16*   houtb = qb;

  k_rowinv<<<dim3(MKV), 256, 0, stream>>>(hs, emb, ftok, cpos, rowinv);

  k_gemm<ASRC_RMS, 0, EPI_BF16><<<dim3(MKV / 128, cD / 128), 256, 0, stream>>>(
      nullptr, wq, qb, nullptr, nullptr, nullptr, nullptr, rs, cD, cD, cD);
  k_gemm<ASRC_RMS, 0, EPI_BF16><<<dim3(MKV / 128, cD / 128), 256, 0, stream>>>(
      nullptr, wk, kb, nullptr, nullptr, nullptr, nullptr, rs, cD, cD, cD);
  k_gemm<ASRC_RMS, 0, EPI_BF16><<<dim3(MKV / 128, cD / 128), 256, 0, stream>>>(
      nullptr, wv, vb, nullptr, nullptr, nullptr, nullptr, rs, cD, cD, cD);

  k_rope<<<dim3(2 * MKV), 256, 0, stream>>>(qb, kb, anchors, cpos);
  k_attn<<<dim3(cB * cNA * cH), 64, 0, stream>>>(qb, kb, vb, nullptr);

  k_gemm<ASRC_AOMAP, 0, EPI_OEMB><<<dim3(MTOK / 128, cD / 128), 256, 0, stream>>>(
      qb, wo, nullptr, xb, nullptr, keepA, nullptr, rs, cD, cD, cD);

  k_rms<<<dim3(MTOK), 256, 0, stream>>>(xb, nmlp, hb);

  for (int cb = 0; cb < cDFF; cb += CW) {
    k_gemm<ASRC_BF16, 0, EPI_BF16><<<dim3(MTOK / 128, CW / 128), 256, 0, stream>>>(
        hb, wg + cb, cbuf, nullptr, nullptr, nullptr, nullptr, rs, cD, cDFF, CW);
    k_gemm<ASRC_BF16, 0, EPI_SILU><<<dim3(MTOK / 128, CW / 128), 256, 0, stream>>>(
        hb, wu + cb, cbuf, nullptr, cbuf, nullptr, nullptr, rs, cD, cDFF, CW);
    k_gemm<ASRC_BF16, 0, EPI_DOWNACC><<<dim3(MTOK / 128, cD / 128), 256, 0, stream>>>(
        cbuf, wd + (size_t)cb * cD, nullptr, xb, nullptr, nullptr, nullptr, rs, CW, cD, cD);
  }

  k_rms<<<dim3(MTOK), 256, 0, stream>>>(xb, nout, houtb);

  k_tgt<<<dim3(MTOK / 4), 256, 0, stream>>>(houtb, wlm, ids, anchors, ttok, tlogit);
  k_gemm<ASRC_BF16, 1, EPI_STATS><<<dim3(MTOK / 128, cV / 128), 256, 0, stream>>>(
      houtb, wlm, nullptr, nullptr, nullptr, nullptr, parts, rs, cD, cD, 0);

  k_combine<<<dim3(MTOK), 256, 0, stream>>>(parts, ttok, tlogit, keepA, anchors, lmask, tokOut, NCH);
  k_final  <<<dim3(1), 256, 0, stream>>>(tokOut, outp);
}